// Round 2
// baseline (3261.842 us; speedup 1.0000x reference)
//
#include <hip/hip_runtime.h>
#include <hip/hip_bf16.h>
#include <math.h>

#define BSZ 2
#define LSEQ 4096
#define DMODEL 1024
#define DINNER 2048
#define NSTATE 16
#define DTRANK 64
#define MROWS (BSZ * LSEQ)   // 8192

__device__ __forceinline__ float sigmoidf_(float x) { return 1.0f / (1.0f + __expf(-x)); }

// ---------------------------------------------------------------------------
// Generic tiled fp32 GEMM: C = act(A @ B + bias)
// A [Mr,K] row-major lda; B [K,Nc] row-major ldb; C [Mr,Nc] ldc.
// Requires Mr % 64 == 0, K % 16 == 0. Nc arbitrary (guarded).
// act: 0 = none, 1 = softplus (bias added first if non-null)
// ---------------------------------------------------------------------------
__global__ __launch_bounds__(256) void gemm_f32_kernel(
    const float* __restrict__ A, const float* __restrict__ Bw,
    float* __restrict__ C, const float* __restrict__ bias,
    int Mr, int Nc, int K, int lda, int ldb, int ldc, int act)
{
    __shared__ float As[16][65];   // [k][m], pad to kill bank conflicts
    __shared__ float Bs[16][65];   // [k][n]

    const int tid = threadIdx.x;
    const int tx = tid & 15;       // output col group
    const int ty = tid >> 4;       // output row group
    const int col0 = blockIdx.x * 64;
    const int row0 = blockIdx.y * 64;

    const int ak = tid & 15, am = tid >> 4;   // A staging: k, row-base
    const int bn = tid & 63, bk = tid >> 6;   // B staging: col, k-base

    float acc[4][4] = {};

    for (int k0 = 0; k0 < K; k0 += 16) {
        #pragma unroll
        for (int q = 0; q < 4; ++q)
            As[ak][am + 16 * q] =
                A[(size_t)(row0 + am + 16 * q) * lda + (k0 + ak)];
        #pragma unroll
        for (int q = 0; q < 4; ++q) {
            int col = col0 + bn;
            Bs[bk + 4 * q][bn] =
                (col < Nc) ? Bw[(size_t)(k0 + bk + 4 * q) * ldb + col] : 0.0f;
        }
        __syncthreads();

        #pragma unroll
        for (int kk = 0; kk < 16; ++kk) {
            float av[4], bv[4];
            #pragma unroll
            for (int i = 0; i < 4; ++i) av[i] = As[kk][ty + 16 * i];
            #pragma unroll
            for (int j = 0; j < 4; ++j) bv[j] = Bs[kk][tx + 16 * j];
            #pragma unroll
            for (int i = 0; i < 4; ++i)
                #pragma unroll
                for (int j = 0; j < 4; ++j)
                    acc[i][j] += av[i] * bv[j];
        }
        __syncthreads();
    }

    #pragma unroll
    for (int i = 0; i < 4; ++i) {
        int row = row0 + ty + 16 * i;
        #pragma unroll
        for (int j = 0; j < 4; ++j) {
            int col = col0 + tx + 16 * j;
            if (col < Nc) {
                float v = acc[i][j];
                if (bias) v += bias[col];
                if (act == 1) v = (v > 20.0f) ? v : log1pf(__expf(v));
                C[(size_t)row * ldc + col] = v;
            }
        }
    }
}

// ---------------------------------------------------------------------------
// Causal depthwise conv1d (width 4) + bias + silu.
// u = xz[:, 0:2048] (row stride 4096). uc [MROWS, DINNER].
// ---------------------------------------------------------------------------
__global__ __launch_bounds__(256) void conv_silu_kernel(
    const float* __restrict__ xz, const float* __restrict__ cw,
    const float* __restrict__ cb, float* __restrict__ uc)
{
    int idx = blockIdx.x * 256 + threadIdx.x;       // over MROWS*DINNER
    int d = idx & (DINNER - 1);
    int row = idx >> 11;                            // DINNER = 2^11
    int t = row & (LSEQ - 1);

    float acc = cb[d];
    #pragma unroll
    for (int k = 0; k < 4; ++k) {
        int tt = t - 3 + k;
        if (tt >= 0)
            acc += xz[(size_t)(row + k - 3) * 4096 + d] * cw[d * 4 + k];
    }
    uc[(size_t)row * DINNER + d] = acc * sigmoidf_(acc);
}

// ---------------------------------------------------------------------------
// Selective scan + skip + gate, fused.
// Block = 16 channels x 16 states (256 thr). lane: n = tid&15 (state),
// c = tid>>4 (channel). LDS-staged chunks of 16 timesteps, double-buffered
// with register prefetch.
// dt lives in xz[:, 0:2048] (u-half, dead after conv); z in xz[:, 2048:].
// Writes gated y IN PLACE over uc (each element consumed before overwrite;
// prefetch of chunk j+1 issued before chunk j's writes; blocks own disjoint
// column ranges).
// ---------------------------------------------------------------------------
__global__ __launch_bounds__(256) void scan_kernel(
    const float* __restrict__ dbc, float* __restrict__ xz,
    float* __restrict__ uc,
    const float* __restrict__ A_log, const float* __restrict__ Dp)
{
    __shared__ float sdt[2][16][16];
    __shared__ float su [2][16][16];
    __shared__ float sz [2][16][16];
    __shared__ float sB [2][16][16];
    __shared__ float sC [2][16][16];

    const int tid = threadIdx.x;
    const int n = tid & 15;          // state index
    const int c = tid >> 4;          // channel within block
    const int b = blockIdx.x >> 7;   // batch (128 d-blocks per batch)
    const int d0 = (blockIdx.x & 127) << 4;
    const int d = d0 + c;

    const float Aln = -__expf(A_log[d * NSTATE + n]);
    const float Dpd = Dp[d];

    // staging roles: r = timestep within chunk, q = channel within block
    const int r = tid >> 4, q = tid & 15;
    const size_t baseRow = (size_t)b * LSEQ;

    float l0, l1, l2, l3, l4;
    {
        size_t row = baseRow + r;
        l0 = xz [row * 4096 + d0 + q];          // dt
        l1 = uc [row * DINNER + d0 + q];        // u
        l2 = xz [row * 4096 + 2048 + d0 + q];   // z
        l3 = dbc[row * 96 + 64 + q];            // B
        l4 = dbc[row * 96 + 80 + q];            // C
    }
    sdt[0][r][q] = l0; su[0][r][q] = l1; sz[0][r][q] = l2;
    sB [0][r][q] = l3; sC[0][r][q] = l4;
    __syncthreads();

    float h = 0.0f;
    int cur = 0;
    const int NCH = LSEQ / 16;

    for (int j = 0; j < NCH; ++j) {
        if (j + 1 < NCH) {  // issue next chunk's loads early (hide HBM latency)
            size_t row = baseRow + (size_t)(j + 1) * 16 + r;
            l0 = xz [row * 4096 + d0 + q];
            l1 = uc [row * DINNER + d0 + q];
            l2 = xz [row * 4096 + 2048 + d0 + q];
            l3 = dbc[row * 96 + 64 + q];
            l4 = dbc[row * 96 + 80 + q];
        }

        float yreg = 0.0f;
        #pragma unroll
        for (int i = 0; i < 16; ++i) {
            float dtv = sdt[cur][i][c];
            float uv  = su [cur][i][c];
            float Bv  = sB [cur][i][n];
            float Cv  = sC [cur][i][n];
            float dA = __expf(dtv * Aln);
            h = h * dA + (dtv * uv) * Bv;
            float p = h * Cv;
            p += __shfl_xor(p, 1);
            p += __shfl_xor(p, 2);
            p += __shfl_xor(p, 4);
            p += __shfl_xor(p, 8);
            if (n == i) {
                float zv = sz[cur][i][c];
                yreg = (p + uv * Dpd) * (zv * sigmoidf_(zv));
            }
        }
        __syncthreads();
        if (j + 1 < NCH) {
            int nxt = cur ^ 1;
            sdt[nxt][r][q] = l0; su[nxt][r][q] = l1; sz[nxt][r][q] = l2;
            sB [nxt][r][q] = l3; sC[nxt][r][q] = l4;
        }
        // lane (c, n) holds gated y for timestep j*16 + n, channel d0 + c
        uc[(baseRow + (size_t)j * 16 + n) * DINNER + d0 + c] = yreg;
        __syncthreads();
        cur ^= 1;
    }
}

// ---------------------------------------------------------------------------
extern "C" void kernel_launch(void* const* d_in, const int* in_sizes, int n_in,
                              void* d_out, int out_size, void* d_ws, size_t ws_size,
                              hipStream_t stream)
{
    const float* x         = (const float*)d_in[0];
    const float* in_proj_w = (const float*)d_in[1];
    const float* conv_w    = (const float*)d_in[2];
    const float* conv_b    = (const float*)d_in[3];
    const float* x_proj_w  = (const float*)d_in[4];
    const float* dt_proj_w = (const float*)d_in[5];
    const float* dt_proj_b = (const float*)d_in[6];
    const float* A_log     = (const float*)d_in[7];
    const float* Dp        = (const float*)d_in[8];
    const float* out_proj_w= (const float*)d_in[9];
    float* out = (float*)d_out;

    // Workspace: 128 + 64 + 3 = 195 MiB (fits 256 MiB budget; previous
    // round's extra 64 MiB dt buffer pushed past it -> GPU fault).
    float* ws  = (float*)d_ws;
    float* xz  = ws;                                  // [MROWS, 4096]  u|z, dt overwrites u
    float* uc  = xz  + (size_t)MROWS * 4096;          // [MROWS, 2048]  conv out, then gated y
    float* dbc = uc  + (size_t)MROWS * 2048;          // [MROWS, 96]

    dim3 blk(256);

    // 1) xz = x @ in_proj_w                [8192,1024]x[1024,4096]
    gemm_f32_kernel<<<dim3(4096 / 64, MROWS / 64), blk, 0, stream>>>(
        x, in_proj_w, xz, nullptr, MROWS, 4096, 1024, 1024, 4096, 4096, 0);

    // 2) uc = silu(causal_conv(u) + conv_b)
    conv_silu_kernel<<<dim3((MROWS * DINNER) / 256), blk, 0, stream>>>(
        xz, conv_w, conv_b, uc);

    // 3) dbc = uc @ x_proj_w               [8192,2048]x[2048,96]
    gemm_f32_kernel<<<dim3(2, MROWS / 64), blk, 0, stream>>>(
        uc, x_proj_w, dbc, nullptr, MROWS, 96, 2048, 2048, 96, 96, 0);

    // 4) dt = softplus(dbc[:, :64] @ dt_proj_w + dt_proj_b) -> xz u-half
    gemm_f32_kernel<<<dim3(2048 / 64, MROWS / 64), blk, 0, stream>>>(
        dbc, dt_proj_w, xz, dt_proj_b, MROWS, 2048, 64, 96, 2048, 4096, 1);

    // 5) selective scan + skip + gate -> gated y in place over uc
    scan_kernel<<<dim3(BSZ * (DINNER / 16)), blk, 0, stream>>>(
        dbc, xz, uc, A_log, Dp);

    // 6) out = y_gated @ out_proj_w        [8192,2048]x[2048,1024]
    gemm_f32_kernel<<<dim3(1024 / 64, MROWS / 64), blk, 0, stream>>>(
        uc, out_proj_w, out, nullptr, MROWS, 1024, 2048, 2048, 1024, 1024, 0);
}

// Round 3
// 1640.056 us; speedup vs baseline: 1.9889x; 1.9889x over previous
//
#include <hip/hip_runtime.h>
#include <hip/hip_bf16.h>
#include <math.h>

#define BSZ 2
#define LSEQ 4096
#define DMODEL 1024
#define DINNER 2048
#define NSTATE 16
#define DTRANK 64
#define MROWS (BSZ * LSEQ)   // 8192

typedef __attribute__((ext_vector_type(8))) short bf16x8;
typedef __attribute__((ext_vector_type(4))) float f32x4;

__device__ __forceinline__ float sigmoidf_(float x) { return 1.0f / (1.0f + __expf(-x)); }

__device__ __forceinline__ unsigned short f2bf(float x) {
    unsigned int u = __float_as_uint(x);
    u += 0x7fff + ((u >> 16) & 1);          // round-to-nearest-even
    return (unsigned short)(u >> 16);
}

// ---------------------------------------------------------------------------
// Transpose + fp32->bf16 convert + global XOR pre-swizzle.
// W [K][N] fp32 row-major  ->  WT [N][K] bf16, where within each 64-element
// k-window the element k is stored at k ^ ((n&7)<<3)  (byte-level: 16B-slot
// XOR (n&7)) so a LINEAR global_load_lds lands the LDS tile pre-swizzled.
// Requires K%64==0, N%64==0.
// ---------------------------------------------------------------------------
__global__ __launch_bounds__(256) void transpose_swz_kernel(
    const float* __restrict__ W, unsigned short* __restrict__ WT, int K, int N)
{
    __shared__ float tile[64][65];
    const int t = threadIdx.x;
    const int n0 = blockIdx.x * 64;
    const int k0 = blockIdx.y * 64;

    #pragma unroll
    for (int i = 0; i < 16; ++i) {
        int flat = i * 256 + t;
        int r = flat >> 6, c = flat & 63;            // r: k, c: n
        tile[r][c] = W[(size_t)(k0 + r) * N + n0 + c];
    }
    __syncthreads();
    #pragma unroll
    for (int i = 0; i < 16; ++i) {
        int flat = i * 256 + t;
        int n = flat >> 6, k = flat & 63;
        int ks = k ^ ((n & 7) << 3);                 // pre-swizzle position
        WT[(size_t)(n0 + n) * K + k0 + ks] = f2bf(tile[k][n]);
    }
}

// ---------------------------------------------------------------------------
// bf16 MFMA GEMM: C[M,N] fp32 = A[M,K] fp32 @ B[K,N], with B given as
// pre-transposed, pre-swizzled bf16 BT[N][K].
// 128x128 tile, BK=64, 256 threads = 4 waves, each wave owns a 64x64
// quadrant = 4x4 grid of 16x16x32 MFMA fragments.
// A reg-staged (fp32->bf16 cvt) into XOR-swizzled LDS; B via
// global_load_lds width-16 (linear dest; source pre-swizzled).
// Requires M%128==0, N%128==0, K%64==0.
// ---------------------------------------------------------------------------
__global__ __launch_bounds__(256) void gemm_bf16_mfma_kernel(
    const float* __restrict__ A, const unsigned short* __restrict__ BT,
    float* __restrict__ C, int M, int N, int K, int lda, int ldc)
{
    __shared__ unsigned short lds_a[128 * 64];   // [row][k] bf16, swizzled
    __shared__ unsigned short lds_b[128 * 64];   // [col][k] bf16, swizzled

    const int tid  = threadIdx.x;
    const int lane = tid & 63;
    const int w    = tid >> 6;
    const int wr   = (w >> 1) * 64;              // wave row offset in tile
    const int wc   = (w & 1) * 64;               // wave col offset in tile
    const int row0 = blockIdx.y * 128;
    const int col0 = blockIdx.x * 128;

    f32x4 acc[4][4];
    #pragma unroll
    for (int m = 0; m < 4; ++m)
        #pragma unroll
        for (int n = 0; n < 4; ++n)
            acc[m][n] = (f32x4){0.f, 0.f, 0.f, 0.f};

    for (int k0 = 0; k0 < K; k0 += 64) {
        // ---- stage A: 128x64 fp32 -> bf16, swizzled ----
        #pragma unroll
        for (int i = 0; i < 8; ++i) {
            int chunk = i * 256 + tid;           // 2048 float4 chunks
            int r  = chunk >> 4;                 // row 0..127
            int kc = chunk & 15;                 // float4 within row
            float4 v = *reinterpret_cast<const float4*>(
                A + (size_t)(row0 + r) * lda + k0 + kc * 4);
            unsigned int p0 = (unsigned int)f2bf(v.x) | ((unsigned int)f2bf(v.y) << 16);
            unsigned int p1 = (unsigned int)f2bf(v.z) | ((unsigned int)f2bf(v.w) << 16);
            int byteoff = r * 128 + ((kc * 8) ^ ((r & 7) << 4));
            unsigned int* dst = reinterpret_cast<unsigned int*>((char*)lds_a + byteoff);
            dst[0] = p0; dst[1] = p1;
        }
        // ---- stage B: 128 rows x 128 B via global_load_lds (linear) ----
        #pragma unroll
        for (int j = 0; j < 4; ++j) {
            int c  = (j * 4 + w) * 64 + lane;    // 16B chunk id, 0..1023
            int br = c >> 3;                     // B row (col of B) 0..127
            int bc = c & 7;                      // 16B chunk within row
            const char* src = (const char*)BT +
                ((size_t)(col0 + br) * K + k0) * 2 + bc * 16;
            __builtin_amdgcn_global_load_lds(
                (const __attribute__((address_space(1))) void*)src,
                (__attribute__((address_space(3))) void*)((char*)lds_b + (j * 4 + w) * 1024),
                16, 0, 0);
        }
        __syncthreads();

        // ---- compute: 2 k-slices x 16 MFMA ----
        #pragma unroll
        for (int kk = 0; kk < 2; ++kk) {
            bf16x8 af[4], bfr[4];
            #pragma unroll
            for (int m = 0; m < 4; ++m) {
                int r = wr + m * 16 + (lane & 15);
                int byteoff = r * 128 + ((kk * 64 + (lane >> 4) * 16) ^ ((r & 7) << 4));
                af[m] = *reinterpret_cast<const bf16x8*>((const char*)lds_a + byteoff);
            }
            #pragma unroll
            for (int n = 0; n < 4; ++n) {
                int r = wc + n * 16 + (lane & 15);
                int byteoff = r * 128 + ((kk * 64 + (lane >> 4) * 16) ^ ((r & 7) << 4));
                bfr[n] = *reinterpret_cast<const bf16x8*>((const char*)lds_b + byteoff);
            }
            #pragma unroll
            for (int m = 0; m < 4; ++m)
                #pragma unroll
                for (int n = 0; n < 4; ++n)
                    acc[m][n] = __builtin_amdgcn_mfma_f32_16x16x32_bf16(
                        af[m], bfr[n], acc[m][n], 0, 0, 0);
        }
        __syncthreads();
    }

    // ---- epilogue: C/D layout col=lane&15, row=(lane>>4)*4+reg ----
    #pragma unroll
    for (int m = 0; m < 4; ++m) {
        int rbase = row0 + wr + m * 16 + (lane >> 4) * 4;
        #pragma unroll
        for (int n = 0; n < 4; ++n) {
            int col = col0 + wc + n * 16 + (lane & 15);
            #pragma unroll
            for (int r = 0; r < 4; ++r)
                C[(size_t)(rbase + r) * ldc + col] = acc[m][n][r];
        }
    }
}

// ---------------------------------------------------------------------------
// Generic tiled fp32 GEMM (kept for x_proj / dt_proj): C = act(A @ B + bias)
// ---------------------------------------------------------------------------
__global__ __launch_bounds__(256) void gemm_f32_kernel(
    const float* __restrict__ A, const float* __restrict__ Bw,
    float* __restrict__ C, const float* __restrict__ bias,
    int Mr, int Nc, int K, int lda, int ldb, int ldc, int act)
{
    __shared__ float As[16][65];
    __shared__ float Bs[16][65];

    const int tid = threadIdx.x;
    const int tx = tid & 15;
    const int ty = tid >> 4;
    const int col0 = blockIdx.x * 64;
    const int row0 = blockIdx.y * 64;

    const int ak = tid & 15, am = tid >> 4;
    const int bn = tid & 63, bk = tid >> 6;

    float acc[4][4] = {};

    for (int k0 = 0; k0 < K; k0 += 16) {
        #pragma unroll
        for (int q = 0; q < 4; ++q)
            As[ak][am + 16 * q] =
                A[(size_t)(row0 + am + 16 * q) * lda + (k0 + ak)];
        #pragma unroll
        for (int q = 0; q < 4; ++q) {
            int col = col0 + bn;
            Bs[bk + 4 * q][bn] =
                (col < Nc) ? Bw[(size_t)(k0 + bk + 4 * q) * ldb + col] : 0.0f;
        }
        __syncthreads();

        #pragma unroll
        for (int kk = 0; kk < 16; ++kk) {
            float av[4], bv[4];
            #pragma unroll
            for (int i = 0; i < 4; ++i) av[i] = As[kk][ty + 16 * i];
            #pragma unroll
            for (int j = 0; j < 4; ++j) bv[j] = Bs[kk][tx + 16 * j];
            #pragma unroll
            for (int i = 0; i < 4; ++i)
                #pragma unroll
                for (int j = 0; j < 4; ++j)
                    acc[i][j] += av[i] * bv[j];
        }
        __syncthreads();
    }

    #pragma unroll
    for (int i = 0; i < 4; ++i) {
        int row = row0 + ty + 16 * i;
        #pragma unroll
        for (int j = 0; j < 4; ++j) {
            int col = col0 + tx + 16 * j;
            if (col < Nc) {
                float v = acc[i][j];
                if (bias) v += bias[col];
                if (act == 1) v = (v > 20.0f) ? v : log1pf(__expf(v));
                C[(size_t)row * ldc + col] = v;
            }
        }
    }
}

// ---------------------------------------------------------------------------
// Causal depthwise conv1d (width 4) + bias + silu.
// ---------------------------------------------------------------------------
__global__ __launch_bounds__(256) void conv_silu_kernel(
    const float* __restrict__ xz, const float* __restrict__ cw,
    const float* __restrict__ cb, float* __restrict__ uc)
{
    int idx = blockIdx.x * 256 + threadIdx.x;
    int d = idx & (DINNER - 1);
    int row = idx >> 11;
    int t = row & (LSEQ - 1);

    float acc = cb[d];
    #pragma unroll
    for (int k = 0; k < 4; ++k) {
        int tt = t - 3 + k;
        if (tt >= 0)
            acc += xz[(size_t)(row + k - 3) * 4096 + d] * cw[d * 4 + k];
    }
    uc[(size_t)row * DINNER + d] = acc * sigmoidf_(acc);
}

// ---------------------------------------------------------------------------
// Selective scan + skip + gate, fused (fp32). Writes gated y in place over uc.
// ---------------------------------------------------------------------------
__global__ __launch_bounds__(256) void scan_kernel(
    const float* __restrict__ dbc, float* __restrict__ xz,
    float* __restrict__ uc,
    const float* __restrict__ A_log, const float* __restrict__ Dp)
{
    __shared__ float sdt[2][16][16];
    __shared__ float su [2][16][16];
    __shared__ float sz [2][16][16];
    __shared__ float sB [2][16][16];
    __shared__ float sC [2][16][16];

    const int tid = threadIdx.x;
    const int n = tid & 15;
    const int c = tid >> 4;
    const int b = blockIdx.x >> 7;
    const int d0 = (blockIdx.x & 127) << 4;
    const int d = d0 + c;

    const float Aln = -__expf(A_log[d * NSTATE + n]);
    const float Dpd = Dp[d];

    const int r = tid >> 4, q = tid & 15;
    const size_t baseRow = (size_t)b * LSEQ;

    float l0, l1, l2, l3, l4;
    {
        size_t row = baseRow + r;
        l0 = xz [row * 4096 + d0 + q];          // dt
        l1 = uc [row * DINNER + d0 + q];        // u
        l2 = xz [row * 4096 + 2048 + d0 + q];   // z
        l3 = dbc[row * 96 + 64 + q];            // B
        l4 = dbc[row * 96 + 80 + q];            // C
    }
    sdt[0][r][q] = l0; su[0][r][q] = l1; sz[0][r][q] = l2;
    sB [0][r][q] = l3; sC[0][r][q] = l4;
    __syncthreads();

    float h = 0.0f;
    int cur = 0;
    const int NCH = LSEQ / 16;

    for (int j = 0; j < NCH; ++j) {
        if (j + 1 < NCH) {
            size_t row = baseRow + (size_t)(j + 1) * 16 + r;
            l0 = xz [row * 4096 + d0 + q];
            l1 = uc [row * DINNER + d0 + q];
            l2 = xz [row * 4096 + 2048 + d0 + q];
            l3 = dbc[row * 96 + 64 + q];
            l4 = dbc[row * 96 + 80 + q];
        }

        float yreg = 0.0f;
        #pragma unroll
        for (int i = 0; i < 16; ++i) {
            float dtv = sdt[cur][i][c];
            float uv  = su [cur][i][c];
            float Bv  = sB [cur][i][n];
            float Cv  = sC [cur][i][n];
            float dA = __expf(dtv * Aln);
            h = h * dA + (dtv * uv) * Bv;
            float p = h * Cv;
            p += __shfl_xor(p, 1);
            p += __shfl_xor(p, 2);
            p += __shfl_xor(p, 4);
            p += __shfl_xor(p, 8);
            if (n == i) {
                float zv = sz[cur][i][c];
                yreg = (p + uv * Dpd) * (zv * sigmoidf_(zv));
            }
        }
        __syncthreads();
        if (j + 1 < NCH) {
            int nxt = cur ^ 1;
            sdt[nxt][r][q] = l0; su[nxt][r][q] = l1; sz[nxt][r][q] = l2;
            sB [nxt][r][q] = l3; sC[nxt][r][q] = l4;
        }
        uc[(baseRow + (size_t)j * 16 + n) * DINNER + d0 + c] = yreg;
        __syncthreads();
        cur ^= 1;
    }
}

// ---------------------------------------------------------------------------
extern "C" void kernel_launch(void* const* d_in, const int* in_sizes, int n_in,
                              void* d_out, int out_size, void* d_ws, size_t ws_size,
                              hipStream_t stream)
{
    const float* x         = (const float*)d_in[0];
    const float* in_proj_w = (const float*)d_in[1];
    const float* conv_w    = (const float*)d_in[2];
    const float* conv_b    = (const float*)d_in[3];
    const float* x_proj_w  = (const float*)d_in[4];
    const float* dt_proj_w = (const float*)d_in[5];
    const float* dt_proj_b = (const float*)d_in[6];
    const float* A_log     = (const float*)d_in[7];
    const float* Dp        = (const float*)d_in[8];
    const float* out_proj_w= (const float*)d_in[9];
    float* out = (float*)d_out;

    // Workspace layout (207 MiB total; budget ~256 MiB):
    float* ws  = (float*)d_ws;
    float* xz  = ws;                                  // [8192][4096] fp32 (u->dt | z)
    float* uc  = xz  + (size_t)MROWS * 4096;          // [8192][2048] fp32 (conv out -> gated y)
    float* dbc = uc  + (size_t)MROWS * 2048;          // [8192][96] fp32
    unsigned short* wT_in  = (unsigned short*)(dbc + (size_t)MROWS * 96); // [4096][1024] bf16 swz
    unsigned short* wT_out = wT_in + (size_t)4096 * 1024;                 // [1024][2048] bf16 swz

    dim3 blk(256);

    // 0) weight transpose+convert+pre-swizzle (tiny)
    transpose_swz_kernel<<<dim3(4096 / 64, 1024 / 64), blk, 0, stream>>>(
        in_proj_w, wT_in, 1024, 4096);
    transpose_swz_kernel<<<dim3(1024 / 64, 2048 / 64), blk, 0, stream>>>(
        out_proj_w, wT_out, 2048, 1024);

    // 1) xz = x @ in_proj_w   (bf16 MFMA)  [8192,1024]x[1024,4096]
    gemm_bf16_mfma_kernel<<<dim3(4096 / 128, MROWS / 128), blk, 0, stream>>>(
        x, wT_in, xz, MROWS, 4096, 1024, 1024, 4096);

    // 2) uc = silu(causal_conv(u) + conv_b)
    conv_silu_kernel<<<dim3((MROWS * DINNER) / 256), blk, 0, stream>>>(
        xz, conv_w, conv_b, uc);

    // 3) dbc = uc @ x_proj_w  (fp32)       [8192,2048]x[2048,96]
    gemm_f32_kernel<<<dim3(2, MROWS / 64), blk, 0, stream>>>(
        uc, x_proj_w, dbc, nullptr, MROWS, 96, 2048, 2048, 96, 96, 0);

    // 4) dt = softplus(dbc[:, :64] @ dt_proj_w + dt_proj_b) -> xz u-half (fp32)
    gemm_f32_kernel<<<dim3(2048 / 64, MROWS / 64), blk, 0, stream>>>(
        dbc, dt_proj_w, xz, dt_proj_b, MROWS, 2048, 64, 96, 2048, 4096, 1);

    // 5) selective scan + skip + gate -> gated y in place over uc (fp32)
    scan_kernel<<<dim3(BSZ * (DINNER / 16)), blk, 0, stream>>>(
        dbc, xz, uc, A_log, Dp);

    // 6) out = y_gated @ out_proj_w  (bf16 MFMA)  [8192,2048]x[2048,1024]
    gemm_bf16_mfma_kernel<<<dim3(1024 / 128, MROWS / 128), blk, 0, stream>>>(
        uc, wT_out, out, MROWS, 1024, 2048, 2048, 1024);
}

// Round 4
// 777.473 us; speedup vs baseline: 4.1954x; 2.1095x over previous
//
#include <hip/hip_runtime.h>
#include <hip/hip_bf16.h>
#include <math.h>

#define BSZ 2
#define LSEQ 4096
#define DMODEL 1024
#define DINNER 2048
#define NSTATE 16
#define DTRANK 64
#define MROWS (BSZ * LSEQ)   // 8192
#define NCHUNK 64
#define CHUNK (LSEQ / NCHUNK)  // 64

#if __has_builtin(__builtin_amdgcn_exp2f)
#define EXP2F(x) __builtin_amdgcn_exp2f(x)
#else
#define EXP2F(x) exp2f(x)
#endif
#define LOG2E 1.44269504088896f

typedef __attribute__((ext_vector_type(8))) short bf16x8;
typedef __attribute__((ext_vector_type(4))) float f32x4;

__device__ __forceinline__ float sigmoidf_(float x) { return 1.0f / (1.0f + __expf(-x)); }

__device__ __forceinline__ unsigned short f2bf(float x) {
    unsigned int u = __float_as_uint(x);
    u += 0x7fff + ((u >> 16) & 1);          // round-to-nearest-even
    return (unsigned short)(u >> 16);
}

// ---------------------------------------------------------------------------
// Transpose + fp32->bf16 convert + global XOR pre-swizzle (for MFMA GEMM B).
// ---------------------------------------------------------------------------
__global__ __launch_bounds__(256) void transpose_swz_kernel(
    const float* __restrict__ W, unsigned short* __restrict__ WT, int K, int N)
{
    __shared__ float tile[64][65];
    const int t = threadIdx.x;
    const int n0 = blockIdx.x * 64;
    const int k0 = blockIdx.y * 64;

    #pragma unroll
    for (int i = 0; i < 16; ++i) {
        int flat = i * 256 + t;
        int r = flat >> 6, c = flat & 63;            // r: k, c: n
        tile[r][c] = W[(size_t)(k0 + r) * N + n0 + c];
    }
    __syncthreads();
    #pragma unroll
    for (int i = 0; i < 16; ++i) {
        int flat = i * 256 + t;
        int n = flat >> 6, k = flat & 63;
        int ks = k ^ ((n & 7) << 3);                 // pre-swizzle position
        WT[(size_t)(n0 + n) * K + k0 + ks] = f2bf(tile[k][n]);
    }
}

// ---------------------------------------------------------------------------
// bf16 MFMA GEMM: C[M,N] fp32 = A[M,K] fp32 @ B, B pre-transposed/swizzled.
// 128x128 tile, BK=64, 4 waves x 64x64 quadrant of 16x16x32 fragments.
// ---------------------------------------------------------------------------
__global__ __launch_bounds__(256) void gemm_bf16_mfma_kernel(
    const float* __restrict__ A, const unsigned short* __restrict__ BT,
    float* __restrict__ C, int M, int N, int K, int lda, int ldc)
{
    __shared__ unsigned short lds_a[128 * 64];
    __shared__ unsigned short lds_b[128 * 64];

    const int tid  = threadIdx.x;
    const int lane = tid & 63;
    const int w    = tid >> 6;
    const int wr   = (w >> 1) * 64;
    const int wc   = (w & 1) * 64;
    const int row0 = blockIdx.y * 128;
    const int col0 = blockIdx.x * 128;

    f32x4 acc[4][4];
    #pragma unroll
    for (int m = 0; m < 4; ++m)
        #pragma unroll
        for (int n = 0; n < 4; ++n)
            acc[m][n] = (f32x4){0.f, 0.f, 0.f, 0.f};

    for (int k0 = 0; k0 < K; k0 += 64) {
        #pragma unroll
        for (int i = 0; i < 8; ++i) {
            int chunk = i * 256 + tid;
            int r  = chunk >> 4;
            int kc = chunk & 15;
            float4 v = *reinterpret_cast<const float4*>(
                A + (size_t)(row0 + r) * lda + k0 + kc * 4);
            unsigned int p0 = (unsigned int)f2bf(v.x) | ((unsigned int)f2bf(v.y) << 16);
            unsigned int p1 = (unsigned int)f2bf(v.z) | ((unsigned int)f2bf(v.w) << 16);
            int byteoff = r * 128 + ((kc * 8) ^ ((r & 7) << 4));
            unsigned int* dst = reinterpret_cast<unsigned int*>((char*)lds_a + byteoff);
            dst[0] = p0; dst[1] = p1;
        }
        #pragma unroll
        for (int j = 0; j < 4; ++j) {
            int c  = (j * 4 + w) * 64 + lane;
            int br = c >> 3;
            int bc = c & 7;
            const char* src = (const char*)BT +
                ((size_t)(col0 + br) * K + k0) * 2 + bc * 16;
            __builtin_amdgcn_global_load_lds(
                (const __attribute__((address_space(1))) void*)src,
                (__attribute__((address_space(3))) void*)((char*)lds_b + (j * 4 + w) * 1024),
                16, 0, 0);
        }
        __syncthreads();

        #pragma unroll
        for (int kk = 0; kk < 2; ++kk) {
            bf16x8 af[4], bfr[4];
            #pragma unroll
            for (int m = 0; m < 4; ++m) {
                int r = wr + m * 16 + (lane & 15);
                int byteoff = r * 128 + ((kk * 64 + (lane >> 4) * 16) ^ ((r & 7) << 4));
                af[m] = *reinterpret_cast<const bf16x8*>((const char*)lds_a + byteoff);
            }
            #pragma unroll
            for (int n = 0; n < 4; ++n) {
                int r = wc + n * 16 + (lane & 15);
                int byteoff = r * 128 + ((kk * 64 + (lane >> 4) * 16) ^ ((r & 7) << 4));
                bfr[n] = *reinterpret_cast<const bf16x8*>((const char*)lds_b + byteoff);
            }
            #pragma unroll
            for (int m = 0; m < 4; ++m)
                #pragma unroll
                for (int n = 0; n < 4; ++n)
                    acc[m][n] = __builtin_amdgcn_mfma_f32_16x16x32_bf16(
                        af[m], bfr[n], acc[m][n], 0, 0, 0);
        }
        __syncthreads();
    }

    #pragma unroll
    for (int m = 0; m < 4; ++m) {
        int rbase = row0 + wr + m * 16 + (lane >> 4) * 4;
        #pragma unroll
        for (int n = 0; n < 4; ++n) {
            int col = col0 + wc + n * 16 + (lane & 15);
            #pragma unroll
            for (int r = 0; r < 4; ++r)
                C[(size_t)(rbase + r) * ldc + col] = acc[m][n][r];
        }
    }
}

// ---------------------------------------------------------------------------
// Generic tiled fp32 GEMM (x_proj / dt_proj): C = act(A @ B + bias)
// ---------------------------------------------------------------------------
__global__ __launch_bounds__(256) void gemm_f32_kernel(
    const float* __restrict__ A, const float* __restrict__ Bw,
    float* __restrict__ C, const float* __restrict__ bias,
    int Mr, int Nc, int K, int lda, int ldb, int ldc, int act)
{
    __shared__ float As[16][65];
    __shared__ float Bs[16][65];

    const int tid = threadIdx.x;
    const int tx = tid & 15;
    const int ty = tid >> 4;
    const int col0 = blockIdx.x * 64;
    const int row0 = blockIdx.y * 64;

    const int ak = tid & 15, am = tid >> 4;
    const int bn = tid & 63, bk = tid >> 6;

    float acc[4][4] = {};

    for (int k0 = 0; k0 < K; k0 += 16) {
        #pragma unroll
        for (int q = 0; q < 4; ++q)
            As[ak][am + 16 * q] =
                A[(size_t)(row0 + am + 16 * q) * lda + (k0 + ak)];
        #pragma unroll
        for (int q = 0; q < 4; ++q) {
            int col = col0 + bn;
            Bs[bk + 4 * q][bn] =
                (col < Nc) ? Bw[(size_t)(k0 + bk + 4 * q) * ldb + col] : 0.0f;
        }
        __syncthreads();

        #pragma unroll
        for (int kk = 0; kk < 16; ++kk) {
            float av[4], bv[4];
            #pragma unroll
            for (int i = 0; i < 4; ++i) av[i] = As[kk][ty + 16 * i];
            #pragma unroll
            for (int j = 0; j < 4; ++j) bv[j] = Bs[kk][tx + 16 * j];
            #pragma unroll
            for (int i = 0; i < 4; ++i)
                #pragma unroll
                for (int j = 0; j < 4; ++j)
                    acc[i][j] += av[i] * bv[j];
        }
        __syncthreads();
    }

    #pragma unroll
    for (int i = 0; i < 4; ++i) {
        int row = row0 + ty + 16 * i;
        #pragma unroll
        for (int j = 0; j < 4; ++j) {
            int col = col0 + tx + 16 * j;
            if (col < Nc) {
                float v = acc[i][j];
                if (bias) v += bias[col];
                if (act == 1) v = (v > 20.0f) ? v : log1pf(__expf(v));
                C[(size_t)row * ldc + col] = v;
            }
        }
    }
}

// ---------------------------------------------------------------------------
// Causal depthwise conv1d (width 4) + bias + silu.
// ---------------------------------------------------------------------------
__global__ __launch_bounds__(256) void conv_silu_kernel(
    const float* __restrict__ xz, const float* __restrict__ cw,
    const float* __restrict__ cb, float* __restrict__ uc)
{
    int idx = blockIdx.x * 256 + threadIdx.x;
    int d = idx & (DINNER - 1);
    int row = idx >> 11;
    int t = row & (LSEQ - 1);

    float acc = cb[d];
    #pragma unroll
    for (int k = 0; k < 4; ++k) {
        int tt = t - 3 + k;
        if (tt >= 0)
            acc += xz[(size_t)(row + k - 3) * 4096 + d] * cw[d * 4 + k];
    }
    uc[(size_t)row * DINNER + d] = acc * sigmoidf_(acc);
}

// ---------------------------------------------------------------------------
// Chunked scan, pass A: per (b,d,chunk) thread computes local scan end-state
// E[16] (from h=0) and chunk decay P[n] = exp2(An2[n] * sum(dt)).
// Layout of P/E: [c][b][d][n].
// ---------------------------------------------------------------------------
__global__ __launch_bounds__(256) void scan_partial_kernel(
    const float* __restrict__ dtm,   // xz: dt at cols [0,2048), row stride 4096
    const float* __restrict__ um,    // uc: [row][2048]
    const float* __restrict__ dbc,   // [row][96], B at 64..80
    const float* __restrict__ A_log,
    float* __restrict__ Pbuf, float* __restrict__ Ebuf)
{
    __shared__ float sB[CHUNK][NSTATE];
    const int tid = threadIdx.x;
    const int c = blockIdx.x;
    const int b = blockIdx.z;
    const int d = blockIdx.y * 256 + tid;
    const size_t row0 = (size_t)b * LSEQ + c * CHUNK;

    {   // stage B chunk: 64 t x 16 n, one float4 per thread
        int s = tid >> 2, f = tid & 3;
        float4 v = *reinterpret_cast<const float4*>(dbc + (row0 + s) * 96 + 64 + f * 4);
        *reinterpret_cast<float4*>(&sB[s][f * 4]) = v;
    }

    float An2[NSTATE];
    #pragma unroll
    for (int k = 0; k < 4; ++k) {
        float4 a = *reinterpret_cast<const float4*>(A_log + (size_t)d * NSTATE + k * 4);
        An2[k*4+0] = -__expf(a.x) * LOG2E;
        An2[k*4+1] = -__expf(a.y) * LOG2E;
        An2[k*4+2] = -__expf(a.z) * LOG2E;
        An2[k*4+3] = -__expf(a.w) * LOG2E;
    }
    __syncthreads();

    float E[NSTATE];
    #pragma unroll
    for (int n = 0; n < NSTATE; ++n) E[n] = 0.f;
    float S = 0.f;

    const float* pdt = dtm + row0 * 4096 + d;
    const float* pu  = um  + row0 * 2048 + d;

    float dtc = pdt[0], ucv = pu[0];
    for (int s = 0; s < CHUNK; ++s) {
        float dtn = 0.f, un = 0.f;
        if (s + 1 < CHUNK) {
            dtn = pdt[(size_t)(s + 1) * 4096];
            un  = pu [(size_t)(s + 1) * 2048];
        }
        S += dtc;
        float du = dtc * ucv;
        float Bv[NSTATE];
        #pragma unroll
        for (int k = 0; k < 4; ++k)
            *reinterpret_cast<float4*>(&Bv[k*4]) =
                *reinterpret_cast<const float4*>(&sB[s][k*4]);
        #pragma unroll
        for (int n = 0; n < NSTATE; ++n) {
            float q = EXP2F(dtc * An2[n]);
            E[n] = fmaf(E[n], q, du * Bv[n]);
        }
        dtc = dtn; ucv = un;
    }

    size_t base = (((size_t)c * BSZ + b) * DINNER + d) * NSTATE;
    #pragma unroll
    for (int n = 0; n < NSTATE; ++n) {
        Pbuf[base + n] = EXP2F(An2[n] * S);
        Ebuf[base + n] = E[n];
    }
}

// ---------------------------------------------------------------------------
// Pass B: exclusive scan over chunks per (b,d,n); h0 written IN PLACE over P.
// ---------------------------------------------------------------------------
__global__ __launch_bounds__(256) void scan_prefix_kernel(
    float* __restrict__ Pbuf, const float* __restrict__ Ebuf)
{
    const int gid = blockIdx.x * 256 + threadIdx.x;   // 65536 = B*D*N
    const size_t stride = (size_t)BSZ * DINNER * NSTATE;
    size_t idx = gid;
    float h = 0.f;
    for (int c = 0; c < NCHUNK; ++c) {
        float P = Pbuf[idx];
        float Ev = Ebuf[idx];
        Pbuf[idx] = h;                 // exclusive prefix (h0 for chunk c)
        h = fmaf(P, h, Ev);
        idx += stride;
    }
}

// ---------------------------------------------------------------------------
// Pass C: re-run local scan seeded with h0; fuse y, skip, gate; write over uc.
// ---------------------------------------------------------------------------
__global__ __launch_bounds__(256) void scan_final_kernel(
    const float* __restrict__ xzm,   // dt at [row][0..2048), z at [row][2048..)
    float* __restrict__ um,          // u in, gated y out (in place)
    const float* __restrict__ dbc,
    const float* __restrict__ A_log, const float* __restrict__ Dp,
    const float* __restrict__ H0)    // = Pbuf after pass B
{
    __shared__ float sBC[CHUNK][2 * NSTATE];
    const int tid = threadIdx.x;
    const int c = blockIdx.x;
    const int b = blockIdx.z;
    const int d = blockIdx.y * 256 + tid;
    const size_t row0 = (size_t)b * LSEQ + c * CHUNK;

    {   // stage B|C chunk: 64 t x 32 cols, two float4 per thread
        #pragma unroll
        for (int i = 0; i < 2; ++i) {
            int j = tid * 2 + i;          // 0..511
            int s = j >> 3, f = j & 7;
            float4 v = *reinterpret_cast<const float4*>(dbc + (row0 + s) * 96 + 64 + f * 4);
            *reinterpret_cast<float4*>(&sBC[s][f * 4]) = v;
        }
    }

    float An2[NSTATE];
    #pragma unroll
    for (int k = 0; k < 4; ++k) {
        float4 a = *reinterpret_cast<const float4*>(A_log + (size_t)d * NSTATE + k * 4);
        An2[k*4+0] = -__expf(a.x) * LOG2E;
        An2[k*4+1] = -__expf(a.y) * LOG2E;
        An2[k*4+2] = -__expf(a.z) * LOG2E;
        An2[k*4+3] = -__expf(a.w) * LOG2E;
    }
    const float Dpd = Dp[d];

    float h[NSTATE];
    {
        size_t base = (((size_t)c * BSZ + b) * DINNER + d) * NSTATE;
        #pragma unroll
        for (int n = 0; n < NSTATE; ++n) h[n] = H0[base + n];
    }
    __syncthreads();

    const float* pdt = xzm + row0 * 4096 + d;
    const float* pz  = xzm + row0 * 4096 + 2048 + d;
    float* py        = um  + row0 * 2048 + d;

    float dtc = pdt[0], ucv = py[0], zc = pz[0];
    for (int s = 0; s < CHUNK; ++s) {
        float dtn = 0.f, un = 0.f, zn = 0.f;
        if (s + 1 < CHUNK) {
            dtn = pdt[(size_t)(s + 1) * 4096];
            un  = py [(size_t)(s + 1) * 2048];
            zn  = pz [(size_t)(s + 1) * 4096];
        }
        float du = dtc * ucv;
        float Bv[NSTATE], Cv[NSTATE];
        #pragma unroll
        for (int k = 0; k < 4; ++k) {
            *reinterpret_cast<float4*>(&Bv[k*4]) =
                *reinterpret_cast<const float4*>(&sBC[s][k*4]);
            *reinterpret_cast<float4*>(&Cv[k*4]) =
                *reinterpret_cast<const float4*>(&sBC[s][16 + k*4]);
        }
        float y0 = 0.f, y1 = 0.f, y2 = 0.f, y3 = 0.f;
        #pragma unroll
        for (int n = 0; n < NSTATE; ++n) {
            float q = EXP2F(dtc * An2[n]);
            h[n] = fmaf(h[n], q, du * Bv[n]);
            float& yk = (n & 3) == 0 ? y0 : (n & 3) == 1 ? y1 : (n & 3) == 2 ? y2 : y3;
            yk = fmaf(h[n], Cv[n], yk);
        }
        float y = (y0 + y1) + (y2 + y3);
        float yg = (y + ucv * Dpd) * (zc * sigmoidf_(zc));
        py[(size_t)s * 2048] = yg;
        dtc = dtn; ucv = un; zc = zn;
    }
}

// ---------------------------------------------------------------------------
extern "C" void kernel_launch(void* const* d_in, const int* in_sizes, int n_in,
                              void* d_out, int out_size, void* d_ws, size_t ws_size,
                              hipStream_t stream)
{
    const float* x         = (const float*)d_in[0];
    const float* in_proj_w = (const float*)d_in[1];
    const float* conv_w    = (const float*)d_in[2];
    const float* conv_b    = (const float*)d_in[3];
    const float* x_proj_w  = (const float*)d_in[4];
    const float* dt_proj_w = (const float*)d_in[5];
    const float* dt_proj_b = (const float*)d_in[6];
    const float* A_log     = (const float*)d_in[7];
    const float* Dp        = (const float*)d_in[8];
    const float* out_proj_w= (const float*)d_in[9];
    float* out = (float*)d_out;

    // Workspace: 128 + 64 + 3 + 8 + 4 + 16 + 16 = 239 MiB (budget ~256 MiB)
    float* ws  = (float*)d_ws;
    float* xz  = ws;                                  // [8192][4096] (u->dt | z)
    float* uc  = xz  + (size_t)MROWS * 4096;          // [8192][2048] (conv -> gated y)
    float* dbc = uc  + (size_t)MROWS * 2048;          // [8192][96]
    unsigned short* wT_in  = (unsigned short*)(dbc + (size_t)MROWS * 96);
    unsigned short* wT_out = wT_in + (size_t)4096 * 1024;
    float* Pbuf = (float*)(wT_out + (size_t)1024 * 2048);   // [64][2][2048][16]
    float* Ebuf = Pbuf + (size_t)NCHUNK * BSZ * DINNER * NSTATE;

    dim3 blk(256);

    // 0) weight transpose+convert+pre-swizzle
    transpose_swz_kernel<<<dim3(4096 / 64, 1024 / 64), blk, 0, stream>>>(
        in_proj_w, wT_in, 1024, 4096);
    transpose_swz_kernel<<<dim3(1024 / 64, 2048 / 64), blk, 0, stream>>>(
        out_proj_w, wT_out, 2048, 1024);

    // 1) xz = x @ in_proj_w   (bf16 MFMA)
    gemm_bf16_mfma_kernel<<<dim3(4096 / 128, MROWS / 128), blk, 0, stream>>>(
        x, wT_in, xz, MROWS, 4096, 1024, 1024, 4096);

    // 2) uc = silu(causal_conv(u) + conv_b)
    conv_silu_kernel<<<dim3((MROWS * DINNER) / 256), blk, 0, stream>>>(
        xz, conv_w, conv_b, uc);

    // 3) dbc = uc @ x_proj_w  (fp32)
    gemm_f32_kernel<<<dim3(2, MROWS / 64), blk, 0, stream>>>(
        uc, x_proj_w, dbc, nullptr, MROWS, 96, 2048, 2048, 96, 96, 0);

    // 4) dt = softplus(dbc[:, :64] @ dt_proj_w + dt_proj_b) -> xz u-half
    gemm_f32_kernel<<<dim3(2048 / 64, MROWS / 64), blk, 0, stream>>>(
        dbc, dt_proj_w, xz, dt_proj_b, MROWS, 2048, 64, 96, 2048, 4096, 1);

    // 5) chunked selective scan (3 passes) -> gated y over uc
    scan_partial_kernel<<<dim3(NCHUNK, DINNER / 256, BSZ), blk, 0, stream>>>(
        xz, uc, dbc, A_log, Pbuf, Ebuf);
    scan_prefix_kernel<<<dim3((BSZ * DINNER * NSTATE) / 256), blk, 0, stream>>>(
        Pbuf, Ebuf);
    scan_final_kernel<<<dim3(NCHUNK, DINNER / 256, BSZ), blk, 0, stream>>>(
        xz, uc, dbc, A_log, Dp, Pbuf);

    // 6) out = y_gated @ out_proj_w  (bf16 MFMA)
    gemm_bf16_mfma_kernel<<<dim3(1024 / 128, MROWS / 128), blk, 0, stream>>>(
        uc, wT_out, out, MROWS, 1024, 2048, 2048, 1024);
}

// Round 5
// 632.530 us; speedup vs baseline: 5.1568x; 1.2291x over previous
//
#include <hip/hip_runtime.h>
#include <hip/hip_bf16.h>
#include <math.h>

#define BSZ 2
#define LSEQ 4096
#define DMODEL 1024
#define DINNER 2048
#define NSTATE 16
#define DTRANK 64
#define MROWS (BSZ * LSEQ)   // 8192
#define NCHUNK 64
#define CHUNK (LSEQ / NCHUNK)  // 64
#define KSPLIT 8
#define KCH (DINNER / KSPLIT)  // 256

#if __has_builtin(__builtin_amdgcn_exp2f)
#define EXP2F(x) __builtin_amdgcn_exp2f(x)
#else
#define EXP2F(x) exp2f(x)
#endif
#define LOG2E 1.44269504088896f

typedef __attribute__((ext_vector_type(8))) short bf16x8;
typedef __attribute__((ext_vector_type(4))) float f32x4;

__device__ __forceinline__ float sigmoidf_(float x) { return 1.0f / (1.0f + __expf(-x)); }

__device__ __forceinline__ unsigned short f2bf(float x) {
    unsigned int u = __float_as_uint(x);
    u += 0x7fff + ((u >> 16) & 1);          // round-to-nearest-even
    return (unsigned short)(u >> 16);
}

// ---------------------------------------------------------------------------
// Transpose + fp32->bf16 convert + global XOR pre-swizzle (for MFMA GEMM B).
// ---------------------------------------------------------------------------
__global__ __launch_bounds__(256) void transpose_swz_kernel(
    const float* __restrict__ W, unsigned short* __restrict__ WT, int K, int N)
{
    __shared__ float tile[64][65];
    const int t = threadIdx.x;
    const int n0 = blockIdx.x * 64;
    const int k0 = blockIdx.y * 64;

    #pragma unroll
    for (int i = 0; i < 16; ++i) {
        int flat = i * 256 + t;
        int r = flat >> 6, c = flat & 63;            // r: k, c: n
        tile[r][c] = W[(size_t)(k0 + r) * N + n0 + c];
    }
    __syncthreads();
    #pragma unroll
    for (int i = 0; i < 16; ++i) {
        int flat = i * 256 + t;
        int n = flat >> 6, k = flat & 63;
        int ks = k ^ ((n & 7) << 3);                 // pre-swizzle position
        WT[(size_t)(n0 + n) * K + k0 + ks] = f2bf(tile[k][n]);
    }
}

// ---------------------------------------------------------------------------
// bf16 MFMA GEMM: C[M,N] fp32 = A[M,K] fp32 @ B, B pre-transposed/swizzled.
// 128x128 tile, BK=64, 4 waves x 64x64 quadrant of 16x16x32 fragments.
// ---------------------------------------------------------------------------
__global__ __launch_bounds__(256) void gemm_bf16_mfma_kernel(
    const float* __restrict__ A, const unsigned short* __restrict__ BT,
    float* __restrict__ C, int M, int N, int K, int lda, int ldc)
{
    __shared__ unsigned short lds_a[128 * 64];
    __shared__ unsigned short lds_b[128 * 64];

    const int tid  = threadIdx.x;
    const int lane = tid & 63;
    const int w    = tid >> 6;
    const int wr   = (w >> 1) * 64;
    const int wc   = (w & 1) * 64;
    const int row0 = blockIdx.y * 128;
    const int col0 = blockIdx.x * 128;

    f32x4 acc[4][4];
    #pragma unroll
    for (int m = 0; m < 4; ++m)
        #pragma unroll
        for (int n = 0; n < 4; ++n)
            acc[m][n] = (f32x4){0.f, 0.f, 0.f, 0.f};

    for (int k0 = 0; k0 < K; k0 += 64) {
        #pragma unroll
        for (int i = 0; i < 8; ++i) {
            int chunk = i * 256 + tid;
            int r  = chunk >> 4;
            int kc = chunk & 15;
            float4 v = *reinterpret_cast<const float4*>(
                A + (size_t)(row0 + r) * lda + k0 + kc * 4);
            unsigned int p0 = (unsigned int)f2bf(v.x) | ((unsigned int)f2bf(v.y) << 16);
            unsigned int p1 = (unsigned int)f2bf(v.z) | ((unsigned int)f2bf(v.w) << 16);
            int byteoff = r * 128 + ((kc * 8) ^ ((r & 7) << 4));
            unsigned int* dst = reinterpret_cast<unsigned int*>((char*)lds_a + byteoff);
            dst[0] = p0; dst[1] = p1;
        }
        #pragma unroll
        for (int j = 0; j < 4; ++j) {
            int c  = (j * 4 + w) * 64 + lane;
            int br = c >> 3;
            int bc = c & 7;
            const char* src = (const char*)BT +
                ((size_t)(col0 + br) * K + k0) * 2 + bc * 16;
            __builtin_amdgcn_global_load_lds(
                (const __attribute__((address_space(1))) void*)src,
                (__attribute__((address_space(3))) void*)((char*)lds_b + (j * 4 + w) * 1024),
                16, 0, 0);
        }
        __syncthreads();

        #pragma unroll
        for (int kk = 0; kk < 2; ++kk) {
            bf16x8 af[4], bfr[4];
            #pragma unroll
            for (int m = 0; m < 4; ++m) {
                int r = wr + m * 16 + (lane & 15);
                int byteoff = r * 128 + ((kk * 64 + (lane >> 4) * 16) ^ ((r & 7) << 4));
                af[m] = *reinterpret_cast<const bf16x8*>((const char*)lds_a + byteoff);
            }
            #pragma unroll
            for (int n = 0; n < 4; ++n) {
                int r = wc + n * 16 + (lane & 15);
                int byteoff = r * 128 + ((kk * 64 + (lane >> 4) * 16) ^ ((r & 7) << 4));
                bfr[n] = *reinterpret_cast<const bf16x8*>((const char*)lds_b + byteoff);
            }
            #pragma unroll
            for (int m = 0; m < 4; ++m)
                #pragma unroll
                for (int n = 0; n < 4; ++n)
                    acc[m][n] = __builtin_amdgcn_mfma_f32_16x16x32_bf16(
                        af[m], bfr[n], acc[m][n], 0, 0, 0);
        }
        __syncthreads();
    }

    #pragma unroll
    for (int m = 0; m < 4; ++m) {
        int rbase = row0 + wr + m * 16 + (lane >> 4) * 4;
        #pragma unroll
        for (int n = 0; n < 4; ++n) {
            int col = col0 + wc + n * 16 + (lane & 15);
            #pragma unroll
            for (int r = 0; r < 4; ++r)
                C[(size_t)(rbase + r) * ldc + col] = acc[m][n][r];
        }
    }
}

// ---------------------------------------------------------------------------
// Generic tiled fp32 GEMM (dt_proj): C = act(A @ B + bias)
// ---------------------------------------------------------------------------
__global__ __launch_bounds__(256) void gemm_f32_kernel(
    const float* __restrict__ A, const float* __restrict__ Bw,
    float* __restrict__ C, const float* __restrict__ bias,
    int Mr, int Nc, int K, int lda, int ldb, int ldc, int act)
{
    __shared__ float As[16][65];
    __shared__ float Bs[16][65];

    const int tid = threadIdx.x;
    const int tx = tid & 15;
    const int ty = tid >> 4;
    const int col0 = blockIdx.x * 64;
    const int row0 = blockIdx.y * 64;

    const int ak = tid & 15, am = tid >> 4;
    const int bn = tid & 63, bk = tid >> 6;

    float acc[4][4] = {};

    for (int k0 = 0; k0 < K; k0 += 16) {
        #pragma unroll
        for (int q = 0; q < 4; ++q)
            As[ak][am + 16 * q] =
                A[(size_t)(row0 + am + 16 * q) * lda + (k0 + ak)];
        #pragma unroll
        for (int q = 0; q < 4; ++q) {
            int col = col0 + bn;
            Bs[bk + 4 * q][bn] =
                (col < Nc) ? Bw[(size_t)(k0 + bk + 4 * q) * ldb + col] : 0.0f;
        }
        __syncthreads();

        #pragma unroll
        for (int kk = 0; kk < 16; ++kk) {
            float av[4], bv[4];
            #pragma unroll
            for (int i = 0; i < 4; ++i) av[i] = As[kk][ty + 16 * i];
            #pragma unroll
            for (int j = 0; j < 4; ++j) bv[j] = Bs[kk][tx + 16 * j];
            #pragma unroll
            for (int i = 0; i < 4; ++i)
                #pragma unroll
                for (int j = 0; j < 4; ++j)
                    acc[i][j] += av[i] * bv[j];
        }
        __syncthreads();
    }

    #pragma unroll
    for (int i = 0; i < 4; ++i) {
        int row = row0 + ty + 16 * i;
        #pragma unroll
        for (int j = 0; j < 4; ++j) {
            int col = col0 + tx + 16 * j;
            if (col < Nc) {
                float v = acc[i][j];
                if (bias) v += bias[col];
                if (act == 1) v = (v > 20.0f) ? v : log1pf(__expf(v));
                C[(size_t)row * ldc + col] = v;
            }
        }
    }
}

// ---------------------------------------------------------------------------
// Split-K x_proj GEMM: part[kz] = uc[:, kz*256:(kz+1)*256] @ W[kz*256:...,:96]
// Grid (2, M/64, KSPLIT). 64x64 tile (col tile 1 half-guarded), K-chunk 256.
// ---------------------------------------------------------------------------
__global__ __launch_bounds__(256) void xproj_splitk_kernel(
    const float* __restrict__ A,    // uc [8192][2048]
    const float* __restrict__ Bw,   // x_proj_w [2048][96]
    float* __restrict__ part)       // [KSPLIT][8192][96]
{
    __shared__ float As[16][65];
    __shared__ float Bs[16][65];

    const int tid = threadIdx.x;
    const int tx = tid & 15;
    const int ty = tid >> 4;
    const int col0 = blockIdx.x * 64;
    const int row0 = blockIdx.y * 64;
    const int kb   = blockIdx.z * KCH;

    const int ak = tid & 15, am = tid >> 4;
    const int bn = tid & 63, bk = tid >> 6;

    float acc[4][4] = {};

    for (int k0 = kb; k0 < kb + KCH; k0 += 16) {
        #pragma unroll
        for (int q = 0; q < 4; ++q)
            As[ak][am + 16 * q] =
                A[(size_t)(row0 + am + 16 * q) * DINNER + (k0 + ak)];
        #pragma unroll
        for (int q = 0; q < 4; ++q) {
            int col = col0 + bn;
            Bs[bk + 4 * q][bn] =
                (col < 96) ? Bw[(size_t)(k0 + bk + 4 * q) * 96 + col] : 0.0f;
        }
        __syncthreads();

        #pragma unroll
        for (int kk = 0; kk < 16; ++kk) {
            float av[4], bv[4];
            #pragma unroll
            for (int i = 0; i < 4; ++i) av[i] = As[kk][ty + 16 * i];
            #pragma unroll
            for (int j = 0; j < 4; ++j) bv[j] = Bs[kk][tx + 16 * j];
            #pragma unroll
            for (int i = 0; i < 4; ++i)
                #pragma unroll
                for (int j = 0; j < 4; ++j)
                    acc[i][j] += av[i] * bv[j];
        }
        __syncthreads();
    }

    float* pbase = part + (size_t)blockIdx.z * MROWS * 96;
    #pragma unroll
    for (int i = 0; i < 4; ++i) {
        int row = row0 + ty + 16 * i;
        #pragma unroll
        for (int j = 0; j < 4; ++j) {
            int col = col0 + tx + 16 * j;
            if (col < 96)
                pbase[(size_t)row * 96 + col] = acc[i][j];
        }
    }
}

__global__ __launch_bounds__(256) void xproj_reduce_kernel(
    const float* __restrict__ part, float* __restrict__ dbc)
{
    int gid = blockIdx.x * 256 + threadIdx.x;     // over 8192*96
    float s = 0.f;
    #pragma unroll
    for (int k = 0; k < KSPLIT; ++k)
        s += part[(size_t)k * MROWS * 96 + gid];
    dbc[gid] = s;
}

// ---------------------------------------------------------------------------
// Causal depthwise conv1d (width 4) + bias + silu.
// ---------------------------------------------------------------------------
__global__ __launch_bounds__(256) void conv_silu_kernel(
    const float* __restrict__ xz, const float* __restrict__ cw,
    const float* __restrict__ cb, float* __restrict__ uc)
{
    int idx = blockIdx.x * 256 + threadIdx.x;
    int d = idx & (DINNER - 1);
    int row = idx >> 11;
    int t = row & (LSEQ - 1);

    float acc = cb[d];
    #pragma unroll
    for (int k = 0; k < 4; ++k) {
        int tt = t - 3 + k;
        if (tt >= 0)
            acc += xz[(size_t)(row + k - 3) * 4096 + d] * cw[d * 4 + k];
    }
    uc[(size_t)row * DINNER + d] = acc * sigmoidf_(acc);
}

// ---------------------------------------------------------------------------
// Chunked scan, pass A: local end-state E[16] and chunk decay P[n].
// ---------------------------------------------------------------------------
__global__ __launch_bounds__(256) void scan_partial_kernel(
    const float* __restrict__ dtm, const float* __restrict__ um,
    const float* __restrict__ dbc, const float* __restrict__ A_log,
    float* __restrict__ Pbuf, float* __restrict__ Ebuf)
{
    __shared__ float sB[CHUNK][NSTATE];
    const int tid = threadIdx.x;
    const int c = blockIdx.x;
    const int b = blockIdx.z;
    const int d = blockIdx.y * 256 + tid;
    const size_t row0 = (size_t)b * LSEQ + c * CHUNK;

    {
        int s = tid >> 2, f = tid & 3;
        float4 v = *reinterpret_cast<const float4*>(dbc + (row0 + s) * 96 + 64 + f * 4);
        *reinterpret_cast<float4*>(&sB[s][f * 4]) = v;
    }

    float An2[NSTATE];
    #pragma unroll
    for (int k = 0; k < 4; ++k) {
        float4 a = *reinterpret_cast<const float4*>(A_log + (size_t)d * NSTATE + k * 4);
        An2[k*4+0] = -__expf(a.x) * LOG2E;
        An2[k*4+1] = -__expf(a.y) * LOG2E;
        An2[k*4+2] = -__expf(a.z) * LOG2E;
        An2[k*4+3] = -__expf(a.w) * LOG2E;
    }
    __syncthreads();

    float E[NSTATE];
    #pragma unroll
    for (int n = 0; n < NSTATE; ++n) E[n] = 0.f;
    float S = 0.f;

    const float* pdt = dtm + row0 * 4096 + d;
    const float* pu  = um  + row0 * 2048 + d;

    float dtc = pdt[0], ucv = pu[0];
    for (int s = 0; s < CHUNK; ++s) {
        float dtn = 0.f, un = 0.f;
        if (s + 1 < CHUNK) {
            dtn = pdt[(size_t)(s + 1) * 4096];
            un  = pu [(size_t)(s + 1) * 2048];
        }
        S += dtc;
        float du = dtc * ucv;
        float Bv[NSTATE];
        #pragma unroll
        for (int k = 0; k < 4; ++k)
            *reinterpret_cast<float4*>(&Bv[k*4]) =
                *reinterpret_cast<const float4*>(&sB[s][k*4]);
        #pragma unroll
        for (int n = 0; n < NSTATE; ++n) {
            float q = EXP2F(dtc * An2[n]);
            E[n] = fmaf(E[n], q, du * Bv[n]);
        }
        dtc = dtn; ucv = un;
    }

    size_t base = (((size_t)c * BSZ + b) * DINNER + d) * NSTATE;
    #pragma unroll
    for (int n = 0; n < NSTATE; ++n) {
        Pbuf[base + n] = EXP2F(An2[n] * S);
        Ebuf[base + n] = E[n];
    }
}

// ---------------------------------------------------------------------------
// Pass B: exclusive scan over chunks per (b,d,n); h0 written IN PLACE over P.
// ---------------------------------------------------------------------------
__global__ __launch_bounds__(256) void scan_prefix_kernel(
    float* __restrict__ Pbuf, const float* __restrict__ Ebuf)
{
    const int gid = blockIdx.x * 256 + threadIdx.x;
    const size_t stride = (size_t)BSZ * DINNER * NSTATE;
    size_t idx = gid;
    float h = 0.f;
    for (int c = 0; c < NCHUNK; ++c) {
        float P = Pbuf[idx];
        float Ev = Ebuf[idx];
        Pbuf[idx] = h;
        h = fmaf(P, h, Ev);
        idx += stride;
    }
}

// ---------------------------------------------------------------------------
// Pass C: re-run local scan seeded with h0; fuse y, skip, gate; write over uc.
// ---------------------------------------------------------------------------
__global__ __launch_bounds__(256) void scan_final_kernel(
    const float* __restrict__ xzm, float* __restrict__ um,
    const float* __restrict__ dbc,
    const float* __restrict__ A_log, const float* __restrict__ Dp,
    const float* __restrict__ H0)
{
    __shared__ float sBC[CHUNK][2 * NSTATE];
    const int tid = threadIdx.x;
    const int c = blockIdx.x;
    const int b = blockIdx.z;
    const int d = blockIdx.y * 256 + tid;
    const size_t row0 = (size_t)b * LSEQ + c * CHUNK;

    {
        #pragma unroll
        for (int i = 0; i < 2; ++i) {
            int j = tid * 2 + i;
            int s = j >> 3, f = j & 7;
            float4 v = *reinterpret_cast<const float4*>(dbc + (row0 + s) * 96 + 64 + f * 4);
            *reinterpret_cast<float4*>(&sBC[s][f * 4]) = v;
        }
    }

    float An2[NSTATE];
    #pragma unroll
    for (int k = 0; k < 4; ++k) {
        float4 a = *reinterpret_cast<const float4*>(A_log + (size_t)d * NSTATE + k * 4);
        An2[k*4+0] = -__expf(a.x) * LOG2E;
        An2[k*4+1] = -__expf(a.y) * LOG2E;
        An2[k*4+2] = -__expf(a.z) * LOG2E;
        An2[k*4+3] = -__expf(a.w) * LOG2E;
    }
    const float Dpd = Dp[d];

    float h[NSTATE];
    {
        size_t base = (((size_t)c * BSZ + b) * DINNER + d) * NSTATE;
        #pragma unroll
        for (int n = 0; n < NSTATE; ++n) h[n] = H0[base + n];
    }
    __syncthreads();

    const float* pdt = xzm + row0 * 4096 + d;
    const float* pz  = xzm + row0 * 4096 + 2048 + d;
    float* py        = um  + row0 * 2048 + d;

    float dtc = pdt[0], ucv = py[0], zc = pz[0];
    for (int s = 0; s < CHUNK; ++s) {
        float dtn = 0.f, un = 0.f, zn = 0.f;
        if (s + 1 < CHUNK) {
            dtn = pdt[(size_t)(s + 1) * 4096];
            un  = py [(size_t)(s + 1) * 2048];
            zn  = pz [(size_t)(s + 1) * 4096];
        }
        float du = dtc * ucv;
        float Bv[NSTATE], Cv[NSTATE];
        #pragma unroll
        for (int k = 0; k < 4; ++k) {
            *reinterpret_cast<float4*>(&Bv[k*4]) =
                *reinterpret_cast<const float4*>(&sBC[s][k*4]);
            *reinterpret_cast<float4*>(&Cv[k*4]) =
                *reinterpret_cast<const float4*>(&sBC[s][16 + k*4]);
        }
        float y0 = 0.f, y1 = 0.f, y2 = 0.f, y3 = 0.f;
        #pragma unroll
        for (int n = 0; n < NSTATE; ++n) {
            float q = EXP2F(dtc * An2[n]);
            h[n] = fmaf(h[n], q, du * Bv[n]);
            float& yk = (n & 3) == 0 ? y0 : (n & 3) == 1 ? y1 : (n & 3) == 2 ? y2 : y3;
            yk = fmaf(h[n], Cv[n], yk);
        }
        float y = (y0 + y1) + (y2 + y3);
        float yg = (y + ucv * Dpd) * (zc * sigmoidf_(zc));
        py[(size_t)s * 2048] = yg;
        dtc = dtn; ucv = un; zc = zn;
    }
}

// ---------------------------------------------------------------------------
extern "C" void kernel_launch(void* const* d_in, const int* in_sizes, int n_in,
                              void* d_out, int out_size, void* d_ws, size_t ws_size,
                              hipStream_t stream)
{
    const float* x         = (const float*)d_in[0];
    const float* in_proj_w = (const float*)d_in[1];
    const float* conv_w    = (const float*)d_in[2];
    const float* conv_b    = (const float*)d_in[3];
    const float* x_proj_w  = (const float*)d_in[4];
    const float* dt_proj_w = (const float*)d_in[5];
    const float* dt_proj_b = (const float*)d_in[6];
    const float* A_log     = (const float*)d_in[7];
    const float* Dp        = (const float*)d_in[8];
    const float* out_proj_w= (const float*)d_in[9];
    float* out = (float*)d_out;

    // Workspace: 128 + 64 + 3 + 8 + 4 + 33.5 = 239 MiB (budget ~256 MiB).
    // xproj split-K partials (24 MiB) overlay Pbuf/Ebuf (dead until scan).
    float* ws  = (float*)d_ws;
    float* xz  = ws;                                  // [8192][4096] (u->dt | z)
    float* uc  = xz  + (size_t)MROWS * 4096;          // [8192][2048] (conv -> gated y)
    float* dbc = uc  + (size_t)MROWS * 2048;          // [8192][96]
    unsigned short* wT_in  = (unsigned short*)(dbc + (size_t)MROWS * 96);
    unsigned short* wT_out = wT_in + (size_t)4096 * 1024;
    float* Pbuf = (float*)(wT_out + (size_t)1024 * 2048);   // [64][2][2048][16]
    float* Ebuf = Pbuf + (size_t)NCHUNK * BSZ * DINNER * NSTATE;
    float* part = Pbuf;                               // [8][8192][96] overlay

    dim3 blk(256);

    // 0) weight transpose+convert+pre-swizzle
    transpose_swz_kernel<<<dim3(4096 / 64, 1024 / 64), blk, 0, stream>>>(
        in_proj_w, wT_in, 1024, 4096);
    transpose_swz_kernel<<<dim3(1024 / 64, 2048 / 64), blk, 0, stream>>>(
        out_proj_w, wT_out, 2048, 1024);

    // 1) xz = x @ in_proj_w   (bf16 MFMA)
    gemm_bf16_mfma_kernel<<<dim3(4096 / 128, MROWS / 128), blk, 0, stream>>>(
        x, wT_in, xz, MROWS, 4096, 1024, 1024, 4096);

    // 2) uc = silu(causal_conv(u) + conv_b)
    conv_silu_kernel<<<dim3((MROWS * DINNER) / 256), blk, 0, stream>>>(
        xz, conv_w, conv_b, uc);

    // 3) dbc = uc @ x_proj_w  (fp32, split-K over 8 chunks + reduce)
    xproj_splitk_kernel<<<dim3(2, MROWS / 64, KSPLIT), blk, 0, stream>>>(
        uc, x_proj_w, part);
    xproj_reduce_kernel<<<dim3((MROWS * 96) / 256), blk, 0, stream>>>(
        part, dbc);

    // 4) dt = softplus(dbc[:, :64] @ dt_proj_w + dt_proj_b) -> xz u-half
    gemm_f32_kernel<<<dim3(2048 / 64, MROWS / 64), blk, 0, stream>>>(
        dbc, dt_proj_w, xz, dt_proj_b, MROWS, 2048, 64, 96, 2048, 4096, 1);

    // 5) chunked selective scan (3 passes) -> gated y over uc
    scan_partial_kernel<<<dim3(NCHUNK, DINNER / 256, BSZ), blk, 0, stream>>>(
        xz, uc, dbc, A_log, Pbuf, Ebuf);
    scan_prefix_kernel<<<dim3((BSZ * DINNER * NSTATE) / 256), blk, 0, stream>>>(
        Pbuf, Ebuf);
    scan_final_kernel<<<dim3(NCHUNK, DINNER / 256, BSZ), blk, 0, stream>>>(
        xz, uc, dbc, A_log, Dp, Pbuf);

    // 6) out = y_gated @ out_proj_w  (bf16 MFMA)
    gemm_bf16_mfma_kernel<<<dim3(1024 / 128, MROWS / 128), blk, 0, stream>>>(
        uc, wT_out, out, MROWS, 1024, 2048, 2048, 1024);
}

// Round 6
// 557.477 us; speedup vs baseline: 5.8511x; 1.1346x over previous
//
#include <hip/hip_runtime.h>
#include <hip/hip_bf16.h>
#include <math.h>

#define BSZ 2
#define LSEQ 4096
#define DMODEL 1024
#define DINNER 2048
#define NSTATE 16
#define DTRANK 64
#define MROWS (BSZ * LSEQ)   // 8192
#define NCHUNK 64
#define CHUNK (LSEQ / NCHUNK)  // 64
#define KSPLIT 8
#define KCH (DINNER / KSPLIT)  // 256

#if __has_builtin(__builtin_amdgcn_exp2f)
#define EXP2F(x) __builtin_amdgcn_exp2f(x)
#else
#define EXP2F(x) exp2f(x)
#endif
#define LOG2E 1.44269504088896f

typedef __attribute__((ext_vector_type(8))) short bf16x8;
typedef __attribute__((ext_vector_type(4))) float f32x4;

__device__ __forceinline__ float sigmoidf_(float x) { return 1.0f / (1.0f + __expf(-x)); }

__device__ __forceinline__ unsigned short f2bf(float x) {
    unsigned int u = __float_as_uint(x);
    u += 0x7fff + ((u >> 16) & 1);          // round-to-nearest-even
    return (unsigned short)(u >> 16);
}

// ---------------------------------------------------------------------------
// fp32 -> bf16 convert + XOR pre-swizzle, row-major kept.
// Element (m,k) stored at m*K + (k ^ ((m&7)<<3)); XOR touches bits 3..5 only,
// so each 64-elem k-window permutes internally at 8-elem granularity.
// One thread = one 8-elem group (32B read, 16B write).
// ---------------------------------------------------------------------------
__global__ __launch_bounds__(256) void cvt_swz_kernel(
    const float* __restrict__ X, unsigned short* __restrict__ Xb,
    int logGpr)   // groups-per-row = 1<<logGpr ; K = 8<<logGpr
{
    int gid = blockIdx.x * 256 + threadIdx.x;
    int m = gid >> logGpr;
    int g = gid & ((1 << logGpr) - 1);
    int K = 8 << logGpr;
    size_t src = (size_t)m * K + g * 8;
    float4 v0 = *reinterpret_cast<const float4*>(X + src);
    float4 v1 = *reinterpret_cast<const float4*>(X + src + 4);
    unsigned int w0 = (unsigned)f2bf(v0.x) | ((unsigned)f2bf(v0.y) << 16);
    unsigned int w1 = (unsigned)f2bf(v0.z) | ((unsigned)f2bf(v0.w) << 16);
    unsigned int w2 = (unsigned)f2bf(v1.x) | ((unsigned)f2bf(v1.y) << 16);
    unsigned int w3 = (unsigned)f2bf(v1.z) | ((unsigned)f2bf(v1.w) << 16);
    size_t dst = (size_t)m * K + ((g * 8) ^ ((m & 7) << 3));
    uint4 w = {w0, w1, w2, w3};
    *reinterpret_cast<uint4*>(Xb + dst) = w;
}

// ---------------------------------------------------------------------------
// Transpose + fp32->bf16 convert + global XOR pre-swizzle (for MFMA GEMM B).
// ---------------------------------------------------------------------------
__global__ __launch_bounds__(256) void transpose_swz_kernel(
    const float* __restrict__ W, unsigned short* __restrict__ WT, int K, int N)
{
    __shared__ float tile[64][65];
    const int t = threadIdx.x;
    const int n0 = blockIdx.x * 64;
    const int k0 = blockIdx.y * 64;

    #pragma unroll
    for (int i = 0; i < 16; ++i) {
        int flat = i * 256 + t;
        int r = flat >> 6, c = flat & 63;            // r: k, c: n
        tile[r][c] = W[(size_t)(k0 + r) * N + n0 + c];
    }
    __syncthreads();
    #pragma unroll
    for (int i = 0; i < 16; ++i) {
        int flat = i * 256 + t;
        int n = flat >> 6, k = flat & 63;
        int ks = k ^ ((n & 7) << 3);                 // pre-swizzle position
        WT[(size_t)(n0 + n) * K + k0 + ks] = f2bf(tile[k][n]);
    }
}

// ---------------------------------------------------------------------------
// Pure-bf16 MFMA GEMM: C[M,N] fp32 = A @ B. BOTH operands pre-converted,
// pre-swizzled bf16 with K contiguous: Abf[M][K], BT[N][K]. Both staged via
// width-16 global_load_lds (linear dest + pre-swizzled source + swizzled
// read = bank-conflict-free). 128x128 tile, BK=64, 4 waves x 64x64 quadrant.
// ---------------------------------------------------------------------------
__global__ __launch_bounds__(256) void gemm_bf16bb_kernel(
    const unsigned short* __restrict__ Abf, const unsigned short* __restrict__ BT,
    float* __restrict__ C, int M, int N, int K, int ldc)
{
    __shared__ unsigned short lds_a[128 * 64];
    __shared__ unsigned short lds_b[128 * 64];

    const int tid  = threadIdx.x;
    const int lane = tid & 63;
    const int w    = tid >> 6;
    const int wr   = (w >> 1) * 64;
    const int wc   = (w & 1) * 64;
    const int row0 = blockIdx.y * 128;
    const int col0 = blockIdx.x * 128;

    f32x4 acc[4][4];
    #pragma unroll
    for (int m = 0; m < 4; ++m)
        #pragma unroll
        for (int n = 0; n < 4; ++n)
            acc[m][n] = (f32x4){0.f, 0.f, 0.f, 0.f};

    for (int k0 = 0; k0 < K; k0 += 64) {
        #pragma unroll
        for (int j = 0; j < 4; ++j) {
            int c  = (j * 4 + w) * 64 + lane;    // 16B chunk id, 0..1023
            int r  = c >> 3;                     // tile row / col index
            int cc = c & 7;                      // 16B chunk within row
            const char* asrc = (const char*)Abf +
                ((size_t)(row0 + r) * K + k0) * 2 + cc * 16;
            __builtin_amdgcn_global_load_lds(
                (const __attribute__((address_space(1))) void*)asrc,
                (__attribute__((address_space(3))) void*)((char*)lds_a + (j * 4 + w) * 1024),
                16, 0, 0);
            const char* bsrc = (const char*)BT +
                ((size_t)(col0 + r) * K + k0) * 2 + cc * 16;
            __builtin_amdgcn_global_load_lds(
                (const __attribute__((address_space(1))) void*)bsrc,
                (__attribute__((address_space(3))) void*)((char*)lds_b + (j * 4 + w) * 1024),
                16, 0, 0);
        }
        __syncthreads();

        #pragma unroll
        for (int kk = 0; kk < 2; ++kk) {
            bf16x8 af[4], bfr[4];
            #pragma unroll
            for (int m = 0; m < 4; ++m) {
                int r = wr + m * 16 + (lane & 15);
                int byteoff = r * 128 + ((kk * 64 + (lane >> 4) * 16) ^ ((r & 7) << 4));
                af[m] = *reinterpret_cast<const bf16x8*>((const char*)lds_a + byteoff);
            }
            #pragma unroll
            for (int n = 0; n < 4; ++n) {
                int r = wc + n * 16 + (lane & 15);
                int byteoff = r * 128 + ((kk * 64 + (lane >> 4) * 16) ^ ((r & 7) << 4));
                bfr[n] = *reinterpret_cast<const bf16x8*>((const char*)lds_b + byteoff);
            }
            #pragma unroll
            for (int m = 0; m < 4; ++m)
                #pragma unroll
                for (int n = 0; n < 4; ++n)
                    acc[m][n] = __builtin_amdgcn_mfma_f32_16x16x32_bf16(
                        af[m], bfr[n], acc[m][n], 0, 0, 0);
        }
        __syncthreads();
    }

    #pragma unroll
    for (int m = 0; m < 4; ++m) {
        int rbase = row0 + wr + m * 16 + (lane >> 4) * 4;
        #pragma unroll
        for (int n = 0; n < 4; ++n) {
            int col = col0 + wc + n * 16 + (lane & 15);
            #pragma unroll
            for (int r = 0; r < 4; ++r)
                C[(size_t)(rbase + r) * ldc + col] = acc[m][n][r];
        }
    }
}

// ---------------------------------------------------------------------------
// bf16 MFMA GEMM, fp32-A variant (fallback path for out_proj when ws is
// too small for the ybf buffer). A reg-staged fp32->bf16 into swizzled LDS.
// ---------------------------------------------------------------------------
__global__ __launch_bounds__(256) void gemm_bf16_mfma_kernel(
    const float* __restrict__ A, const unsigned short* __restrict__ BT,
    float* __restrict__ C, int M, int N, int K, int lda, int ldc)
{
    __shared__ unsigned short lds_a[128 * 64];
    __shared__ unsigned short lds_b[128 * 64];

    const int tid  = threadIdx.x;
    const int lane = tid & 63;
    const int w    = tid >> 6;
    const int wr   = (w >> 1) * 64;
    const int wc   = (w & 1) * 64;
    const int row0 = blockIdx.y * 128;
    const int col0 = blockIdx.x * 128;

    f32x4 acc[4][4];
    #pragma unroll
    for (int m = 0; m < 4; ++m)
        #pragma unroll
        for (int n = 0; n < 4; ++n)
            acc[m][n] = (f32x4){0.f, 0.f, 0.f, 0.f};

    for (int k0 = 0; k0 < K; k0 += 64) {
        #pragma unroll
        for (int i = 0; i < 8; ++i) {
            int chunk = i * 256 + tid;
            int r  = chunk >> 4;
            int kc = chunk & 15;
            float4 v = *reinterpret_cast<const float4*>(
                A + (size_t)(row0 + r) * lda + k0 + kc * 4);
            unsigned int p0 = (unsigned int)f2bf(v.x) | ((unsigned int)f2bf(v.y) << 16);
            unsigned int p1 = (unsigned int)f2bf(v.z) | ((unsigned int)f2bf(v.w) << 16);
            int byteoff = r * 128 + ((kc * 8) ^ ((r & 7) << 4));
            unsigned int* dst = reinterpret_cast<unsigned int*>((char*)lds_a + byteoff);
            dst[0] = p0; dst[1] = p1;
        }
        #pragma unroll
        for (int j = 0; j < 4; ++j) {
            int c  = (j * 4 + w) * 64 + lane;
            int br = c >> 3;
            int bc = c & 7;
            const char* src = (const char*)BT +
                ((size_t)(col0 + br) * K + k0) * 2 + bc * 16;
            __builtin_amdgcn_global_load_lds(
                (const __attribute__((address_space(1))) void*)src,
                (__attribute__((address_space(3))) void*)((char*)lds_b + (j * 4 + w) * 1024),
                16, 0, 0);
        }
        __syncthreads();

        #pragma unroll
        for (int kk = 0; kk < 2; ++kk) {
            bf16x8 af[4], bfr[4];
            #pragma unroll
            for (int m = 0; m < 4; ++m) {
                int r = wr + m * 16 + (lane & 15);
                int byteoff = r * 128 + ((kk * 64 + (lane >> 4) * 16) ^ ((r & 7) << 4));
                af[m] = *reinterpret_cast<const bf16x8*>((const char*)lds_a + byteoff);
            }
            #pragma unroll
            for (int n = 0; n < 4; ++n) {
                int r = wc + n * 16 + (lane & 15);
                int byteoff = r * 128 + ((kk * 64 + (lane >> 4) * 16) ^ ((r & 7) << 4));
                bfr[n] = *reinterpret_cast<const bf16x8*>((const char*)lds_b + byteoff);
            }
            #pragma unroll
            for (int m = 0; m < 4; ++m)
                #pragma unroll
                for (int n = 0; n < 4; ++n)
                    acc[m][n] = __builtin_amdgcn_mfma_f32_16x16x32_bf16(
                        af[m], bfr[n], acc[m][n], 0, 0, 0);
        }
        __syncthreads();
    }

    #pragma unroll
    for (int m = 0; m < 4; ++m) {
        int rbase = row0 + wr + m * 16 + (lane >> 4) * 4;
        #pragma unroll
        for (int n = 0; n < 4; ++n) {
            int col = col0 + wc + n * 16 + (lane & 15);
            #pragma unroll
            for (int r = 0; r < 4; ++r)
                C[(size_t)(rbase + r) * ldc + col] = acc[m][n][r];
        }
    }
}

// ---------------------------------------------------------------------------
// Generic tiled fp32 GEMM (dt_proj): C = act(A @ B + bias)
// ---------------------------------------------------------------------------
__global__ __launch_bounds__(256) void gemm_f32_kernel(
    const float* __restrict__ A, const float* __restrict__ Bw,
    float* __restrict__ C, const float* __restrict__ bias,
    int Mr, int Nc, int K, int lda, int ldb, int ldc, int act)
{
    __shared__ float As[16][65];
    __shared__ float Bs[16][65];

    const int tid = threadIdx.x;
    const int tx = tid & 15;
    const int ty = tid >> 4;
    const int col0 = blockIdx.x * 64;
    const int row0 = blockIdx.y * 64;

    const int ak = tid & 15, am = tid >> 4;
    const int bn = tid & 63, bk = tid >> 6;

    float acc[4][4] = {};

    for (int k0 = 0; k0 < K; k0 += 16) {
        #pragma unroll
        for (int q = 0; q < 4; ++q)
            As[ak][am + 16 * q] =
                A[(size_t)(row0 + am + 16 * q) * lda + (k0 + ak)];
        #pragma unroll
        for (int q = 0; q < 4; ++q) {
            int col = col0 + bn;
            Bs[bk + 4 * q][bn] =
                (col < Nc) ? Bw[(size_t)(k0 + bk + 4 * q) * ldb + col] : 0.0f;
        }
        __syncthreads();

        #pragma unroll
        for (int kk = 0; kk < 16; ++kk) {
            float av[4], bv[4];
            #pragma unroll
            for (int i = 0; i < 4; ++i) av[i] = As[kk][ty + 16 * i];
            #pragma unroll
            for (int j = 0; j < 4; ++j) bv[j] = Bs[kk][tx + 16 * j];
            #pragma unroll
            for (int i = 0; i < 4; ++i)
                #pragma unroll
                for (int j = 0; j < 4; ++j)
                    acc[i][j] += av[i] * bv[j];
        }
        __syncthreads();
    }

    #pragma unroll
    for (int i = 0; i < 4; ++i) {
        int row = row0 + ty + 16 * i;
        #pragma unroll
        for (int j = 0; j < 4; ++j) {
            int col = col0 + tx + 16 * j;
            if (col < Nc) {
                float v = acc[i][j];
                if (bias) v += bias[col];
                if (act == 1) v = (v > 20.0f) ? v : log1pf(__expf(v));
                C[(size_t)row * ldc + col] = v;
            }
        }
    }
}

// ---------------------------------------------------------------------------
// Split-K x_proj GEMM + reduce.
// ---------------------------------------------------------------------------
__global__ __launch_bounds__(256) void xproj_splitk_kernel(
    const float* __restrict__ A, const float* __restrict__ Bw,
    float* __restrict__ part)
{
    __shared__ float As[16][65];
    __shared__ float Bs[16][65];

    const int tid = threadIdx.x;
    const int tx = tid & 15;
    const int ty = tid >> 4;
    const int col0 = blockIdx.x * 64;
    const int row0 = blockIdx.y * 64;
    const int kb   = blockIdx.z * KCH;

    const int ak = tid & 15, am = tid >> 4;
    const int bn = tid & 63, bk = tid >> 6;

    float acc[4][4] = {};

    for (int k0 = kb; k0 < kb + KCH; k0 += 16) {
        #pragma unroll
        for (int q = 0; q < 4; ++q)
            As[ak][am + 16 * q] =
                A[(size_t)(row0 + am + 16 * q) * DINNER + (k0 + ak)];
        #pragma unroll
        for (int q = 0; q < 4; ++q) {
            int col = col0 + bn;
            Bs[bk + 4 * q][bn] =
                (col < 96) ? Bw[(size_t)(k0 + bk + 4 * q) * 96 + col] : 0.0f;
        }
        __syncthreads();

        #pragma unroll
        for (int kk = 0; kk < 16; ++kk) {
            float av[4], bv[4];
            #pragma unroll
            for (int i = 0; i < 4; ++i) av[i] = As[kk][ty + 16 * i];
            #pragma unroll
            for (int j = 0; j < 4; ++j) bv[j] = Bs[kk][tx + 16 * j];
            #pragma unroll
            for (int i = 0; i < 4; ++i)
                #pragma unroll
                for (int j = 0; j < 4; ++j)
                    acc[i][j] += av[i] * bv[j];
        }
        __syncthreads();
    }

    float* pbase = part + (size_t)blockIdx.z * MROWS * 96;
    #pragma unroll
    for (int i = 0; i < 4; ++i) {
        int row = row0 + ty + 16 * i;
        #pragma unroll
        for (int j = 0; j < 4; ++j) {
            int col = col0 + tx + 16 * j;
            if (col < 96)
                pbase[(size_t)row * 96 + col] = acc[i][j];
        }
    }
}

__global__ __launch_bounds__(256) void xproj_reduce_kernel(
    const float* __restrict__ part, float* __restrict__ dbc)
{
    int gid = blockIdx.x * 256 + threadIdx.x;
    float s = 0.f;
    #pragma unroll
    for (int k = 0; k < KSPLIT; ++k)
        s += part[(size_t)k * MROWS * 96 + gid];
    dbc[gid] = s;
}

// ---------------------------------------------------------------------------
// Causal depthwise conv1d (width 4) + bias + silu.
// ---------------------------------------------------------------------------
__global__ __launch_bounds__(256) void conv_silu_kernel(
    const float* __restrict__ xz, const float* __restrict__ cw,
    const float* __restrict__ cb, float* __restrict__ uc)
{
    int idx = blockIdx.x * 256 + threadIdx.x;
    int d = idx & (DINNER - 1);
    int row = idx >> 11;
    int t = row & (LSEQ - 1);

    float acc = cb[d];
    #pragma unroll
    for (int k = 0; k < 4; ++k) {
        int tt = t - 3 + k;
        if (tt >= 0)
            acc += xz[(size_t)(row + k - 3) * 4096 + d] * cw[d * 4 + k];
    }
    uc[(size_t)row * DINNER + d] = acc * sigmoidf_(acc);
}

// ---------------------------------------------------------------------------
// Chunked scan, pass A: local end-state E[16] and chunk decay P[n].
// ---------------------------------------------------------------------------
__global__ __launch_bounds__(256) void scan_partial_kernel(
    const float* __restrict__ dtm, const float* __restrict__ um,
    const float* __restrict__ dbc, const float* __restrict__ A_log,
    float* __restrict__ Pbuf, float* __restrict__ Ebuf)
{
    __shared__ float sB[CHUNK][NSTATE];
    const int tid = threadIdx.x;
    const int c = blockIdx.x;
    const int b = blockIdx.z;
    const int d = blockIdx.y * 256 + tid;
    const size_t row0 = (size_t)b * LSEQ + c * CHUNK;

    {
        int s = tid >> 2, f = tid & 3;
        float4 v = *reinterpret_cast<const float4*>(dbc + (row0 + s) * 96 + 64 + f * 4);
        *reinterpret_cast<float4*>(&sB[s][f * 4]) = v;
    }

    float An2[NSTATE];
    #pragma unroll
    for (int k = 0; k < 4; ++k) {
        float4 a = *reinterpret_cast<const float4*>(A_log + (size_t)d * NSTATE + k * 4);
        An2[k*4+0] = -__expf(a.x) * LOG2E;
        An2[k*4+1] = -__expf(a.y) * LOG2E;
        An2[k*4+2] = -__expf(a.z) * LOG2E;
        An2[k*4+3] = -__expf(a.w) * LOG2E;
    }
    __syncthreads();

    float E[NSTATE];
    #pragma unroll
    for (int n = 0; n < NSTATE; ++n) E[n] = 0.f;
    float S = 0.f;

    const float* pdt = dtm + row0 * 4096 + d;
    const float* pu  = um  + row0 * 2048 + d;

    float dtc = pdt[0], ucv = pu[0];
    for (int s = 0; s < CHUNK; ++s) {
        float dtn = 0.f, un = 0.f;
        if (s + 1 < CHUNK) {
            dtn = pdt[(size_t)(s + 1) * 4096];
            un  = pu [(size_t)(s + 1) * 2048];
        }
        S += dtc;
        float du = dtc * ucv;
        float Bv[NSTATE];
        #pragma unroll
        for (int k = 0; k < 4; ++k)
            *reinterpret_cast<float4*>(&Bv[k*4]) =
                *reinterpret_cast<const float4*>(&sB[s][k*4]);
        #pragma unroll
        for (int n = 0; n < NSTATE; ++n) {
            float q = EXP2F(dtc * An2[n]);
            E[n] = fmaf(E[n], q, du * Bv[n]);
        }
        dtc = dtn; ucv = un;
    }

    size_t base = (((size_t)c * BSZ + b) * DINNER + d) * NSTATE;
    #pragma unroll
    for (int n = 0; n < NSTATE; ++n) {
        Pbuf[base + n] = EXP2F(An2[n] * S);
        Ebuf[base + n] = E[n];
    }
}

// ---------------------------------------------------------------------------
// Pass B: exclusive scan over chunks per (b,d,n); h0 written IN PLACE over P.
// ---------------------------------------------------------------------------
__global__ __launch_bounds__(256) void scan_prefix_kernel(
    float* __restrict__ Pbuf, const float* __restrict__ Ebuf)
{
    const int gid = blockIdx.x * 256 + threadIdx.x;
    const size_t stride = (size_t)BSZ * DINNER * NSTATE;
    size_t idx = gid;
    float h = 0.f;
    for (int c = 0; c < NCHUNK; ++c) {
        float P = Pbuf[idx];
        float Ev = Ebuf[idx];
        Pbuf[idx] = h;
        h = fmaf(P, h, Ev);
        idx += stride;
    }
}

// ---------------------------------------------------------------------------
// Pass C: local scan seeded with h0; fuse y, skip, gate.
// writeBf=1: emit pre-swizzled bf16 into ybf (for pure-bf16 out_proj);
// writeBf=0: fp32 in-place over uc (fallback).
// ---------------------------------------------------------------------------
__global__ __launch_bounds__(256) void scan_final_kernel(
    const float* __restrict__ xzm, float* __restrict__ um,
    const float* __restrict__ dbc,
    const float* __restrict__ A_log, const float* __restrict__ Dp,
    const float* __restrict__ H0,
    unsigned short* __restrict__ ybf, int writeBf)
{
    __shared__ float sBC[CHUNK][2 * NSTATE];
    const int tid = threadIdx.x;
    const int c = blockIdx.x;
    const int b = blockIdx.z;
    const int d = blockIdx.y * 256 + tid;
    const size_t row0 = (size_t)b * LSEQ + c * CHUNK;

    {
        #pragma unroll
        for (int i = 0; i < 2; ++i) {
            int j = tid * 2 + i;
            int s = j >> 3, f = j & 7;
            float4 v = *reinterpret_cast<const float4*>(dbc + (row0 + s) * 96 + 64 + f * 4);
            *reinterpret_cast<float4*>(&sBC[s][f * 4]) = v;
        }
    }

    float An2[NSTATE];
    #pragma unroll
    for (int k = 0; k < 4; ++k) {
        float4 a = *reinterpret_cast<const float4*>(A_log + (size_t)d * NSTATE + k * 4);
        An2[k*4+0] = -__expf(a.x) * LOG2E;
        An2[k*4+1] = -__expf(a.y) * LOG2E;
        An2[k*4+2] = -__expf(a.z) * LOG2E;
        An2[k*4+3] = -__expf(a.w) * LOG2E;
    }
    const float Dpd = Dp[d];

    float h[NSTATE];
    {
        size_t base = (((size_t)c * BSZ + b) * DINNER + d) * NSTATE;
        #pragma unroll
        for (int n = 0; n < NSTATE; ++n) h[n] = H0[base + n];
    }
    __syncthreads();

    const float* pdt = xzm + row0 * 4096 + d;
    const float* pz  = xzm + row0 * 4096 + 2048 + d;
    float* py        = um  + row0 * 2048 + d;

    float dtc = pdt[0], ucv = py[0], zc = pz[0];
    for (int s = 0; s < CHUNK; ++s) {
        float dtn = 0.f, un = 0.f, zn = 0.f;
        if (s + 1 < CHUNK) {
            dtn = pdt[(size_t)(s + 1) * 4096];
            un  = py [(size_t)(s + 1) * 2048];
            zn  = pz [(size_t)(s + 1) * 4096];
        }
        float du = dtc * ucv;
        float Bv[NSTATE], Cv[NSTATE];
        #pragma unroll
        for (int k = 0; k < 4; ++k) {
            *reinterpret_cast<float4*>(&Bv[k*4]) =
                *reinterpret_cast<const float4*>(&sBC[s][k*4]);
            *reinterpret_cast<float4*>(&Cv[k*4]) =
                *reinterpret_cast<const float4*>(&sBC[s][16 + k*4]);
        }
        float y0 = 0.f, y1 = 0.f, y2 = 0.f, y3 = 0.f;
        #pragma unroll
        for (int n = 0; n < NSTATE; ++n) {
            float q = EXP2F(dtc * An2[n]);
            h[n] = fmaf(h[n], q, du * Bv[n]);
            float& yk = (n & 3) == 0 ? y0 : (n & 3) == 1 ? y1 : (n & 3) == 2 ? y2 : y3;
            yk = fmaf(h[n], Cv[n], yk);
        }
        float y = (y0 + y1) + (y2 + y3);
        float yg = (y + ucv * Dpd) * (zc * sigmoidf_(zc));
        if (writeBf) {
            // pre-swizzled bf16: element (row, d) at row*DINNER + (d ^ ((row&7)<<3))
            ybf[(row0 + s) * DINNER + (d ^ ((s & 7) << 3))] = f2bf(yg);
        } else {
            py[(size_t)s * 2048] = yg;
        }
        dtc = dtn; ucv = un; zc = zn;
    }
}

// ---------------------------------------------------------------------------
extern "C" void kernel_launch(void* const* d_in, const int* in_sizes, int n_in,
                              void* d_out, int out_size, void* d_ws, size_t ws_size,
                              hipStream_t stream)
{
    const float* x         = (const float*)d_in[0];
    const float* in_proj_w = (const float*)d_in[1];
    const float* conv_w    = (const float*)d_in[2];
    const float* conv_b    = (const float*)d_in[3];
    const float* x_proj_w  = (const float*)d_in[4];
    const float* dt_proj_w = (const float*)d_in[5];
    const float* dt_proj_b = (const float*)d_in[6];
    const float* A_log     = (const float*)d_in[7];
    const float* Dp        = (const float*)d_in[8];
    const float* out_proj_w= (const float*)d_in[9];
    float* out = (float*)d_out;

    // Fixed regions: xz 128 | uc 64 | dbc 3 | wT_in 8 | wT_out 4 = 207 MiB.
    // Union region U (lifetime-disjoint overlays):
    //   xbf  = U+0  (16 MiB)   live: cvt .. in_proj
    //   part = U+0  (24 MiB)   live: xproj splitk .. reduce
    //   Pbuf = U+0  (16 MiB)   live: scan A .. scan C
    //   Ebuf = U+16 (16 MiB)   live: scan A .. prefix
    //   ybf  = U+16 (32 MiB)   live: scan C .. out_proj   [full path only]
    // Full path: U = 48 MiB -> 255 MiB total. Fallback: U = 32 MiB -> 239 MiB.
    char* base = (char*)d_ws;
    float* xz  = (float*)base;
    float* uc  = (float*)(base + (128ull << 20));
    float* dbc = (float*)(base + (192ull << 20));
    unsigned short* wT_in  = (unsigned short*)(base + (195ull << 20));
    unsigned short* wT_out = (unsigned short*)(base + (203ull << 20));
    char* U = base + (207ull << 20);
    unsigned short* xbf = (unsigned short*)U;
    float* part = (float*)U;
    float* Pbuf = (float*)U;
    float* Ebuf = (float*)(U + (16ull << 20));
    unsigned short* ybf = (unsigned short*)(U + (16ull << 20));

    const int full = (ws_size >= (255ull << 20)) ? 1 : 0;

    dim3 blk(256);

    // 0) operand prep: x -> bf16 pre-swizzled; weights transpose+cvt+swizzle
    cvt_swz_kernel<<<dim3((MROWS * DMODEL / 8) / 256), blk, 0, stream>>>(
        x, xbf, 7);   // K=1024 -> 128 groups/row
    transpose_swz_kernel<<<dim3(4096 / 64, 1024 / 64), blk, 0, stream>>>(
        in_proj_w, wT_in, 1024, 4096);
    transpose_swz_kernel<<<dim3(1024 / 64, 2048 / 64), blk, 0, stream>>>(
        out_proj_w, wT_out, 2048, 1024);

    // 1) xz = x @ in_proj_w   (pure-bf16 MFMA)
    gemm_bf16bb_kernel<<<dim3(4096 / 128, MROWS / 128), blk, 0, stream>>>(
        xbf, wT_in, xz, MROWS, 4096, 1024, 4096);

    // 2) uc = silu(causal_conv(u) + conv_b)
    conv_silu_kernel<<<dim3((MROWS * DINNER) / 256), blk, 0, stream>>>(
        xz, conv_w, conv_b, uc);

    // 3) dbc = uc @ x_proj_w  (fp32 split-K + reduce)
    xproj_splitk_kernel<<<dim3(2, MROWS / 64, KSPLIT), blk, 0, stream>>>(
        uc, x_proj_w, part);
    xproj_reduce_kernel<<<dim3((MROWS * 96) / 256), blk, 0, stream>>>(
        part, dbc);

    // 4) dt = softplus(dbc[:, :64] @ dt_proj_w + dt_proj_b) -> xz u-half
    gemm_f32_kernel<<<dim3(2048 / 64, MROWS / 64), blk, 0, stream>>>(
        dbc, dt_proj_w, xz, dt_proj_b, MROWS, 2048, 64, 96, 2048, 4096, 1);

    // 5) chunked selective scan (3 passes)
    scan_partial_kernel<<<dim3(NCHUNK, DINNER / 256, BSZ), blk, 0, stream>>>(
        xz, uc, dbc, A_log, Pbuf, Ebuf);
    scan_prefix_kernel<<<dim3((BSZ * DINNER * NSTATE) / 256), blk, 0, stream>>>(
        Pbuf, Ebuf);
    scan_final_kernel<<<dim3(NCHUNK, DINNER / 256, BSZ), blk, 0, stream>>>(
        xz, uc, dbc, A_log, Dp, Pbuf, ybf, full);

    // 6) out = y_gated @ out_proj_w
    if (full) {
        gemm_bf16bb_kernel<<<dim3(1024 / 128, MROWS / 128), blk, 0, stream>>>(
            ybf, wT_out, out, MROWS, 1024, 2048, 1024);
    } else {
        gemm_bf16_mfma_kernel<<<dim3(1024 / 128, MROWS / 128), blk, 0, stream>>>(
            uc, wT_out, out, MROWS, 1024, 2048, 2048, 1024);
    }
}

// Round 7
// 472.259 us; speedup vs baseline: 6.9069x; 1.1804x over previous
//
#include <hip/hip_runtime.h>
#include <hip/hip_bf16.h>
#include <math.h>

#define BSZ 2
#define LSEQ 4096
#define DMODEL 1024
#define DINNER 2048
#define NSTATE 16
#define DTRANK 64
#define MROWS (BSZ * LSEQ)   // 8192
#define NCHUNK 64
#define CHUNK (LSEQ / NCHUNK)  // 64
#define KSPLIT 8
#define KCH (DINNER / KSPLIT)  // 256  (fp32 fallback split-K)
#define XKS 4
#define XKCH (DINNER / XKS)    // 512  (MFMA split-K)

#if __has_builtin(__builtin_amdgcn_exp2f)
#define EXP2F(x) __builtin_amdgcn_exp2f(x)
#else
#define EXP2F(x) exp2f(x)
#endif
#define LOG2E 1.44269504088896f

typedef __attribute__((ext_vector_type(8))) short bf16x8;
typedef __attribute__((ext_vector_type(4))) float f32x4;

__device__ __forceinline__ float sigmoidf_(float x) { return 1.0f / (1.0f + __expf(-x)); }

__device__ __forceinline__ unsigned short f2bf(float x) {
    unsigned int u = __float_as_uint(x);
    u += 0x7fff + ((u >> 16) & 1);          // round-to-nearest-even
    return (unsigned short)(u >> 16);
}

// ---------------------------------------------------------------------------
// fp32 -> bf16 convert + XOR pre-swizzle, row-major kept.
// Element (m,k) stored at m*K + (k ^ ((m&7)<<3)).
// ---------------------------------------------------------------------------
__global__ __launch_bounds__(256) void cvt_swz_kernel(
    const float* __restrict__ X, unsigned short* __restrict__ Xb,
    int logGpr)
{
    int gid = blockIdx.x * 256 + threadIdx.x;
    int m = gid >> logGpr;
    int g = gid & ((1 << logGpr) - 1);
    int K = 8 << logGpr;
    size_t src = (size_t)m * K + g * 8;
    float4 v0 = *reinterpret_cast<const float4*>(X + src);
    float4 v1 = *reinterpret_cast<const float4*>(X + src + 4);
    unsigned int w0 = (unsigned)f2bf(v0.x) | ((unsigned)f2bf(v0.y) << 16);
    unsigned int w1 = (unsigned)f2bf(v0.z) | ((unsigned)f2bf(v0.w) << 16);
    unsigned int w2 = (unsigned)f2bf(v1.x) | ((unsigned)f2bf(v1.y) << 16);
    unsigned int w3 = (unsigned)f2bf(v1.z) | ((unsigned)f2bf(v1.w) << 16);
    size_t dst = (size_t)m * K + ((g * 8) ^ ((m & 7) << 3));
    uint4 w = {w0, w1, w2, w3};
    *reinterpret_cast<uint4*>(Xb + dst) = w;
}

// ---------------------------------------------------------------------------
// Transpose + fp32->bf16 convert + XOR pre-swizzle. W [K][Nsrc] -> WT [Npad][K]
// where Npad = gridDim.x*64 (zero-padded rows beyond Nsrc). K % 64 == 0.
// ---------------------------------------------------------------------------
__global__ __launch_bounds__(256) void transpose_swz_kernel(
    const float* __restrict__ W, unsigned short* __restrict__ WT, int K, int Nsrc)
{
    __shared__ float tile[64][65];
    const int t = threadIdx.x;
    const int n0 = blockIdx.x * 64;
    const int k0 = blockIdx.y * 64;

    #pragma unroll
    for (int i = 0; i < 16; ++i) {
        int flat = i * 256 + t;
        int r = flat >> 6, c = flat & 63;            // r: k, c: n
        tile[r][c] = (n0 + c < Nsrc) ? W[(size_t)(k0 + r) * Nsrc + n0 + c] : 0.0f;
    }
    __syncthreads();
    #pragma unroll
    for (int i = 0; i < 16; ++i) {
        int flat = i * 256 + t;
        int n = flat >> 6, k = flat & 63;
        int ks = k ^ ((n & 7) << 3);
        WT[(size_t)(n0 + n) * K + k0 + ks] = f2bf(tile[k][n]);
    }
}

// ---------------------------------------------------------------------------
// Pure-bf16 MFMA GEMM: both operands pre-swizzled bf16, K contiguous.
// Both staged via width-16 global_load_lds. 128x128 tile, BK=64.
// ---------------------------------------------------------------------------
__global__ __launch_bounds__(256) void gemm_bf16bb_kernel(
    const unsigned short* __restrict__ Abf, const unsigned short* __restrict__ BT,
    float* __restrict__ C, int M, int N, int K, int ldc)
{
    __shared__ unsigned short lds_a[128 * 64];
    __shared__ unsigned short lds_b[128 * 64];

    const int tid  = threadIdx.x;
    const int lane = tid & 63;
    const int w    = tid >> 6;
    const int wr   = (w >> 1) * 64;
    const int wc   = (w & 1) * 64;
    const int row0 = blockIdx.y * 128;
    const int col0 = blockIdx.x * 128;

    f32x4 acc[4][4];
    #pragma unroll
    for (int m = 0; m < 4; ++m)
        #pragma unroll
        for (int n = 0; n < 4; ++n)
            acc[m][n] = (f32x4){0.f, 0.f, 0.f, 0.f};

    for (int k0 = 0; k0 < K; k0 += 64) {
        #pragma unroll
        for (int j = 0; j < 4; ++j) {
            int c  = (j * 4 + w) * 64 + lane;
            int r  = c >> 3;
            int cc = c & 7;
            const char* asrc = (const char*)Abf +
                ((size_t)(row0 + r) * K + k0) * 2 + cc * 16;
            __builtin_amdgcn_global_load_lds(
                (const __attribute__((address_space(1))) void*)asrc,
                (__attribute__((address_space(3))) void*)((char*)lds_a + (j * 4 + w) * 1024),
                16, 0, 0);
            const char* bsrc = (const char*)BT +
                ((size_t)(col0 + r) * K + k0) * 2 + cc * 16;
            __builtin_amdgcn_global_load_lds(
                (const __attribute__((address_space(1))) void*)bsrc,
                (__attribute__((address_space(3))) void*)((char*)lds_b + (j * 4 + w) * 1024),
                16, 0, 0);
        }
        __syncthreads();

        #pragma unroll
        for (int kk = 0; kk < 2; ++kk) {
            bf16x8 af[4], bfr[4];
            #pragma unroll
            for (int m = 0; m < 4; ++m) {
                int r = wr + m * 16 + (lane & 15);
                int byteoff = r * 128 + ((kk * 64 + (lane >> 4) * 16) ^ ((r & 7) << 4));
                af[m] = *reinterpret_cast<const bf16x8*>((const char*)lds_a + byteoff);
            }
            #pragma unroll
            for (int n = 0; n < 4; ++n) {
                int r = wc + n * 16 + (lane & 15);
                int byteoff = r * 128 + ((kk * 64 + (lane >> 4) * 16) ^ ((r & 7) << 4));
                bfr[n] = *reinterpret_cast<const bf16x8*>((const char*)lds_b + byteoff);
            }
            #pragma unroll
            for (int m = 0; m < 4; ++m)
                #pragma unroll
                for (int n = 0; n < 4; ++n)
                    acc[m][n] = __builtin_amdgcn_mfma_f32_16x16x32_bf16(
                        af[m], bfr[n], acc[m][n], 0, 0, 0);
        }
        __syncthreads();
    }

    #pragma unroll
    for (int m = 0; m < 4; ++m) {
        int rbase = row0 + wr + m * 16 + (lane >> 4) * 4;
        #pragma unroll
        for (int n = 0; n < 4; ++n) {
            int col = col0 + wc + n * 16 + (lane & 15);
            #pragma unroll
            for (int r = 0; r < 4; ++r)
                C[(size_t)(rbase + r) * ldc + col] = acc[m][n][r];
        }
    }
}

// ---------------------------------------------------------------------------
// MFMA split-K x_proj: part[z] = ucbf[:, z*512:(z+1)*512] @ wXT^T (N=96 of 128)
// Grid (1, M/128, XKS). fp32 partials [XKS][MROWS][96].
// ---------------------------------------------------------------------------
__global__ __launch_bounds__(256) void xproj_splitk_bb_kernel(
    const unsigned short* __restrict__ Abf, const unsigned short* __restrict__ BT,
    float* __restrict__ part)
{
    __shared__ unsigned short lds_a[128 * 64];
    __shared__ unsigned short lds_b[128 * 64];

    const int tid  = threadIdx.x;
    const int lane = tid & 63;
    const int w    = tid >> 6;
    const int wr   = (w >> 1) * 64;
    const int wc   = (w & 1) * 64;
    const int row0 = blockIdx.y * 128;
    const int kb   = blockIdx.z * XKCH;
    const int K    = DINNER;

    f32x4 acc[4][4];
    #pragma unroll
    for (int m = 0; m < 4; ++m)
        #pragma unroll
        for (int n = 0; n < 4; ++n)
            acc[m][n] = (f32x4){0.f, 0.f, 0.f, 0.f};

    for (int k0 = kb; k0 < kb + XKCH; k0 += 64) {
        #pragma unroll
        for (int j = 0; j < 4; ++j) {
            int c  = (j * 4 + w) * 64 + lane;
            int r  = c >> 3;
            int cc = c & 7;
            const char* asrc = (const char*)Abf +
                ((size_t)(row0 + r) * K + k0) * 2 + cc * 16;
            __builtin_amdgcn_global_load_lds(
                (const __attribute__((address_space(1))) void*)asrc,
                (__attribute__((address_space(3))) void*)((char*)lds_a + (j * 4 + w) * 1024),
                16, 0, 0);
            const char* bsrc = (const char*)BT +
                ((size_t)r * K + k0) * 2 + cc * 16;
            __builtin_amdgcn_global_load_lds(
                (const __attribute__((address_space(1))) void*)bsrc,
                (__attribute__((address_space(3))) void*)((char*)lds_b + (j * 4 + w) * 1024),
                16, 0, 0);
        }
        __syncthreads();

        #pragma unroll
        for (int kk = 0; kk < 2; ++kk) {
            bf16x8 af[4], bfr[4];
            #pragma unroll
            for (int m = 0; m < 4; ++m) {
                int r = wr + m * 16 + (lane & 15);
                int byteoff = r * 128 + ((kk * 64 + (lane >> 4) * 16) ^ ((r & 7) << 4));
                af[m] = *reinterpret_cast<const bf16x8*>((const char*)lds_a + byteoff);
            }
            #pragma unroll
            for (int n = 0; n < 4; ++n) {
                int r = wc + n * 16 + (lane & 15);
                int byteoff = r * 128 + ((kk * 64 + (lane >> 4) * 16) ^ ((r & 7) << 4));
                bfr[n] = *reinterpret_cast<const bf16x8*>((const char*)lds_b + byteoff);
            }
            #pragma unroll
            for (int m = 0; m < 4; ++m)
                #pragma unroll
                for (int n = 0; n < 4; ++n)
                    acc[m][n] = __builtin_amdgcn_mfma_f32_16x16x32_bf16(
                        af[m], bfr[n], acc[m][n], 0, 0, 0);
        }
        __syncthreads();
    }

    float* pbase = part + (size_t)blockIdx.z * MROWS * 96;
    #pragma unroll
    for (int m = 0; m < 4; ++m) {
        int rbase = row0 + wr + m * 16 + (lane >> 4) * 4;
        #pragma unroll
        for (int n = 0; n < 4; ++n) {
            int col = wc + n * 16 + (lane & 15);
            if (col < 96) {
                #pragma unroll
                for (int r = 0; r < 4; ++r)
                    pbase[(size_t)(rbase + r) * 96 + col] = acc[m][n][r];
            }
        }
    }
}

// Reduce XKS partials -> dbc fp32; cols<64 also emitted as pre-swizzled bf16.
__global__ __launch_bounds__(256) void xproj_reduce4_kernel(
    const float* __restrict__ part, float* __restrict__ dbc,
    unsigned short* __restrict__ dtlo)
{
    int gid = blockIdx.x * 256 + threadIdx.x;
    float s = 0.f;
    #pragma unroll
    for (int k = 0; k < XKS; ++k)
        s += part[(size_t)k * MROWS * 96 + gid];
    dbc[gid] = s;
    int row = gid / 96;
    int col = gid - row * 96;
    if (col < 64)
        dtlo[(size_t)row * 64 + (col ^ ((row & 7) << 3))] = f2bf(s);
}

// ---------------------------------------------------------------------------
// dt_proj MFMA (K=64, one K-step): dt = softplus(dtlo @ wDT^T + bias) -> xz.
// ---------------------------------------------------------------------------
__global__ __launch_bounds__(256) void gemm_dtproj_bb_kernel(
    const unsigned short* __restrict__ Abf, const unsigned short* __restrict__ BT,
    const float* __restrict__ bias, float* __restrict__ C)
{
    __shared__ unsigned short lds_a[128 * 64];
    __shared__ unsigned short lds_b[128 * 64];

    const int tid  = threadIdx.x;
    const int lane = tid & 63;
    const int w    = tid >> 6;
    const int wr   = (w >> 1) * 64;
    const int wc   = (w & 1) * 64;
    const int row0 = blockIdx.y * 128;
    const int col0 = blockIdx.x * 128;

    f32x4 acc[4][4];
    #pragma unroll
    for (int m = 0; m < 4; ++m)
        #pragma unroll
        for (int n = 0; n < 4; ++n)
            acc[m][n] = (f32x4){0.f, 0.f, 0.f, 0.f};

    #pragma unroll
    for (int j = 0; j < 4; ++j) {
        int c  = (j * 4 + w) * 64 + lane;
        int r  = c >> 3;
        int cc = c & 7;
        const char* asrc = (const char*)Abf + ((size_t)(row0 + r) * 64) * 2 + cc * 16;
        __builtin_amdgcn_global_load_lds(
            (const __attribute__((address_space(1))) void*)asrc,
            (__attribute__((address_space(3))) void*)((char*)lds_a + (j * 4 + w) * 1024),
            16, 0, 0);
        const char* bsrc = (const char*)BT + ((size_t)(col0 + r) * 64) * 2 + cc * 16;
        __builtin_amdgcn_global_load_lds(
            (const __attribute__((address_space(1))) void*)bsrc,
            (__attribute__((address_space(3))) void*)((char*)lds_b + (j * 4 + w) * 1024),
            16, 0, 0);
    }
    __syncthreads();

    #pragma unroll
    for (int kk = 0; kk < 2; ++kk) {
        bf16x8 af[4], bfr[4];
        #pragma unroll
        for (int m = 0; m < 4; ++m) {
            int r = wr + m * 16 + (lane & 15);
            int byteoff = r * 128 + ((kk * 64 + (lane >> 4) * 16) ^ ((r & 7) << 4));
            af[m] = *reinterpret_cast<const bf16x8*>((const char*)lds_a + byteoff);
        }
        #pragma unroll
        for (int n = 0; n < 4; ++n) {
            int r = wc + n * 16 + (lane & 15);
            int byteoff = r * 128 + ((kk * 64 + (lane >> 4) * 16) ^ ((r & 7) << 4));
            bfr[n] = *reinterpret_cast<const bf16x8*>((const char*)lds_b + byteoff);
        }
        #pragma unroll
        for (int m = 0; m < 4; ++m)
            #pragma unroll
            for (int n = 0; n < 4; ++n)
                acc[m][n] = __builtin_amdgcn_mfma_f32_16x16x32_bf16(
                    af[m], bfr[n], acc[m][n], 0, 0, 0);
    }

    #pragma unroll
    for (int m = 0; m < 4; ++m) {
        int rbase = row0 + wr + m * 16 + (lane >> 4) * 4;
        #pragma unroll
        for (int n = 0; n < 4; ++n) {
            int col = col0 + wc + n * 16 + (lane & 15);
            float bv = bias[col];
            #pragma unroll
            for (int r = 0; r < 4; ++r) {
                float v = acc[m][n][r] + bv;
                v = (v > 20.0f) ? v : log1pf(__expf(v));
                C[(size_t)(rbase + r) * 4096 + col] = v;
            }
        }
    }
}

// ---------------------------------------------------------------------------
// Fallback kernels (fp32 x_proj split-K, fp32 dt GEMM, fp32-A MFMA GEMM)
// ---------------------------------------------------------------------------
__global__ __launch_bounds__(256) void gemm_bf16_mfma_kernel(
    const float* __restrict__ A, const unsigned short* __restrict__ BT,
    float* __restrict__ C, int M, int N, int K, int lda, int ldc)
{
    __shared__ unsigned short lds_a[128 * 64];
    __shared__ unsigned short lds_b[128 * 64];

    const int tid  = threadIdx.x;
    const int lane = tid & 63;
    const int w    = tid >> 6;
    const int wr   = (w >> 1) * 64;
    const int wc   = (w & 1) * 64;
    const int row0 = blockIdx.y * 128;
    const int col0 = blockIdx.x * 128;

    f32x4 acc[4][4];
    #pragma unroll
    for (int m = 0; m < 4; ++m)
        #pragma unroll
        for (int n = 0; n < 4; ++n)
            acc[m][n] = (f32x4){0.f, 0.f, 0.f, 0.f};

    for (int k0 = 0; k0 < K; k0 += 64) {
        #pragma unroll
        for (int i = 0; i < 8; ++i) {
            int chunk = i * 256 + tid;
            int r  = chunk >> 4;
            int kc = chunk & 15;
            float4 v = *reinterpret_cast<const float4*>(
                A + (size_t)(row0 + r) * lda + k0 + kc * 4);
            unsigned int p0 = (unsigned int)f2bf(v.x) | ((unsigned int)f2bf(v.y) << 16);
            unsigned int p1 = (unsigned int)f2bf(v.z) | ((unsigned int)f2bf(v.w) << 16);
            int byteoff = r * 128 + ((kc * 8) ^ ((r & 7) << 4));
            unsigned int* dst = reinterpret_cast<unsigned int*>((char*)lds_a + byteoff);
            dst[0] = p0; dst[1] = p1;
        }
        #pragma unroll
        for (int j = 0; j < 4; ++j) {
            int c  = (j * 4 + w) * 64 + lane;
            int br = c >> 3;
            int bc = c & 7;
            const char* src = (const char*)BT +
                ((size_t)(col0 + br) * K + k0) * 2 + bc * 16;
            __builtin_amdgcn_global_load_lds(
                (const __attribute__((address_space(1))) void*)src,
                (__attribute__((address_space(3))) void*)((char*)lds_b + (j * 4 + w) * 1024),
                16, 0, 0);
        }
        __syncthreads();

        #pragma unroll
        for (int kk = 0; kk < 2; ++kk) {
            bf16x8 af[4], bfr[4];
            #pragma unroll
            for (int m = 0; m < 4; ++m) {
                int r = wr + m * 16 + (lane & 15);
                int byteoff = r * 128 + ((kk * 64 + (lane >> 4) * 16) ^ ((r & 7) << 4));
                af[m] = *reinterpret_cast<const bf16x8*>((const char*)lds_a + byteoff);
            }
            #pragma unroll
            for (int n = 0; n < 4; ++n) {
                int r = wc + n * 16 + (lane & 15);
                int byteoff = r * 128 + ((kk * 64 + (lane >> 4) * 16) ^ ((r & 7) << 4));
                bfr[n] = *reinterpret_cast<const bf16x8*>((const char*)lds_b + byteoff);
            }
            #pragma unroll
            for (int m = 0; m < 4; ++m)
                #pragma unroll
                for (int n = 0; n < 4; ++n)
                    acc[m][n] = __builtin_amdgcn_mfma_f32_16x16x32_bf16(
                        af[m], bfr[n], acc[m][n], 0, 0, 0);
        }
        __syncthreads();
    }

    #pragma unroll
    for (int m = 0; m < 4; ++m) {
        int rbase = row0 + wr + m * 16 + (lane >> 4) * 4;
        #pragma unroll
        for (int n = 0; n < 4; ++n) {
            int col = col0 + wc + n * 16 + (lane & 15);
            #pragma unroll
            for (int r = 0; r < 4; ++r)
                C[(size_t)(rbase + r) * ldc + col] = acc[m][n][r];
        }
    }
}

__global__ __launch_bounds__(256) void gemm_f32_kernel(
    const float* __restrict__ A, const float* __restrict__ Bw,
    float* __restrict__ C, const float* __restrict__ bias,
    int Mr, int Nc, int K, int lda, int ldb, int ldc, int act)
{
    __shared__ float As[16][65];
    __shared__ float Bs[16][65];

    const int tid = threadIdx.x;
    const int tx = tid & 15;
    const int ty = tid >> 4;
    const int col0 = blockIdx.x * 64;
    const int row0 = blockIdx.y * 64;

    const int ak = tid & 15, am = tid >> 4;
    const int bn = tid & 63, bk = tid >> 6;

    float acc[4][4] = {};

    for (int k0 = 0; k0 < K; k0 += 16) {
        #pragma unroll
        for (int q = 0; q < 4; ++q)
            As[ak][am + 16 * q] =
                A[(size_t)(row0 + am + 16 * q) * lda + (k0 + ak)];
        #pragma unroll
        for (int q = 0; q < 4; ++q) {
            int col = col0 + bn;
            Bs[bk + 4 * q][bn] =
                (col < Nc) ? Bw[(size_t)(k0 + bk + 4 * q) * ldb + col] : 0.0f;
        }
        __syncthreads();

        #pragma unroll
        for (int kk = 0; kk < 16; ++kk) {
            float av[4], bv[4];
            #pragma unroll
            for (int i = 0; i < 4; ++i) av[i] = As[kk][ty + 16 * i];
            #pragma unroll
            for (int j = 0; j < 4; ++j) bv[j] = Bs[kk][tx + 16 * j];
            #pragma unroll
            for (int i = 0; i < 4; ++i)
                #pragma unroll
                for (int j = 0; j < 4; ++j)
                    acc[i][j] += av[i] * bv[j];
        }
        __syncthreads();
    }

    #pragma unroll
    for (int i = 0; i < 4; ++i) {
        int row = row0 + ty + 16 * i;
        #pragma unroll
        for (int j = 0; j < 4; ++j) {
            int col = col0 + tx + 16 * j;
            if (col < Nc) {
                float v = acc[i][j];
                if (bias) v += bias[col];
                if (act == 1) v = (v > 20.0f) ? v : log1pf(__expf(v));
                C[(size_t)row * ldc + col] = v;
            }
        }
    }
}

__global__ __launch_bounds__(256) void xproj_splitk_kernel(
    const float* __restrict__ A, const float* __restrict__ Bw,
    float* __restrict__ part)
{
    __shared__ float As[16][65];
    __shared__ float Bs[16][65];

    const int tid = threadIdx.x;
    const int tx = tid & 15;
    const int ty = tid >> 4;
    const int col0 = blockIdx.x * 64;
    const int row0 = blockIdx.y * 64;
    const int kb   = blockIdx.z * KCH;

    const int ak = tid & 15, am = tid >> 4;
    const int bn = tid & 63, bk = tid >> 6;

    float acc[4][4] = {};

    for (int k0 = kb; k0 < kb + KCH; k0 += 16) {
        #pragma unroll
        for (int q = 0; q < 4; ++q)
            As[ak][am + 16 * q] =
                A[(size_t)(row0 + am + 16 * q) * DINNER + (k0 + ak)];
        #pragma unroll
        for (int q = 0; q < 4; ++q) {
            int col = col0 + bn;
            Bs[bk + 4 * q][bn] =
                (col < 96) ? Bw[(size_t)(k0 + bk + 4 * q) * 96 + col] : 0.0f;
        }
        __syncthreads();

        #pragma unroll
        for (int kk = 0; kk < 16; ++kk) {
            float av[4], bv[4];
            #pragma unroll
            for (int i = 0; i < 4; ++i) av[i] = As[kk][ty + 16 * i];
            #pragma unroll
            for (int j = 0; j < 4; ++j) bv[j] = Bs[kk][tx + 16 * j];
            #pragma unroll
            for (int i = 0; i < 4; ++i)
                #pragma unroll
                for (int j = 0; j < 4; ++j)
                    acc[i][j] += av[i] * bv[j];
        }
        __syncthreads();
    }

    float* pbase = part + (size_t)blockIdx.z * MROWS * 96;
    #pragma unroll
    for (int i = 0; i < 4; ++i) {
        int row = row0 + ty + 16 * i;
        #pragma unroll
        for (int j = 0; j < 4; ++j) {
            int col = col0 + tx + 16 * j;
            if (col < 96)
                pbase[(size_t)row * 96 + col] = acc[i][j];
        }
    }
}

__global__ __launch_bounds__(256) void xproj_reduce_kernel(
    const float* __restrict__ part, float* __restrict__ dbc)
{
    int gid = blockIdx.x * 256 + threadIdx.x;
    float s = 0.f;
    #pragma unroll
    for (int k = 0; k < KSPLIT; ++k)
        s += part[(size_t)k * MROWS * 96 + gid];
    dbc[gid] = s;
}

// ---------------------------------------------------------------------------
// Causal depthwise conv1d (width 4) + bias + silu; optional bf16 swz copy.
// ---------------------------------------------------------------------------
__global__ __launch_bounds__(256) void conv_silu_kernel(
    const float* __restrict__ xz, const float* __restrict__ cw,
    const float* __restrict__ cb, float* __restrict__ uc,
    unsigned short* __restrict__ ucbf, int emitBf)
{
    int idx = blockIdx.x * 256 + threadIdx.x;
    int d = idx & (DINNER - 1);
    int row = idx >> 11;
    int t = row & (LSEQ - 1);

    float acc = cb[d];
    #pragma unroll
    for (int k = 0; k < 4; ++k) {
        int tt = t - 3 + k;
        if (tt >= 0)
            acc += xz[(size_t)(row + k - 3) * 4096 + d] * cw[d * 4 + k];
    }
    float v = acc * sigmoidf_(acc);
    uc[(size_t)row * DINNER + d] = v;
    if (emitBf)
        ucbf[(size_t)row * DINNER + (d ^ ((row & 7) << 3))] = f2bf(v);
}

// ---------------------------------------------------------------------------
// Chunked scan passes (unchanged from round 5/6).
// ---------------------------------------------------------------------------
__global__ __launch_bounds__(256) void scan_partial_kernel(
    const float* __restrict__ dtm, const float* __restrict__ um,
    const float* __restrict__ dbc, const float* __restrict__ A_log,
    float* __restrict__ Pbuf, float* __restrict__ Ebuf)
{
    __shared__ float sB[CHUNK][NSTATE];
    const int tid = threadIdx.x;
    const int c = blockIdx.x;
    const int b = blockIdx.z;
    const int d = blockIdx.y * 256 + tid;
    const size_t row0 = (size_t)b * LSEQ + c * CHUNK;

    {
        int s = tid >> 2, f = tid & 3;
        float4 v = *reinterpret_cast<const float4*>(dbc + (row0 + s) * 96 + 64 + f * 4);
        *reinterpret_cast<float4*>(&sB[s][f * 4]) = v;
    }

    float An2[NSTATE];
    #pragma unroll
    for (int k = 0; k < 4; ++k) {
        float4 a = *reinterpret_cast<const float4*>(A_log + (size_t)d * NSTATE + k * 4);
        An2[k*4+0] = -__expf(a.x) * LOG2E;
        An2[k*4+1] = -__expf(a.y) * LOG2E;
        An2[k*4+2] = -__expf(a.z) * LOG2E;
        An2[k*4+3] = -__expf(a.w) * LOG2E;
    }
    __syncthreads();

    float E[NSTATE];
    #pragma unroll
    for (int n = 0; n < NSTATE; ++n) E[n] = 0.f;
    float S = 0.f;

    const float* pdt = dtm + row0 * 4096 + d;
    const float* pu  = um  + row0 * 2048 + d;

    float dtc = pdt[0], ucv = pu[0];
    for (int s = 0; s < CHUNK; ++s) {
        float dtn = 0.f, un = 0.f;
        if (s + 1 < CHUNK) {
            dtn = pdt[(size_t)(s + 1) * 4096];
            un  = pu [(size_t)(s + 1) * 2048];
        }
        S += dtc;
        float du = dtc * ucv;
        float Bv[NSTATE];
        #pragma unroll
        for (int k = 0; k < 4; ++k)
            *reinterpret_cast<float4*>(&Bv[k*4]) =
                *reinterpret_cast<const float4*>(&sB[s][k*4]);
        #pragma unroll
        for (int n = 0; n < NSTATE; ++n) {
            float q = EXP2F(dtc * An2[n]);
            E[n] = fmaf(E[n], q, du * Bv[n]);
        }
        dtc = dtn; ucv = un;
    }

    size_t base = (((size_t)c * BSZ + b) * DINNER + d) * NSTATE;
    #pragma unroll
    for (int n = 0; n < NSTATE; ++n) {
        Pbuf[base + n] = EXP2F(An2[n] * S);
        Ebuf[base + n] = E[n];
    }
}

__global__ __launch_bounds__(256) void scan_prefix_kernel(
    float* __restrict__ Pbuf, const float* __restrict__ Ebuf)
{
    const int gid = blockIdx.x * 256 + threadIdx.x;
    const size_t stride = (size_t)BSZ * DINNER * NSTATE;
    size_t idx = gid;
    float h = 0.f;
    for (int c = 0; c < NCHUNK; ++c) {
        float P = Pbuf[idx];
        float Ev = Ebuf[idx];
        Pbuf[idx] = h;
        h = fmaf(P, h, Ev);
        idx += stride;
    }
}

__global__ __launch_bounds__(256) void scan_final_kernel(
    const float* __restrict__ xzm, float* __restrict__ um,
    const float* __restrict__ dbc,
    const float* __restrict__ A_log, const float* __restrict__ Dp,
    const float* __restrict__ H0,
    unsigned short* __restrict__ ybf, int writeBf)
{
    __shared__ float sBC[CHUNK][2 * NSTATE];
    const int tid = threadIdx.x;
    const int c = blockIdx.x;
    const int b = blockIdx.z;
    const int d = blockIdx.y * 256 + tid;
    const size_t row0 = (size_t)b * LSEQ + c * CHUNK;

    {
        #pragma unroll
        for (int i = 0; i < 2; ++i) {
            int j = tid * 2 + i;
            int s = j >> 3, f = j & 7;
            float4 v = *reinterpret_cast<const float4*>(dbc + (row0 + s) * 96 + 64 + f * 4);
            *reinterpret_cast<float4*>(&sBC[s][f * 4]) = v;
        }
    }

    float An2[NSTATE];
    #pragma unroll
    for (int k = 0; k < 4; ++k) {
        float4 a = *reinterpret_cast<const float4*>(A_log + (size_t)d * NSTATE + k * 4);
        An2[k*4+0] = -__expf(a.x) * LOG2E;
        An2[k*4+1] = -__expf(a.y) * LOG2E;
        An2[k*4+2] = -__expf(a.z) * LOG2E;
        An2[k*4+3] = -__expf(a.w) * LOG2E;
    }
    const float Dpd = Dp[d];

    float h[NSTATE];
    {
        size_t base = (((size_t)c * BSZ + b) * DINNER + d) * NSTATE;
        #pragma unroll
        for (int n = 0; n < NSTATE; ++n) h[n] = H0[base + n];
    }
    __syncthreads();

    const float* pdt = xzm + row0 * 4096 + d;
    const float* pz  = xzm + row0 * 4096 + 2048 + d;
    float* py        = um  + row0 * 2048 + d;

    float dtc = pdt[0], ucv = py[0], zc = pz[0];
    for (int s = 0; s < CHUNK; ++s) {
        float dtn = 0.f, un = 0.f, zn = 0.f;
        if (s + 1 < CHUNK) {
            dtn = pdt[(size_t)(s + 1) * 4096];
            un  = py [(size_t)(s + 1) * 2048];
            zn  = pz [(size_t)(s + 1) * 4096];
        }
        float du = dtc * ucv;
        float Bv[NSTATE], Cv[NSTATE];
        #pragma unroll
        for (int k = 0; k < 4; ++k) {
            *reinterpret_cast<float4*>(&Bv[k*4]) =
                *reinterpret_cast<const float4*>(&sBC[s][k*4]);
            *reinterpret_cast<float4*>(&Cv[k*4]) =
                *reinterpret_cast<const float4*>(&sBC[s][16 + k*4]);
        }
        float y0 = 0.f, y1 = 0.f, y2 = 0.f, y3 = 0.f;
        #pragma unroll
        for (int n = 0; n < NSTATE; ++n) {
            float q = EXP2F(dtc * An2[n]);
            h[n] = fmaf(h[n], q, du * Bv[n]);
            float& yk = (n & 3) == 0 ? y0 : (n & 3) == 1 ? y1 : (n & 3) == 2 ? y2 : y3;
            yk = fmaf(h[n], Cv[n], yk);
        }
        float y = (y0 + y1) + (y2 + y3);
        float yg = (y + ucv * Dpd) * (zc * sigmoidf_(zc));
        if (writeBf) {
            ybf[(row0 + s) * DINNER + (d ^ ((s & 7) << 3))] = f2bf(yg);
        } else {
            py[(size_t)s * 2048] = yg;
        }
        dtc = dtn; ucv = un; zc = zn;
    }
}

// ---------------------------------------------------------------------------
extern "C" void kernel_launch(void* const* d_in, const int* in_sizes, int n_in,
                              void* d_out, int out_size, void* d_ws, size_t ws_size,
                              hipStream_t stream)
{
    const float* x         = (const float*)d_in[0];
    const float* in_proj_w = (const float*)d_in[1];
    const float* conv_w    = (const float*)d_in[2];
    const float* conv_b    = (const float*)d_in[3];
    const float* x_proj_w  = (const float*)d_in[4];
    const float* dt_proj_w = (const float*)d_in[5];
    const float* dt_proj_b = (const float*)d_in[6];
    const float* A_log     = (const float*)d_in[7];
    const float* Dp        = (const float*)d_in[8];
    const float* out_proj_w= (const float*)d_in[9];
    float* out = (float*)d_out;

    dim3 blk(256);
    char* base = (char*)d_ws;
    const int full = (ws_size >= (248ull << 20)) ? 1 : 0;

    if (full) {
        // Fixed: xz 128 | uc 64 | dbc 3 | wT_out 4 | wXT .5 | wDT .25 -> U @200M
        // U overlays (lifetime-disjoint): xbf U+0(16), wT_in U+16(8);
        // ucbf U+0(32), part U+32(12), dtlo U+44(1);
        // Pbuf U+0(16), Ebuf U+16(16); ybf U+16(32). Total 248 MiB.
        float* xz  = (float*)base;
        float* uc  = (float*)(base + (128ull << 20));
        float* dbc = (float*)(base + (192ull << 20));
        unsigned short* wT_out = (unsigned short*)(base + (195ull << 20));
        unsigned short* wXT    = (unsigned short*)(base + (199ull << 20));
        unsigned short* wDT    = (unsigned short*)(base + (199ull << 20) + 524288);
        char* U = base + (200ull << 20);
        unsigned short* xbf   = (unsigned short*)U;
        unsigned short* wT_in = (unsigned short*)(U + (16ull << 20));
        unsigned short* ucbf  = (unsigned short*)U;
        float* part = (float*)(U + (32ull << 20));
        unsigned short* dtlo  = (unsigned short*)(U + (44ull << 20));
        float* Pbuf = (float*)U;
        float* Ebuf = (float*)(U + (16ull << 20));
        unsigned short* ybf   = (unsigned short*)(U + (16ull << 20));

        cvt_swz_kernel<<<dim3(4096), blk, 0, stream>>>(x, xbf, 7);
        transpose_swz_kernel<<<dim3(64, 16), blk, 0, stream>>>(in_proj_w, wT_in, 1024, 4096);
        transpose_swz_kernel<<<dim3(16, 32), blk, 0, stream>>>(out_proj_w, wT_out, 2048, 1024);
        transpose_swz_kernel<<<dim3(2, 32),  blk, 0, stream>>>(x_proj_w,  wXT, 2048, 96);
        transpose_swz_kernel<<<dim3(32, 1),  blk, 0, stream>>>(dt_proj_w, wDT, 64, 2048);

        gemm_bf16bb_kernel<<<dim3(32, 64), blk, 0, stream>>>(
            xbf, wT_in, xz, MROWS, 4096, 1024, 4096);

        conv_silu_kernel<<<dim3((MROWS * DINNER) / 256), blk, 0, stream>>>(
            xz, conv_w, conv_b, uc, ucbf, 1);

        xproj_splitk_bb_kernel<<<dim3(1, 64, XKS), blk, 0, stream>>>(ucbf, wXT, part);
        xproj_reduce4_kernel<<<dim3((MROWS * 96) / 256), blk, 0, stream>>>(part, dbc, dtlo);

        gemm_dtproj_bb_kernel<<<dim3(16, 64), blk, 0, stream>>>(dtlo, wDT, dt_proj_b, xz);

        scan_partial_kernel<<<dim3(NCHUNK, DINNER / 256, BSZ), blk, 0, stream>>>(
            xz, uc, dbc, A_log, Pbuf, Ebuf);
        scan_prefix_kernel<<<dim3((BSZ * DINNER * NSTATE) / 256), blk, 0, stream>>>(Pbuf, Ebuf);
        scan_final_kernel<<<dim3(NCHUNK, DINNER / 256, BSZ), blk, 0, stream>>>(
            xz, uc, dbc, A_log, Dp, Pbuf, ybf, 1);

        gemm_bf16bb_kernel<<<dim3(8, 64), blk, 0, stream>>>(
            ybf, wT_out, out, MROWS, 1024, 2048, 1024);
    } else {
        // Fallback: round-6 proven 239 MiB layout (fp32 x_proj/dt, fp32-A out).
        float* xz  = (float*)base;
        float* uc  = (float*)(base + (128ull << 20));
        float* dbc = (float*)(base + (192ull << 20));
        unsigned short* wT_in  = (unsigned short*)(base + (195ull << 20));
        unsigned short* wT_out = (unsigned short*)(base + (203ull << 20));
        char* U = base + (207ull << 20);
        unsigned short* xbf = (unsigned short*)U;
        float* part = (float*)U;
        float* Pbuf = (float*)U;
        float* Ebuf = (float*)(U + (16ull << 20));

        cvt_swz_kernel<<<dim3(4096), blk, 0, stream>>>(x, xbf, 7);
        transpose_swz_kernel<<<dim3(64, 16), blk, 0, stream>>>(in_proj_w, wT_in, 1024, 4096);
        transpose_swz_kernel<<<dim3(16, 32), blk, 0, stream>>>(out_proj_w, wT_out, 2048, 1024);

        gemm_bf16bb_kernel<<<dim3(32, 64), blk, 0, stream>>>(
            xbf, wT_in, xz, MROWS, 4096, 1024, 4096);

        conv_silu_kernel<<<dim3((MROWS * DINNER) / 256), blk, 0, stream>>>(
            xz, conv_w, conv_b, uc, (unsigned short*)uc, 0);

        xproj_splitk_kernel<<<dim3(2, MROWS / 64, KSPLIT), blk, 0, stream>>>(
            uc, x_proj_w, part);
        xproj_reduce_kernel<<<dim3((MROWS * 96) / 256), blk, 0, stream>>>(part, dbc);

        gemm_f32_kernel<<<dim3(2048 / 64, MROWS / 64), blk, 0, stream>>>(
            dbc, dt_proj_w, xz, dt_proj_b, MROWS, 2048, 64, 96, 2048, 4096, 1);

        scan_partial_kernel<<<dim3(NCHUNK, DINNER / 256, BSZ), blk, 0, stream>>>(
            xz, uc, dbc, A_log, Pbuf, Ebuf);
        scan_prefix_kernel<<<dim3((BSZ * DINNER * NSTATE) / 256), blk, 0, stream>>>(Pbuf, Ebuf);
        scan_final_kernel<<<dim3(NCHUNK, DINNER / 256, BSZ), blk, 0, stream>>>(
            xz, uc, dbc, A_log, Dp, Pbuf, (unsigned short*)uc, 0);

        gemm_bf16_mfma_kernel<<<dim3(8, 64), blk, 0, stream>>>(
            uc, wT_out, out, MROWS, 1024, 2048, 2048, 1024);
    }
}

// Round 8
// 435.243 us; speedup vs baseline: 7.4943x; 1.0850x over previous
//
#include <hip/hip_runtime.h>
#include <hip/hip_bf16.h>
#include <math.h>

#define BSZ 2
#define LSEQ 4096
#define DMODEL 1024
#define DINNER 2048
#define NSTATE 16
#define DTRANK 64
#define MROWS (BSZ * LSEQ)   // 8192
#define NCHUNK 64
#define CHUNK (LSEQ / NCHUNK)  // 64
#define XKS 8
#define XKCH (DINNER / XKS)    // 256

#if __has_builtin(__builtin_amdgcn_exp2f)
#define EXP2F(x) __builtin_amdgcn_exp2f(x)
#else
#define EXP2F(x) exp2f(x)
#endif
#define LOG2E 1.44269504088896f

typedef __attribute__((ext_vector_type(8))) short bf16x8;
typedef __attribute__((ext_vector_type(4))) float f32x4;

__device__ __forceinline__ float sigmoidf_(float x) { return 1.0f / (1.0f + __expf(-x)); }

__device__ __forceinline__ unsigned short f2bf(float x) {
    unsigned int u = __float_as_uint(x);
    u += 0x7fff + ((u >> 16) & 1);          // round-to-nearest-even
    return (unsigned short)(u >> 16);
}
__device__ __forceinline__ float bf2f(unsigned short b) {
    return __uint_as_float(((unsigned int)b) << 16);
}

// ---------------------------------------------------------------------------
// fp32 -> bf16 convert + XOR pre-swizzle, row-major kept.
// Element (m,k) stored at m*K + (k ^ ((m&7)<<3)).
// ---------------------------------------------------------------------------
__global__ __launch_bounds__(256) void cvt_swz_kernel(
    const float* __restrict__ X, unsigned short* __restrict__ Xb,
    int logGpr)
{
    int gid = blockIdx.x * 256 + threadIdx.x;
    int m = gid >> logGpr;
    int g = gid & ((1 << logGpr) - 1);
    int K = 8 << logGpr;
    size_t src = (size_t)m * K + g * 8;
    float4 v0 = *reinterpret_cast<const float4*>(X + src);
    float4 v1 = *reinterpret_cast<const float4*>(X + src + 4);
    unsigned int w0 = (unsigned)f2bf(v0.x) | ((unsigned)f2bf(v0.y) << 16);
    unsigned int w1 = (unsigned)f2bf(v0.z) | ((unsigned)f2bf(v0.w) << 16);
    unsigned int w2 = (unsigned)f2bf(v1.x) | ((unsigned)f2bf(v1.y) << 16);
    unsigned int w3 = (unsigned)f2bf(v1.z) | ((unsigned)f2bf(v1.w) << 16);
    size_t dst = (size_t)m * K + ((g * 8) ^ ((m & 7) << 3));
    uint4 w = {w0, w1, w2, w3};
    *reinterpret_cast<uint4*>(Xb + dst) = w;
}

// ---------------------------------------------------------------------------
// Transpose + fp32->bf16 convert + XOR pre-swizzle. W [K][Nsrc] -> WT [Npad][K]
// (rows >= Nsrc zero-padded, Npad = gridDim.x*64). K % 64 == 0.
// ---------------------------------------------------------------------------
__global__ __launch_bounds__(256) void transpose_swz_kernel(
    const float* __restrict__ W, unsigned short* __restrict__ WT, int K, int Nsrc)
{
    __shared__ float tile[64][65];
    const int t = threadIdx.x;
    const int n0 = blockIdx.x * 64;
    const int k0 = blockIdx.y * 64;

    #pragma unroll
    for (int i = 0; i < 16; ++i) {
        int flat = i * 256 + t;
        int r = flat >> 6, c = flat & 63;
        tile[r][c] = (n0 + c < Nsrc) ? W[(size_t)(k0 + r) * Nsrc + n0 + c] : 0.0f;
    }
    __syncthreads();
    #pragma unroll
    for (int i = 0; i < 16; ++i) {
        int flat = i * 256 + t;
        int n = flat >> 6, k = flat & 63;
        int ks = k ^ ((n & 7) << 3);
        WT[(size_t)(n0 + n) * K + k0 + ks] = f2bf(tile[k][n]);
    }
}

// ---------------------------------------------------------------------------
// Pure-bf16 MFMA GEMM: both operands pre-swizzled bf16 [.][K].
// Both staged via width-16 global_load_lds. 128x128 tile, BK=64.
// OBF=1: C written as bf16 (linear); OBF=0: fp32.
// ---------------------------------------------------------------------------
template<int OBF>
__global__ __launch_bounds__(256) void gemm_bb_kernel(
    const unsigned short* __restrict__ Abf, const unsigned short* __restrict__ BT,
    void* __restrict__ Cv, int M, int N, int K, int ldc)
{
    __shared__ unsigned short lds_a[128 * 64];
    __shared__ unsigned short lds_b[128 * 64];

    const int tid  = threadIdx.x;
    const int lane = tid & 63;
    const int w    = tid >> 6;
    const int wr   = (w >> 1) * 64;
    const int wc   = (w & 1) * 64;
    const int row0 = blockIdx.y * 128;
    const int col0 = blockIdx.x * 128;

    f32x4 acc[4][4];
    #pragma unroll
    for (int m = 0; m < 4; ++m)
        #pragma unroll
        for (int n = 0; n < 4; ++n)
            acc[m][n] = (f32x4){0.f, 0.f, 0.f, 0.f};

    for (int k0 = 0; k0 < K; k0 += 64) {
        #pragma unroll
        for (int j = 0; j < 4; ++j) {
            int c  = (j * 4 + w) * 64 + lane;
            int r  = c >> 3;
            int cc = c & 7;
            const char* asrc = (const char*)Abf +
                ((size_t)(row0 + r) * K + k0) * 2 + cc * 16;
            __builtin_amdgcn_global_load_lds(
                (const __attribute__((address_space(1))) void*)asrc,
                (__attribute__((address_space(3))) void*)((char*)lds_a + (j * 4 + w) * 1024),
                16, 0, 0);
            const char* bsrc = (const char*)BT +
                ((size_t)(col0 + r) * K + k0) * 2 + cc * 16;
            __builtin_amdgcn_global_load_lds(
                (const __attribute__((address_space(1))) void*)bsrc,
                (__attribute__((address_space(3))) void*)((char*)lds_b + (j * 4 + w) * 1024),
                16, 0, 0);
        }
        __syncthreads();

        #pragma unroll
        for (int kk = 0; kk < 2; ++kk) {
            bf16x8 af[4], bfr[4];
            #pragma unroll
            for (int m = 0; m < 4; ++m) {
                int r = wr + m * 16 + (lane & 15);
                int byteoff = r * 128 + ((kk * 64 + (lane >> 4) * 16) ^ ((r & 7) << 4));
                af[m] = *reinterpret_cast<const bf16x8*>((const char*)lds_a + byteoff);
            }
            #pragma unroll
            for (int n = 0; n < 4; ++n) {
                int r = wc + n * 16 + (lane & 15);
                int byteoff = r * 128 + ((kk * 64 + (lane >> 4) * 16) ^ ((r & 7) << 4));
                bfr[n] = *reinterpret_cast<const bf16x8*>((const char*)lds_b + byteoff);
            }
            #pragma unroll
            for (int m = 0; m < 4; ++m)
                #pragma unroll
                for (int n = 0; n < 4; ++n)
                    acc[m][n] = __builtin_amdgcn_mfma_f32_16x16x32_bf16(
                        af[m], bfr[n], acc[m][n], 0, 0, 0);
        }
        __syncthreads();
    }

    #pragma unroll
    for (int m = 0; m < 4; ++m) {
        int rbase = row0 + wr + m * 16 + (lane >> 4) * 4;
        #pragma unroll
        for (int n = 0; n < 4; ++n) {
            int col = col0 + wc + n * 16 + (lane & 15);
            #pragma unroll
            for (int r = 0; r < 4; ++r) {
                if (OBF) {
                    ((unsigned short*)Cv)[(size_t)(rbase + r) * ldc + col] =
                        f2bf(acc[m][n][r]);
                } else {
                    ((float*)Cv)[(size_t)(rbase + r) * ldc + col] = acc[m][n][r];
                }
            }
        }
    }
}

// ---------------------------------------------------------------------------
// MFMA split-K x_proj: part[z] = ucbf[:, kb:kb+256] @ wXT^T (N=96 of 128).
// Grid (1, M/128, XKS). fp32 partials [XKS][MROWS][96].
// ---------------------------------------------------------------------------
__global__ __launch_bounds__(256) void xproj_splitk_bb_kernel(
    const unsigned short* __restrict__ Abf, const unsigned short* __restrict__ BT,
    float* __restrict__ part)
{
    __shared__ unsigned short lds_a[128 * 64];
    __shared__ unsigned short lds_b[128 * 64];

    const int tid  = threadIdx.x;
    const int lane = tid & 63;
    const int w    = tid >> 6;
    const int wr   = (w >> 1) * 64;
    const int wc   = (w & 1) * 64;
    const int row0 = blockIdx.y * 128;
    const int kb   = blockIdx.z * XKCH;
    const int K    = DINNER;

    f32x4 acc[4][4];
    #pragma unroll
    for (int m = 0; m < 4; ++m)
        #pragma unroll
        for (int n = 0; n < 4; ++n)
            acc[m][n] = (f32x4){0.f, 0.f, 0.f, 0.f};

    for (int k0 = kb; k0 < kb + XKCH; k0 += 64) {
        #pragma unroll
        for (int j = 0; j < 4; ++j) {
            int c  = (j * 4 + w) * 64 + lane;
            int r  = c >> 3;
            int cc = c & 7;
            const char* asrc = (const char*)Abf +
                ((size_t)(row0 + r) * K + k0) * 2 + cc * 16;
            __builtin_amdgcn_global_load_lds(
                (const __attribute__((address_space(1))) void*)asrc,
                (__attribute__((address_space(3))) void*)((char*)lds_a + (j * 4 + w) * 1024),
                16, 0, 0);
            const char* bsrc = (const char*)BT +
                ((size_t)r * K + k0) * 2 + cc * 16;
            __builtin_amdgcn_global_load_lds(
                (const __attribute__((address_space(1))) void*)bsrc,
                (__attribute__((address_space(3))) void*)((char*)lds_b + (j * 4 + w) * 1024),
                16, 0, 0);
        }
        __syncthreads();

        #pragma unroll
        for (int kk = 0; kk < 2; ++kk) {
            bf16x8 af[4], bfr[4];
            #pragma unroll
            for (int m = 0; m < 4; ++m) {
                int r = wr + m * 16 + (lane & 15);
                int byteoff = r * 128 + ((kk * 64 + (lane >> 4) * 16) ^ ((r & 7) << 4));
                af[m] = *reinterpret_cast<const bf16x8*>((const char*)lds_a + byteoff);
            }
            #pragma unroll
            for (int n = 0; n < 4; ++n) {
                int r = wc + n * 16 + (lane & 15);
                int byteoff = r * 128 + ((kk * 64 + (lane >> 4) * 16) ^ ((r & 7) << 4));
                bfr[n] = *reinterpret_cast<const bf16x8*>((const char*)lds_b + byteoff);
            }
            #pragma unroll
            for (int m = 0; m < 4; ++m)
                #pragma unroll
                for (int n = 0; n < 4; ++n)
                    acc[m][n] = __builtin_amdgcn_mfma_f32_16x16x32_bf16(
                        af[m], bfr[n], acc[m][n], 0, 0, 0);
        }
        __syncthreads();
    }

    float* pbase = part + (size_t)blockIdx.z * MROWS * 96;
    #pragma unroll
    for (int m = 0; m < 4; ++m) {
        int rbase = row0 + wr + m * 16 + (lane >> 4) * 4;
        #pragma unroll
        for (int n = 0; n < 4; ++n) {
            int col = wc + n * 16 + (lane & 15);
            if (col < 96) {
                #pragma unroll
                for (int r = 0; r < 4; ++r)
                    pbase[(size_t)(rbase + r) * 96 + col] = acc[m][n][r];
            }
        }
    }
}

// Reduce XKS partials -> dbc fp32; cols<64 also emitted as pre-swizzled bf16.
__global__ __launch_bounds__(256) void xproj_reduce_kernel(
    const float* __restrict__ part, float* __restrict__ dbc,
    unsigned short* __restrict__ dtlo)
{
    int gid = blockIdx.x * 256 + threadIdx.x;
    float s = 0.f;
    #pragma unroll
    for (int k = 0; k < XKS; ++k)
        s += part[(size_t)k * MROWS * 96 + gid];
    dbc[gid] = s;
    int row = gid / 96;
    int col = gid - row * 96;
    if (col < 64)
        dtlo[(size_t)row * 64 + (col ^ ((row & 7) << 3))] = f2bf(s);
}

// ---------------------------------------------------------------------------
// dt_proj MFMA (K=64, one K-step): dt = softplus(dtlo @ wDT^T + bias) -> dtf.
// ---------------------------------------------------------------------------
__global__ __launch_bounds__(256) void gemm_dtproj_bb_kernel(
    const unsigned short* __restrict__ Abf, const unsigned short* __restrict__ BT,
    const float* __restrict__ bias, float* __restrict__ C)
{
    __shared__ unsigned short lds_a[128 * 64];
    __shared__ unsigned short lds_b[128 * 64];

    const int tid  = threadIdx.x;
    const int lane = tid & 63;
    const int w    = tid >> 6;
    const int wr   = (w >> 1) * 64;
    const int wc   = (w & 1) * 64;
    const int row0 = blockIdx.y * 128;
    const int col0 = blockIdx.x * 128;

    f32x4 acc[4][4];
    #pragma unroll
    for (int m = 0; m < 4; ++m)
        #pragma unroll
        for (int n = 0; n < 4; ++n)
            acc[m][n] = (f32x4){0.f, 0.f, 0.f, 0.f};

    #pragma unroll
    for (int j = 0; j < 4; ++j) {
        int c  = (j * 4 + w) * 64 + lane;
        int r  = c >> 3;
        int cc = c & 7;
        const char* asrc = (const char*)Abf + ((size_t)(row0 + r) * 64) * 2 + cc * 16;
        __builtin_amdgcn_global_load_lds(
            (const __attribute__((address_space(1))) void*)asrc,
            (__attribute__((address_space(3))) void*)((char*)lds_a + (j * 4 + w) * 1024),
            16, 0, 0);
        const char* bsrc = (const char*)BT + ((size_t)(col0 + r) * 64) * 2 + cc * 16;
        __builtin_amdgcn_global_load_lds(
            (const __attribute__((address_space(1))) void*)bsrc,
            (__attribute__((address_space(3))) void*)((char*)lds_b + (j * 4 + w) * 1024),
            16, 0, 0);
    }
    __syncthreads();

    #pragma unroll
    for (int kk = 0; kk < 2; ++kk) {
        bf16x8 af[4], bfr[4];
        #pragma unroll
        for (int m = 0; m < 4; ++m) {
            int r = wr + m * 16 + (lane & 15);
            int byteoff = r * 128 + ((kk * 64 + (lane >> 4) * 16) ^ ((r & 7) << 4));
            af[m] = *reinterpret_cast<const bf16x8*>((const char*)lds_a + byteoff);
        }
        #pragma unroll
        for (int n = 0; n < 4; ++n) {
            int r = wc + n * 16 + (lane & 15);
            int byteoff = r * 128 + ((kk * 64 + (lane >> 4) * 16) ^ ((r & 7) << 4));
            bfr[n] = *reinterpret_cast<const bf16x8*>((const char*)lds_b + byteoff);
        }
        #pragma unroll
        for (int m = 0; m < 4; ++m)
            #pragma unroll
            for (int n = 0; n < 4; ++n)
                acc[m][n] = __builtin_amdgcn_mfma_f32_16x16x32_bf16(
                    af[m], bfr[n], acc[m][n], 0, 0, 0);
    }

    #pragma unroll
    for (int m = 0; m < 4; ++m) {
        int rbase = row0 + wr + m * 16 + (lane >> 4) * 4;
        #pragma unroll
        for (int n = 0; n < 4; ++n) {
            int col = col0 + wc + n * 16 + (lane & 15);
            float bv = bias[col];
            #pragma unroll
            for (int r = 0; r < 4; ++r) {
                float v = acc[m][n][r] + bv;
                v = (v > 20.0f) ? v : log1pf(__expf(v));
                C[(size_t)(rbase + r) * DINNER + col] = v;
            }
        }
    }
}

// ---------------------------------------------------------------------------
// Causal depthwise conv1d (width 4) + bias + silu, bf16 in -> swizzled bf16 out.
// One thread = 8 consecutive channels (16B vector loads/stores).
// ---------------------------------------------------------------------------
__global__ __launch_bounds__(256) void conv_silu_kernel(
    const unsigned short* __restrict__ xzb, const float* __restrict__ cw,
    const float* __restrict__ cb, unsigned short* __restrict__ ucbf)
{
    int gid = blockIdx.x * 256 + threadIdx.x;     // over MROWS * (DINNER/8)
    int row = gid >> 8;                           // 256 groups per row
    int d0  = (gid & 255) * 8;
    int t = row & (LSEQ - 1);

    uint4 uv[4];
    #pragma unroll
    for (int k = 0; k < 4; ++k) {
        if (t - 3 + k >= 0)
            uv[k] = *reinterpret_cast<const uint4*>(
                xzb + (size_t)(row + k - 3) * 4096 + d0);
        else
            uv[k] = (uint4){0u, 0u, 0u, 0u};      // bf16 zeros
    }

    float v[8];
    #pragma unroll
    for (int i = 0; i < 8; ++i) {
        float acc = cb[d0 + i];
        float4 wv = *reinterpret_cast<const float4*>(cw + (size_t)(d0 + i) * 4);
        float wk[4] = {wv.x, wv.y, wv.z, wv.w};
        #pragma unroll
        for (int k = 0; k < 4; ++k) {
            unsigned int word = (&uv[k].x)[i >> 1];
            float u = __uint_as_float((i & 1) ? (word & 0xffff0000u) : (word << 16));
            acc = fmaf(u, wk[k], acc);
        }
        v[i] = acc * sigmoidf_(acc);
    }

    uint4 o;
    o.x = (unsigned)f2bf(v[0]) | ((unsigned)f2bf(v[1]) << 16);
    o.y = (unsigned)f2bf(v[2]) | ((unsigned)f2bf(v[3]) << 16);
    o.z = (unsigned)f2bf(v[4]) | ((unsigned)f2bf(v[5]) << 16);
    o.w = (unsigned)f2bf(v[6]) | ((unsigned)f2bf(v[7]) << 16);
    *reinterpret_cast<uint4*>(
        ucbf + (size_t)row * DINNER + (d0 ^ ((row & 7) << 3))) = o;
}

// ---------------------------------------------------------------------------
// Chunked scan, pass A: local end-state E[16] and chunk decay P[n].
// u from swizzled bf16 ucbf; dt from dense fp32 dtf.
// ---------------------------------------------------------------------------
__global__ __launch_bounds__(256) void scan_partial_kernel(
    const float* __restrict__ dtf, const unsigned short* __restrict__ ucbf,
    const float* __restrict__ dbc, const float* __restrict__ A_log,
    float* __restrict__ Pbuf, float* __restrict__ Ebuf)
{
    __shared__ float sB[CHUNK][NSTATE];
    const int tid = threadIdx.x;
    const int c = blockIdx.x;
    const int b = blockIdx.z;
    const int d = blockIdx.y * 256 + tid;
    const size_t row0 = (size_t)b * LSEQ + c * CHUNK;   // multiple of 8

    {
        int s = tid >> 2, f = tid & 3;
        float4 v = *reinterpret_cast<const float4*>(dbc + (row0 + s) * 96 + 64 + f * 4);
        *reinterpret_cast<float4*>(&sB[s][f * 4]) = v;
    }

    float An2[NSTATE];
    #pragma unroll
    for (int k = 0; k < 4; ++k) {
        float4 a = *reinterpret_cast<const float4*>(A_log + (size_t)d * NSTATE + k * 4);
        An2[k*4+0] = -__expf(a.x) * LOG2E;
        An2[k*4+1] = -__expf(a.y) * LOG2E;
        An2[k*4+2] = -__expf(a.z) * LOG2E;
        An2[k*4+3] = -__expf(a.w) * LOG2E;
    }
    __syncthreads();

    float E[NSTATE];
    #pragma unroll
    for (int n = 0; n < NSTATE; ++n) E[n] = 0.f;
    float S = 0.f;

    float dtc = dtf[row0 * DINNER + d];
    float ucv = bf2f(ucbf[row0 * DINNER + d]);          // s=0: XOR term 0
    for (int s = 0; s < CHUNK; ++s) {
        float dtn = 0.f, un = 0.f;
        if (s + 1 < CHUNK) {
            dtn = dtf[(row0 + s + 1) * DINNER + d];
            un  = bf2f(ucbf[(row0 + s + 1) * DINNER + (d ^ (((s + 1) & 7) << 3))]);
        }
        S += dtc;
        float du = dtc * ucv;
        float Bv[NSTATE];
        #pragma unroll
        for (int k = 0; k < 4; ++k)
            *reinterpret_cast<float4*>(&Bv[k*4]) =
                *reinterpret_cast<const float4*>(&sB[s][k*4]);
        #pragma unroll
        for (int n = 0; n < NSTATE; ++n) {
            float q = EXP2F(dtc * An2[n]);
            E[n] = fmaf(E[n], q, du * Bv[n]);
        }
        dtc = dtn; ucv = un;
    }

    size_t base = (((size_t)c * BSZ + b) * DINNER + d) * NSTATE;
    #pragma unroll
    for (int n = 0; n < NSTATE; ++n) {
        Pbuf[base + n] = EXP2F(An2[n] * S);
        Ebuf[base + n] = E[n];
    }
}

// ---------------------------------------------------------------------------
// Pass B: exclusive scan over chunks per (b,d,n); h0 written IN PLACE over P.
// ---------------------------------------------------------------------------
__global__ __launch_bounds__(256) void scan_prefix_kernel(
    float* __restrict__ Pbuf, const float* __restrict__ Ebuf)
{
    const int gid = blockIdx.x * 256 + threadIdx.x;
    const size_t stride = (size_t)BSZ * DINNER * NSTATE;
    size_t idx = gid;
    float h = 0.f;
    for (int c = 0; c < NCHUNK; ++c) {
        float P = Pbuf[idx];
        float Ev = Ebuf[idx];
        Pbuf[idx] = h;
        h = fmaf(P, h, Ev);
        idx += stride;
    }
}

// ---------------------------------------------------------------------------
// Pass C: local scan seeded with h0; fuse y, skip, gate; emit swizzled bf16 ybf.
// u from ucbf (bf16 swz), dt from dtf (fp32), z from xzb cols 2048.. (bf16).
// ---------------------------------------------------------------------------
__global__ __launch_bounds__(256) void scan_final_kernel(
    const float* __restrict__ dtf, const unsigned short* __restrict__ ucbf,
    const unsigned short* __restrict__ xzb, const float* __restrict__ dbc,
    const float* __restrict__ A_log, const float* __restrict__ Dp,
    const float* __restrict__ H0, unsigned short* __restrict__ ybf)
{
    __shared__ float sBC[CHUNK][2 * NSTATE];
    const int tid = threadIdx.x;
    const int c = blockIdx.x;
    const int b = blockIdx.z;
    const int d = blockIdx.y * 256 + tid;
    const size_t row0 = (size_t)b * LSEQ + c * CHUNK;

    {
        #pragma unroll
        for (int i = 0; i < 2; ++i) {
            int j = tid * 2 + i;
            int s = j >> 3, f = j & 7;
            float4 v = *reinterpret_cast<const float4*>(dbc + (row0 + s) * 96 + 64 + f * 4);
            *reinterpret_cast<float4*>(&sBC[s][f * 4]) = v;
        }
    }

    float An2[NSTATE];
    #pragma unroll
    for (int k = 0; k < 4; ++k) {
        float4 a = *reinterpret_cast<const float4*>(A_log + (size_t)d * NSTATE + k * 4);
        An2[k*4+0] = -__expf(a.x) * LOG2E;
        An2[k*4+1] = -__expf(a.y) * LOG2E;
        An2[k*4+2] = -__expf(a.z) * LOG2E;
        An2[k*4+3] = -__expf(a.w) * LOG2E;
    }
    const float Dpd = Dp[d];

    float h[NSTATE];
    {
        size_t base = (((size_t)c * BSZ + b) * DINNER + d) * NSTATE;
        #pragma unroll
        for (int n = 0; n < NSTATE; ++n) h[n] = H0[base + n];
    }
    __syncthreads();

    float dtc = dtf[row0 * DINNER + d];
    float ucv = bf2f(ucbf[row0 * DINNER + d]);
    float zc  = bf2f(xzb[row0 * 4096 + 2048 + d]);
    for (int s = 0; s < CHUNK; ++s) {
        float dtn = 0.f, un = 0.f, zn = 0.f;
        if (s + 1 < CHUNK) {
            dtn = dtf[(row0 + s + 1) * DINNER + d];
            un  = bf2f(ucbf[(row0 + s + 1) * DINNER + (d ^ (((s + 1) & 7) << 3))]);
            zn  = bf2f(xzb[(row0 + s + 1) * 4096 + 2048 + d]);
        }
        float du = dtc * ucv;
        float Bv[NSTATE], Cv[NSTATE];
        #pragma unroll
        for (int k = 0; k < 4; ++k) {
            *reinterpret_cast<float4*>(&Bv[k*4]) =
                *reinterpret_cast<const float4*>(&sBC[s][k*4]);
            *reinterpret_cast<float4*>(&Cv[k*4]) =
                *reinterpret_cast<const float4*>(&sBC[s][16 + k*4]);
        }
        float y0 = 0.f, y1 = 0.f, y2 = 0.f, y3 = 0.f;
        #pragma unroll
        for (int n = 0; n < NSTATE; ++n) {
            float q = EXP2F(dtc * An2[n]);
            h[n] = fmaf(h[n], q, du * Bv[n]);
            float& yk = (n & 3) == 0 ? y0 : (n & 3) == 1 ? y1 : (n & 3) == 2 ? y2 : y3;
            yk = fmaf(h[n], Cv[n], yk);
        }
        float y = (y0 + y1) + (y2 + y3);
        float yg = (y + ucv * Dpd) * (zc * sigmoidf_(zc));
        ybf[(row0 + s) * DINNER + (d ^ ((s & 7) << 3))] = f2bf(yg);
        dtc = dtn; ucv = un; zc = zn;
    }
}

// ---------------------------------------------------------------------------
extern "C" void kernel_launch(void* const* d_in, const int* in_sizes, int n_in,
                              void* d_out, int out_size, void* d_ws, size_t ws_size,
                              hipStream_t stream)
{
    const float* x         = (const float*)d_in[0];
    const float* in_proj_w = (const float*)d_in[1];
    const float* conv_w    = (const float*)d_in[2];
    const float* conv_b    = (const float*)d_in[3];
    const float* x_proj_w  = (const float*)d_in[4];
    const float* dt_proj_w = (const float*)d_in[5];
    const float* dt_proj_b = (const float*)d_in[6];
    const float* A_log     = (const float*)d_in[7];
    const float* Dp        = (const float*)d_in[8];
    const float* out_proj_w= (const float*)d_in[9];
    float* out = (float*)d_out;

    // Workspace (240 MiB total; >=248 MiB available, confirmed round 7):
    //  xzb   bf16 [8192][4096]  64 MiB   (in_proj out: u|z)
    //  dtf   f32  [8192][2048]  64 MiB   (softplus dt)
    //  ucbf  bf16 [8192][2048]  32 MiB   (conv out, pre-swizzled)
    //  dbc   f32  [8192][96]     3 MiB
    //  wT_in 8 | wT_out 4 | wXT .5 | wDT .25
    //  U (64 MiB union, lifetime-disjoint):
    //   xbf U+0 16 [cvt..in_proj]; part U+0 24 [xproj..reduce];
    //   dtlo U+24 1 [reduce..dtproj]; Pbuf U+16 16 [scanA..scanC];
    //   Ebuf U+32 16 [scanA..prefix]; ybf U+32 32 [scanC..out_proj]
    char* base = (char*)d_ws;
    unsigned short* xzb  = (unsigned short*)base;
    float* dtf           = (float*)(base + (64ull << 20));
    unsigned short* ucbf = (unsigned short*)(base + (128ull << 20));
    float* dbc           = (float*)(base + (160ull << 20));
    unsigned short* wT_in  = (unsigned short*)(base + (163ull << 20));
    unsigned short* wT_out = (unsigned short*)(base + (171ull << 20));
    unsigned short* wXT    = (unsigned short*)(base + (175ull << 20));
    unsigned short* wDT    = (unsigned short*)(base + (175ull << 20) + (512ull << 10));
    char* U = base + (176ull << 20);
    unsigned short* xbf  = (unsigned short*)U;
    float* part          = (float*)U;
    unsigned short* dtlo = (unsigned short*)(U + (24ull << 20));
    float* Pbuf          = (float*)(U + (16ull << 20));
    float* Ebuf          = (float*)(U + (32ull << 20));
    unsigned short* ybf  = (unsigned short*)(U + (32ull << 20));

    dim3 blk(256);

    // 0) operand prep
    cvt_swz_kernel<<<dim3(4096), blk, 0, stream>>>(x, xbf, 7);
    transpose_swz_kernel<<<dim3(64, 16), blk, 0, stream>>>(in_proj_w, wT_in, 1024, 4096);
    transpose_swz_kernel<<<dim3(16, 32), blk, 0, stream>>>(out_proj_w, wT_out, 2048, 1024);
    transpose_swz_kernel<<<dim3(2, 32),  blk, 0, stream>>>(x_proj_w,  wXT, 2048, 96);
    transpose_swz_kernel<<<dim3(32, 1),  blk, 0, stream>>>(dt_proj_w, wDT, 64, 2048);

    // 1) xzb = bf16(x @ in_proj_w)
    gemm_bb_kernel<1><<<dim3(32, 64), blk, 0, stream>>>(
        xbf, wT_in, (void*)xzb, MROWS, 4096, 1024, 4096);

    // 2) ucbf = swz_bf16(silu(causal_conv(u) + conv_b))
    conv_silu_kernel<<<dim3((MROWS * (DINNER / 8)) / 256), blk, 0, stream>>>(
        xzb, conv_w, conv_b, ucbf);

    // 3) dbc = uc @ x_proj_w  (bf16 MFMA split-K + reduce; emits dtlo bf16)
    xproj_splitk_bb_kernel<<<dim3(1, 64, XKS), blk, 0, stream>>>(ucbf, wXT, part);
    xproj_reduce_kernel<<<dim3((MROWS * 96) / 256), blk, 0, stream>>>(part, dbc, dtlo);

    // 4) dtf = softplus(dtlo @ dt_proj_w + dt_proj_b)
    gemm_dtproj_bb_kernel<<<dim3(16, 64), blk, 0, stream>>>(dtlo, wDT, dt_proj_b, dtf);

    // 5) chunked selective scan (3 passes) -> ybf (swizzled bf16)
    scan_partial_kernel<<<dim3(NCHUNK, DINNER / 256, BSZ), blk, 0, stream>>>(
        dtf, ucbf, dbc, A_log, Pbuf, Ebuf);
    scan_prefix_kernel<<<dim3((BSZ * DINNER * NSTATE) / 256), blk, 0, stream>>>(Pbuf, Ebuf);
    scan_final_kernel<<<dim3(NCHUNK, DINNER / 256, BSZ), blk, 0, stream>>>(
        dtf, ucbf, xzb, dbc, A_log, Dp, Pbuf, ybf);

    // 6) out = y_gated @ out_proj_w (fp32 out)
    gemm_bb_kernel<0><<<dim3(8, 64), blk, 0, stream>>>(
        ybf, wT_out, (void*)out, MROWS, 1024, 2048, 1024);
}

// Round 9
// 403.913 us; speedup vs baseline: 8.0756x; 1.0776x over previous
//
#include <hip/hip_runtime.h>
#include <hip/hip_bf16.h>
#include <math.h>

#define BSZ 2
#define LSEQ 4096
#define DMODEL 1024
#define DINNER 2048
#define NSTATE 16
#define DTRANK 64
#define MROWS (BSZ * LSEQ)   // 8192
#define NCHUNK 64
#define CHUNK (LSEQ / NCHUNK)  // 64
#define XKS 8
#define XKCH (DINNER / XKS)    // 256

#if __has_builtin(__builtin_amdgcn_exp2f)
#define EXP2F(x) __builtin_amdgcn_exp2f(x)
#else
#define EXP2F(x) exp2f(x)
#endif
#define LOG2E 1.44269504088896f

typedef __attribute__((ext_vector_type(8))) short bf16x8;
typedef __attribute__((ext_vector_type(4))) float f32x4;

__device__ __forceinline__ float sigmoidf_(float x) { return 1.0f / (1.0f + __expf(-x)); }

__device__ __forceinline__ unsigned short f2bf(float x) {
    unsigned int u = __float_as_uint(x);
    u += 0x7fff + ((u >> 16) & 1);          // round-to-nearest-even
    return (unsigned short)(u >> 16);
}
__device__ __forceinline__ float bf2f(unsigned short b) {
    return __uint_as_float(((unsigned int)b) << 16);
}

// ---------------------------------------------------------------------------
// Fused operand prep: one launch does
//  blocks [0,1024):    in_proj_w  [1024][4096] -> wT_in  [4096][1024] swz
//  blocks [1024,1536): out_proj_w [2048][1024] -> wT_out [1024][2048] swz
//  blocks [1536,1600): x_proj_w   [2048][96]   -> wXT    [128][2048]  swz (pad)
//  blocks [1600,1632): dt_proj_w  [64][2048]   -> wDT    [2048][64]   swz
//  blocks [1632,5728): x [8192][1024] fp32 -> xbf bf16 row-major swz
// Swizzle: element k of a 64-window stored at k ^ ((row&7)<<3).
// ---------------------------------------------------------------------------
__global__ __launch_bounds__(256) void prep_kernel(
    const float* __restrict__ x, unsigned short* __restrict__ xbf,
    const float* __restrict__ w_in, unsigned short* __restrict__ wT_in,
    const float* __restrict__ w_out, unsigned short* __restrict__ wT_out,
    const float* __restrict__ w_x, unsigned short* __restrict__ wXT,
    const float* __restrict__ w_dt, unsigned short* __restrict__ wDT)
{
    __shared__ float tile[64][65];
    const int id = blockIdx.x;
    const int t = threadIdx.x;

    if (id >= 1632) {   // cvt x -> xbf (K=1024, 128 groups of 8 per row)
        int gid = (id - 1632) * 256 + t;
        int m = gid >> 7;
        int g = gid & 127;
        size_t src = (size_t)m * 1024 + g * 8;
        float4 v0 = *reinterpret_cast<const float4*>(x + src);
        float4 v1 = *reinterpret_cast<const float4*>(x + src + 4);
        uint4 w;
        w.x = (unsigned)f2bf(v0.x) | ((unsigned)f2bf(v0.y) << 16);
        w.y = (unsigned)f2bf(v0.z) | ((unsigned)f2bf(v0.w) << 16);
        w.z = (unsigned)f2bf(v1.x) | ((unsigned)f2bf(v1.y) << 16);
        w.w = (unsigned)f2bf(v1.z) | ((unsigned)f2bf(v1.w) << 16);
        size_t dst = (size_t)m * 1024 + ((g * 8) ^ ((m & 7) << 3));
        *reinterpret_cast<uint4*>(xbf + dst) = w;
        return;
    }

    const float* W; unsigned short* WT; int K, Nsrc, nb, kb;
    if (id < 1024)      { W = w_in;  WT = wT_in;  K = 1024; Nsrc = 4096; nb = id & 63; kb = id >> 6; }
    else if (id < 1536) { int q = id - 1024; W = w_out; WT = wT_out; K = 2048; Nsrc = 1024; nb = q & 15; kb = q >> 4; }
    else if (id < 1600) { int q = id - 1536; W = w_x;   WT = wXT;   K = 2048; Nsrc = 96;   nb = q & 1;  kb = q >> 1; }
    else                { int q = id - 1600; W = w_dt;  WT = wDT;   K = 64;   Nsrc = 2048; nb = q;      kb = 0; }

    const int n0 = nb * 64;
    const int k0 = kb * 64;

    #pragma unroll
    for (int i = 0; i < 16; ++i) {
        int flat = i * 256 + t;
        int r = flat >> 6, c = flat & 63;
        tile[r][c] = (n0 + c < Nsrc) ? W[(size_t)(k0 + r) * Nsrc + n0 + c] : 0.0f;
    }
    __syncthreads();
    #pragma unroll
    for (int i = 0; i < 16; ++i) {
        int flat = i * 256 + t;
        int n = flat >> 6, k = flat & 63;
        int ks = k ^ ((n & 7) << 3);
        WT[(size_t)(n0 + n) * K + k0 + ks] = f2bf(tile[k][n]);
    }
}

// ---------------------------------------------------------------------------
// Pure-bf16 MFMA GEMM: both operands pre-swizzled bf16 [.][K], staged via
// width-16 global_load_lds. 128x128 tile, BK=64. XCD-aware bijective block
// swizzle (requires nwg % 8 == 0). OBF=1: bf16 C; OBF=0: fp32 C.
// ---------------------------------------------------------------------------
template<int OBF>
__global__ __launch_bounds__(256) void gemm_bb_kernel(
    const unsigned short* __restrict__ Abf, const unsigned short* __restrict__ BT,
    void* __restrict__ Cv, int M, int N, int K, int ldc)
{
    __shared__ unsigned short lds_a[128 * 64];
    __shared__ unsigned short lds_b[128 * 64];

    // XCD swizzle: contiguous chunk of the grid per XCD (8 XCDs)
    const int nwg = gridDim.x * gridDim.y;
    const int wg  = blockIdx.y * gridDim.x + blockIdx.x;
    const int cpx = nwg >> 3;
    const int swz = (wg & 7) * cpx + (wg >> 3);
    const int bx  = swz % gridDim.x;
    const int by  = swz / gridDim.x;

    const int tid  = threadIdx.x;
    const int lane = tid & 63;
    const int w    = tid >> 6;
    const int wr   = (w >> 1) * 64;
    const int wc   = (w & 1) * 64;
    const int row0 = by * 128;
    const int col0 = bx * 128;

    f32x4 acc[4][4];
    #pragma unroll
    for (int m = 0; m < 4; ++m)
        #pragma unroll
        for (int n = 0; n < 4; ++n)
            acc[m][n] = (f32x4){0.f, 0.f, 0.f, 0.f};

    for (int k0 = 0; k0 < K; k0 += 64) {
        #pragma unroll
        for (int j = 0; j < 4; ++j) {
            int c  = (j * 4 + w) * 64 + lane;
            int r  = c >> 3;
            int cc = c & 7;
            const char* asrc = (const char*)Abf +
                ((size_t)(row0 + r) * K + k0) * 2 + cc * 16;
            __builtin_amdgcn_global_load_lds(
                (const __attribute__((address_space(1))) void*)asrc,
                (__attribute__((address_space(3))) void*)((char*)lds_a + (j * 4 + w) * 1024),
                16, 0, 0);
            const char* bsrc = (const char*)BT +
                ((size_t)(col0 + r) * K + k0) * 2 + cc * 16;
            __builtin_amdgcn_global_load_lds(
                (const __attribute__((address_space(1))) void*)bsrc,
                (__attribute__((address_space(3))) void*)((char*)lds_b + (j * 4 + w) * 1024),
                16, 0, 0);
        }
        __syncthreads();

        #pragma unroll
        for (int kk = 0; kk < 2; ++kk) {
            bf16x8 af[4], bfr[4];
            #pragma unroll
            for (int m = 0; m < 4; ++m) {
                int r = wr + m * 16 + (lane & 15);
                int byteoff = r * 128 + ((kk * 64 + (lane >> 4) * 16) ^ ((r & 7) << 4));
                af[m] = *reinterpret_cast<const bf16x8*>((const char*)lds_a + byteoff);
            }
            #pragma unroll
            for (int n = 0; n < 4; ++n) {
                int r = wc + n * 16 + (lane & 15);
                int byteoff = r * 128 + ((kk * 64 + (lane >> 4) * 16) ^ ((r & 7) << 4));
                bfr[n] = *reinterpret_cast<const bf16x8*>((const char*)lds_b + byteoff);
            }
            #pragma unroll
            for (int m = 0; m < 4; ++m)
                #pragma unroll
                for (int n = 0; n < 4; ++n)
                    acc[m][n] = __builtin_amdgcn_mfma_f32_16x16x32_bf16(
                        af[m], bfr[n], acc[m][n], 0, 0, 0);
        }
        __syncthreads();
    }

    #pragma unroll
    for (int m = 0; m < 4; ++m) {
        int rbase = row0 + wr + m * 16 + (lane >> 4) * 4;
        #pragma unroll
        for (int n = 0; n < 4; ++n) {
            int col = col0 + wc + n * 16 + (lane & 15);
            #pragma unroll
            for (int r = 0; r < 4; ++r) {
                if (OBF) {
                    ((unsigned short*)Cv)[(size_t)(rbase + r) * ldc + col] =
                        f2bf(acc[m][n][r]);
                } else {
                    ((float*)Cv)[(size_t)(rbase + r) * ldc + col] = acc[m][n][r];
                }
            }
        }
    }
}

// ---------------------------------------------------------------------------
// MFMA split-K x_proj: part[z] = ucbf[:, kb:kb+256] @ wXT^T (N=96 of 128).
// Grid (1, M/128, XKS). fp32 partials [XKS][MROWS][96].
// ---------------------------------------------------------------------------
__global__ __launch_bounds__(256) void xproj_splitk_bb_kernel(
    const unsigned short* __restrict__ Abf, const unsigned short* __restrict__ BT,
    float* __restrict__ part)
{
    __shared__ unsigned short lds_a[128 * 64];
    __shared__ unsigned short lds_b[128 * 64];

    const int tid  = threadIdx.x;
    const int lane = tid & 63;
    const int w    = tid >> 6;
    const int wr   = (w >> 1) * 64;
    const int wc   = (w & 1) * 64;
    const int row0 = blockIdx.y * 128;
    const int kb   = blockIdx.z * XKCH;
    const int K    = DINNER;

    f32x4 acc[4][4];
    #pragma unroll
    for (int m = 0; m < 4; ++m)
        #pragma unroll
        for (int n = 0; n < 4; ++n)
            acc[m][n] = (f32x4){0.f, 0.f, 0.f, 0.f};

    for (int k0 = kb; k0 < kb + XKCH; k0 += 64) {
        #pragma unroll
        for (int j = 0; j < 4; ++j) {
            int c  = (j * 4 + w) * 64 + lane;
            int r  = c >> 3;
            int cc = c & 7;
            const char* asrc = (const char*)Abf +
                ((size_t)(row0 + r) * K + k0) * 2 + cc * 16;
            __builtin_amdgcn_global_load_lds(
                (const __attribute__((address_space(1))) void*)asrc,
                (__attribute__((address_space(3))) void*)((char*)lds_a + (j * 4 + w) * 1024),
                16, 0, 0);
            const char* bsrc = (const char*)BT +
                ((size_t)r * K + k0) * 2 + cc * 16;
            __builtin_amdgcn_global_load_lds(
                (const __attribute__((address_space(1))) void*)bsrc,
                (__attribute__((address_space(3))) void*)((char*)lds_b + (j * 4 + w) * 1024),
                16, 0, 0);
        }
        __syncthreads();

        #pragma unroll
        for (int kk = 0; kk < 2; ++kk) {
            bf16x8 af[4], bfr[4];
            #pragma unroll
            for (int m = 0; m < 4; ++m) {
                int r = wr + m * 16 + (lane & 15);
                int byteoff = r * 128 + ((kk * 64 + (lane >> 4) * 16) ^ ((r & 7) << 4));
                af[m] = *reinterpret_cast<const bf16x8*>((const char*)lds_a + byteoff);
            }
            #pragma unroll
            for (int n = 0; n < 4; ++n) {
                int r = wc + n * 16 + (lane & 15);
                int byteoff = r * 128 + ((kk * 64 + (lane >> 4) * 16) ^ ((r & 7) << 4));
                bfr[n] = *reinterpret_cast<const bf16x8*>((const char*)lds_b + byteoff);
            }
            #pragma unroll
            for (int m = 0; m < 4; ++m)
                #pragma unroll
                for (int n = 0; n < 4; ++n)
                    acc[m][n] = __builtin_amdgcn_mfma_f32_16x16x32_bf16(
                        af[m], bfr[n], acc[m][n], 0, 0, 0);
        }
        __syncthreads();
    }

    float* pbase = part + (size_t)blockIdx.z * MROWS * 96;
    #pragma unroll
    for (int m = 0; m < 4; ++m) {
        int rbase = row0 + wr + m * 16 + (lane >> 4) * 4;
        #pragma unroll
        for (int n = 0; n < 4; ++n) {
            int col = wc + n * 16 + (lane & 15);
            if (col < 96) {
                #pragma unroll
                for (int r = 0; r < 4; ++r)
                    pbase[(size_t)(rbase + r) * 96 + col] = acc[m][n][r];
            }
        }
    }
}

// Reduce XKS partials -> dbc fp32; cols<64 also emitted as pre-swizzled bf16.
__global__ __launch_bounds__(256) void xproj_reduce_kernel(
    const float* __restrict__ part, float* __restrict__ dbc,
    unsigned short* __restrict__ dtlo)
{
    int gid = blockIdx.x * 256 + threadIdx.x;
    float s = 0.f;
    #pragma unroll
    for (int k = 0; k < XKS; ++k)
        s += part[(size_t)k * MROWS * 96 + gid];
    dbc[gid] = s;
    int row = gid / 96;
    int col = gid - row * 96;
    if (col < 64)
        dtlo[(size_t)row * 64 + (col ^ ((row & 7) << 3))] = f2bf(s);
}

// ---------------------------------------------------------------------------
// dt_proj MFMA (K=64, one K-step): dtb = bf16(softplus(dtlo @ wDT^T + bias)).
// ---------------------------------------------------------------------------
__global__ __launch_bounds__(256) void gemm_dtproj_bb_kernel(
    const unsigned short* __restrict__ Abf, const unsigned short* __restrict__ BT,
    const float* __restrict__ bias, unsigned short* __restrict__ C)
{
    __shared__ unsigned short lds_a[128 * 64];
    __shared__ unsigned short lds_b[128 * 64];

    const int tid  = threadIdx.x;
    const int lane = tid & 63;
    const int w    = tid >> 6;
    const int wr   = (w >> 1) * 64;
    const int wc   = (w & 1) * 64;
    const int row0 = blockIdx.y * 128;
    const int col0 = blockIdx.x * 128;

    f32x4 acc[4][4];
    #pragma unroll
    for (int m = 0; m < 4; ++m)
        #pragma unroll
        for (int n = 0; n < 4; ++n)
            acc[m][n] = (f32x4){0.f, 0.f, 0.f, 0.f};

    #pragma unroll
    for (int j = 0; j < 4; ++j) {
        int c  = (j * 4 + w) * 64 + lane;
        int r  = c >> 3;
        int cc = c & 7;
        const char* asrc = (const char*)Abf + ((size_t)(row0 + r) * 64) * 2 + cc * 16;
        __builtin_amdgcn_global_load_lds(
            (const __attribute__((address_space(1))) void*)asrc,
            (__attribute__((address_space(3))) void*)((char*)lds_a + (j * 4 + w) * 1024),
            16, 0, 0);
        const char* bsrc = (const char*)BT + ((size_t)(col0 + r) * 64) * 2 + cc * 16;
        __builtin_amdgcn_global_load_lds(
            (const __attribute__((address_space(1))) void*)bsrc,
            (__attribute__((address_space(3))) void*)((char*)lds_b + (j * 4 + w) * 1024),
            16, 0, 0);
    }
    __syncthreads();

    #pragma unroll
    for (int kk = 0; kk < 2; ++kk) {
        bf16x8 af[4], bfr[4];
        #pragma unroll
        for (int m = 0; m < 4; ++m) {
            int r = wr + m * 16 + (lane & 15);
            int byteoff = r * 128 + ((kk * 64 + (lane >> 4) * 16) ^ ((r & 7) << 4));
            af[m] = *reinterpret_cast<const bf16x8*>((const char*)lds_a + byteoff);
        }
        #pragma unroll
        for (int n = 0; n < 4; ++n) {
            int r = wc + n * 16 + (lane & 15);
            int byteoff = r * 128 + ((kk * 64 + (lane >> 4) * 16) ^ ((r & 7) << 4));
            bfr[n] = *reinterpret_cast<const bf16x8*>((const char*)lds_b + byteoff);
        }
        #pragma unroll
        for (int m = 0; m < 4; ++m)
            #pragma unroll
            for (int n = 0; n < 4; ++n)
                acc[m][n] = __builtin_amdgcn_mfma_f32_16x16x32_bf16(
                    af[m], bfr[n], acc[m][n], 0, 0, 0);
    }

    #pragma unroll
    for (int m = 0; m < 4; ++m) {
        int rbase = row0 + wr + m * 16 + (lane >> 4) * 4;
        #pragma unroll
        for (int n = 0; n < 4; ++n) {
            int col = col0 + wc + n * 16 + (lane & 15);
            float bv = bias[col];
            #pragma unroll
            for (int r = 0; r < 4; ++r) {
                float v = acc[m][n][r] + bv;
                v = (v > 20.0f) ? v : log1pf(__expf(v));
                C[(size_t)(rbase + r) * DINNER + col] = f2bf(v);
            }
        }
    }
}

// ---------------------------------------------------------------------------
// Causal depthwise conv1d (width 4) + bias + silu, bf16 in -> swizzled bf16 out.
// ---------------------------------------------------------------------------
__global__ __launch_bounds__(256) void conv_silu_kernel(
    const unsigned short* __restrict__ xzb, const float* __restrict__ cw,
    const float* __restrict__ cb, unsigned short* __restrict__ ucbf)
{
    int gid = blockIdx.x * 256 + threadIdx.x;     // over MROWS * (DINNER/8)
    int row = gid >> 8;
    int d0  = (gid & 255) * 8;
    int t = row & (LSEQ - 1);

    uint4 uv[4];
    #pragma unroll
    for (int k = 0; k < 4; ++k) {
        if (t - 3 + k >= 0)
            uv[k] = *reinterpret_cast<const uint4*>(
                xzb + (size_t)(row + k - 3) * 4096 + d0);
        else
            uv[k] = (uint4){0u, 0u, 0u, 0u};
    }

    float v[8];
    #pragma unroll
    for (int i = 0; i < 8; ++i) {
        float acc = cb[d0 + i];
        float4 wv = *reinterpret_cast<const float4*>(cw + (size_t)(d0 + i) * 4);
        float wk[4] = {wv.x, wv.y, wv.z, wv.w};
        #pragma unroll
        for (int k = 0; k < 4; ++k) {
            unsigned int word = (&uv[k].x)[i >> 1];
            float u = __uint_as_float((i & 1) ? (word & 0xffff0000u) : (word << 16));
            acc = fmaf(u, wk[k], acc);
        }
        v[i] = acc * sigmoidf_(acc);
    }

    uint4 o;
    o.x = (unsigned)f2bf(v[0]) | ((unsigned)f2bf(v[1]) << 16);
    o.y = (unsigned)f2bf(v[2]) | ((unsigned)f2bf(v[3]) << 16);
    o.z = (unsigned)f2bf(v[4]) | ((unsigned)f2bf(v[5]) << 16);
    o.w = (unsigned)f2bf(v[6]) | ((unsigned)f2bf(v[7]) << 16);
    *reinterpret_cast<uint4*>(
        ucbf + (size_t)row * DINNER + (d0 ^ ((row & 7) << 3))) = o;
}

// ---------------------------------------------------------------------------
// Chunked scan, pass A: local end-state E[16] and chunk decay P[n].
// u from swizzled bf16 ucbf; dt from dense bf16 dtb.
// ---------------------------------------------------------------------------
__global__ __launch_bounds__(256) void scan_partial_kernel(
    const unsigned short* __restrict__ dtb, const unsigned short* __restrict__ ucbf,
    const float* __restrict__ dbc, const float* __restrict__ A_log,
    float* __restrict__ Pbuf, float* __restrict__ Ebuf)
{
    __shared__ float sB[CHUNK][NSTATE];
    const int tid = threadIdx.x;
    const int c = blockIdx.x;
    const int b = blockIdx.z;
    const int d = blockIdx.y * 256 + tid;
    const size_t row0 = (size_t)b * LSEQ + c * CHUNK;

    {
        int s = tid >> 2, f = tid & 3;
        float4 v = *reinterpret_cast<const float4*>(dbc + (row0 + s) * 96 + 64 + f * 4);
        *reinterpret_cast<float4*>(&sB[s][f * 4]) = v;
    }

    float An2[NSTATE];
    #pragma unroll
    for (int k = 0; k < 4; ++k) {
        float4 a = *reinterpret_cast<const float4*>(A_log + (size_t)d * NSTATE + k * 4);
        An2[k*4+0] = -__expf(a.x) * LOG2E;
        An2[k*4+1] = -__expf(a.y) * LOG2E;
        An2[k*4+2] = -__expf(a.z) * LOG2E;
        An2[k*4+3] = -__expf(a.w) * LOG2E;
    }
    __syncthreads();

    float E[NSTATE];
    #pragma unroll
    for (int n = 0; n < NSTATE; ++n) E[n] = 0.f;
    float S = 0.f;

    float dtc = bf2f(dtb[row0 * DINNER + d]);
    float ucv = bf2f(ucbf[row0 * DINNER + d]);
    for (int s = 0; s < CHUNK; ++s) {
        float dtn = 0.f, un = 0.f;
        if (s + 1 < CHUNK) {
            dtn = bf2f(dtb[(row0 + s + 1) * DINNER + d]);
            un  = bf2f(ucbf[(row0 + s + 1) * DINNER + (d ^ (((s + 1) & 7) << 3))]);
        }
        S += dtc;
        float du = dtc * ucv;
        float Bv[NSTATE];
        #pragma unroll
        for (int k = 0; k < 4; ++k)
            *reinterpret_cast<float4*>(&Bv[k*4]) =
                *reinterpret_cast<const float4*>(&sB[s][k*4]);
        #pragma unroll
        for (int n = 0; n < NSTATE; ++n) {
            float q = EXP2F(dtc * An2[n]);
            E[n] = fmaf(E[n], q, du * Bv[n]);
        }
        dtc = dtn; ucv = un;
    }

    size_t base = (((size_t)c * BSZ + b) * DINNER + d) * NSTATE;
    #pragma unroll
    for (int n = 0; n < NSTATE; ++n) {
        Pbuf[base + n] = EXP2F(An2[n] * S);
        Ebuf[base + n] = E[n];
    }
}

// ---------------------------------------------------------------------------
// Pass B: exclusive scan over chunks per (b,d,n); h0 written IN PLACE over P.
// ---------------------------------------------------------------------------
__global__ __launch_bounds__(256) void scan_prefix_kernel(
    float* __restrict__ Pbuf, const float* __restrict__ Ebuf)
{
    const int gid = blockIdx.x * 256 + threadIdx.x;
    const size_t stride = (size_t)BSZ * DINNER * NSTATE;
    size_t idx = gid;
    float h = 0.f;
    for (int c = 0; c < NCHUNK; ++c) {
        float P = Pbuf[idx];
        float Ev = Ebuf[idx];
        Pbuf[idx] = h;
        h = fmaf(P, h, Ev);
        idx += stride;
    }
}

// ---------------------------------------------------------------------------
// Pass C: local scan seeded with h0; fuse y, skip, gate; emit swizzled bf16 ybf.
// ---------------------------------------------------------------------------
__global__ __launch_bounds__(256) void scan_final_kernel(
    const unsigned short* __restrict__ dtb, const unsigned short* __restrict__ ucbf,
    const unsigned short* __restrict__ xzb, const float* __restrict__ dbc,
    const float* __restrict__ A_log, const float* __restrict__ Dp,
    const float* __restrict__ H0, unsigned short* __restrict__ ybf)
{
    __shared__ float sBC[CHUNK][2 * NSTATE];
    const int tid = threadIdx.x;
    const int c = blockIdx.x;
    const int b = blockIdx.z;
    const int d = blockIdx.y * 256 + tid;
    const size_t row0 = (size_t)b * LSEQ + c * CHUNK;

    {
        #pragma unroll
        for (int i = 0; i < 2; ++i) {
            int j = tid * 2 + i;
            int s = j >> 3, f = j & 7;
            float4 v = *reinterpret_cast<const float4*>(dbc + (row0 + s) * 96 + 64 + f * 4);
            *reinterpret_cast<float4*>(&sBC[s][f * 4]) = v;
        }
    }

    float An2[NSTATE];
    #pragma unroll
    for (int k = 0; k < 4; ++k) {
        float4 a = *reinterpret_cast<const float4*>(A_log + (size_t)d * NSTATE + k * 4);
        An2[k*4+0] = -__expf(a.x) * LOG2E;
        An2[k*4+1] = -__expf(a.y) * LOG2E;
        An2[k*4+2] = -__expf(a.z) * LOG2E;
        An2[k*4+3] = -__expf(a.w) * LOG2E;
    }
    const float Dpd = Dp[d];

    float h[NSTATE];
    {
        size_t base = (((size_t)c * BSZ + b) * DINNER + d) * NSTATE;
        #pragma unroll
        for (int n = 0; n < NSTATE; ++n) h[n] = H0[base + n];
    }
    __syncthreads();

    float dtc = bf2f(dtb[row0 * DINNER + d]);
    float ucv = bf2f(ucbf[row0 * DINNER + d]);
    float zc  = bf2f(xzb[row0 * 4096 + 2048 + d]);
    for (int s = 0; s < CHUNK; ++s) {
        float dtn = 0.f, un = 0.f, zn = 0.f;
        if (s + 1 < CHUNK) {
            dtn = bf2f(dtb[(row0 + s + 1) * DINNER + d]);
            un  = bf2f(ucbf[(row0 + s + 1) * DINNER + (d ^ (((s + 1) & 7) << 3))]);
            zn  = bf2f(xzb[(row0 + s + 1) * 4096 + 2048 + d]);
        }
        float du = dtc * ucv;
        float Bv[NSTATE], Cv[NSTATE];
        #pragma unroll
        for (int k = 0; k < 4; ++k) {
            *reinterpret_cast<float4*>(&Bv[k*4]) =
                *reinterpret_cast<const float4*>(&sBC[s][k*4]);
            *reinterpret_cast<float4*>(&Cv[k*4]) =
                *reinterpret_cast<const float4*>(&sBC[s][16 + k*4]);
        }
        float y0 = 0.f, y1 = 0.f, y2 = 0.f, y3 = 0.f;
        #pragma unroll
        for (int n = 0; n < NSTATE; ++n) {
            float q = EXP2F(dtc * An2[n]);
            h[n] = fmaf(h[n], q, du * Bv[n]);
            float& yk = (n & 3) == 0 ? y0 : (n & 3) == 1 ? y1 : (n & 3) == 2 ? y2 : y3;
            yk = fmaf(h[n], Cv[n], yk);
        }
        float y = (y0 + y1) + (y2 + y3);
        float yg = (y + ucv * Dpd) * (zc * sigmoidf_(zc));
        ybf[(row0 + s) * DINNER + (d ^ ((s & 7) << 3))] = f2bf(yg);
        dtc = dtn; ucv = un; zc = zn;
    }
}

// ---------------------------------------------------------------------------
extern "C" void kernel_launch(void* const* d_in, const int* in_sizes, int n_in,
                              void* d_out, int out_size, void* d_ws, size_t ws_size,
                              hipStream_t stream)
{
    const float* x         = (const float*)d_in[0];
    const float* in_proj_w = (const float*)d_in[1];
    const float* conv_w    = (const float*)d_in[2];
    const float* conv_b    = (const float*)d_in[3];
    const float* x_proj_w  = (const float*)d_in[4];
    const float* dt_proj_w = (const float*)d_in[5];
    const float* dt_proj_b = (const float*)d_in[6];
    const float* A_log     = (const float*)d_in[7];
    const float* Dp        = (const float*)d_in[8];
    const float* out_proj_w= (const float*)d_in[9];
    float* out = (float*)d_out;

    // Workspace (208 MiB total):
    //  xzb   bf16 [8192][4096]  64 MiB @0     (in_proj out: u|z)
    //  dtb   bf16 [8192][2048]  32 MiB @64    (softplus dt)
    //  ucbf  bf16 [8192][2048]  32 MiB @96    (conv out, pre-swizzled)
    //  dbc   f32  [8192][96]     3 MiB @128
    //  wT_in 8 @131 | wT_out 4 @139 | wXT .5 @143 | wDT .25 @143.5
    //  U @144 (64 MiB union, lifetime-disjoint):
    //   xbf  U+0  16  [prep .. in_proj]
    //   part U+0  24  [splitk .. reduce]
    //   dtlo U+24  1  [reduce .. dtproj]
    //   Pbuf U+0  16  [scanA .. scanC]
    //   Ebuf U+16 16  [scanA .. prefix]
    //   ybf  U+32 32  [scanC .. out_proj]
    char* base = (char*)d_ws;
    unsigned short* xzb  = (unsigned short*)base;
    unsigned short* dtb  = (unsigned short*)(base + (64ull << 20));
    unsigned short* ucbf = (unsigned short*)(base + (96ull << 20));
    float* dbc           = (float*)(base + (128ull << 20));
    unsigned short* wT_in  = (unsigned short*)(base + (131ull << 20));
    unsigned short* wT_out = (unsigned short*)(base + (139ull << 20));
    unsigned short* wXT    = (unsigned short*)(base + (143ull << 20));
    unsigned short* wDT    = (unsigned short*)(base + (143ull << 20) + (512ull << 10));
    char* U = base + (144ull << 20);
    unsigned short* xbf  = (unsigned short*)U;
    float* part          = (float*)U;
    unsigned short* dtlo = (unsigned short*)(U + (24ull << 20));
    float* Pbuf          = (float*)U;
    float* Ebuf          = (float*)(U + (16ull << 20));
    unsigned short* ybf  = (unsigned short*)(U + (32ull << 20));

    dim3 blk(256);

    // 0) fused operand prep (cvt x + all 4 weight transposes)
    prep_kernel<<<dim3(5728), blk, 0, stream>>>(
        x, xbf, in_proj_w, wT_in, out_proj_w, wT_out, x_proj_w, wXT, dt_proj_w, wDT);

    // 1) xzb = bf16(x @ in_proj_w)
    gemm_bb_kernel<1><<<dim3(32, 64), blk, 0, stream>>>(
        xbf, wT_in, (void*)xzb, MROWS, 4096, 1024, 4096);

    // 2) ucbf = swz_bf16(silu(causal_conv(u) + conv_b))
    conv_silu_kernel<<<dim3((MROWS * (DINNER / 8)) / 256), blk, 0, stream>>>(
        xzb, conv_w, conv_b, ucbf);

    // 3) dbc = uc @ x_proj_w  (bf16 MFMA split-K + reduce; emits dtlo bf16)
    xproj_splitk_bb_kernel<<<dim3(1, 64, XKS), blk, 0, stream>>>(ucbf, wXT, part);
    xproj_reduce_kernel<<<dim3((MROWS * 96) / 256), blk, 0, stream>>>(part, dbc, dtlo);

    // 4) dtb = bf16(softplus(dtlo @ dt_proj_w + dt_proj_b))
    gemm_dtproj_bb_kernel<<<dim3(16, 64), blk, 0, stream>>>(dtlo, wDT, dt_proj_b, dtb);

    // 5) chunked selective scan (3 passes) -> ybf (swizzled bf16)
    scan_partial_kernel<<<dim3(NCHUNK, DINNER / 256, BSZ), blk, 0, stream>>>(
        dtb, ucbf, dbc, A_log, Pbuf, Ebuf);
    scan_prefix_kernel<<<dim3((BSZ * DINNER * NSTATE) / 256), blk, 0, stream>>>(Pbuf, Ebuf);
    scan_final_kernel<<<dim3(NCHUNK, DINNER / 256, BSZ), blk, 0, stream>>>(
        dtb, ucbf, xzb, dbc, A_log, Dp, Pbuf, ybf);

    // 6) out = y_gated @ out_proj_w (fp32 out)
    gemm_bb_kernel<0><<<dim3(8, 64), blk, 0, stream>>>(
        ybf, wT_out, (void*)out, MROWS, 1024, 2048, 1024);
}

// Round 10
// 392.680 us; speedup vs baseline: 8.3066x; 1.0286x over previous
//
#include <hip/hip_runtime.h>
#include <hip/hip_bf16.h>
#include <math.h>

#define BSZ 2
#define LSEQ 4096
#define DMODEL 1024
#define DINNER 2048
#define NSTATE 16
#define DTRANK 64
#define MROWS (BSZ * LSEQ)   // 8192
#define NCHUNK 64
#define CHUNK (LSEQ / NCHUNK)  // 64
#define XKS 8
#define XKCH (DINNER / XKS)    // 256

#if __has_builtin(__builtin_amdgcn_exp2f)
#define EXP2F(x) __builtin_amdgcn_exp2f(x)
#else
#define EXP2F(x) exp2f(x)
#endif
#define LOG2E 1.44269504088896f

typedef __attribute__((ext_vector_type(8))) short bf16x8;
typedef __attribute__((ext_vector_type(4))) float f32x4;

__device__ __forceinline__ float sigmoidf_(float x) { return 1.0f / (1.0f + __expf(-x)); }

__device__ __forceinline__ unsigned short f2bf(float x) {
    unsigned int u = __float_as_uint(x);
    u += 0x7fff + ((u >> 16) & 1);          // round-to-nearest-even
    return (unsigned short)(u >> 16);
}
__device__ __forceinline__ float bf2f(unsigned short b) {
    return __uint_as_float(((unsigned int)b) << 16);
}

// ---------------------------------------------------------------------------
// Fused operand prep (cvt x + 4 weight transposes), demuxed on blockIdx.
// Swizzle: element k of a 64-window stored at k ^ ((row&7)<<3).
// ---------------------------------------------------------------------------
__global__ __launch_bounds__(256) void prep_kernel(
    const float* __restrict__ x, unsigned short* __restrict__ xbf,
    const float* __restrict__ w_in, unsigned short* __restrict__ wT_in,
    const float* __restrict__ w_out, unsigned short* __restrict__ wT_out,
    const float* __restrict__ w_x, unsigned short* __restrict__ wXT,
    const float* __restrict__ w_dt, unsigned short* __restrict__ wDT)
{
    __shared__ float tile[64][65];
    const int id = blockIdx.x;
    const int t = threadIdx.x;

    if (id >= 1632) {   // cvt x -> xbf (K=1024, 128 groups of 8 per row)
        int gid = (id - 1632) * 256 + t;
        int m = gid >> 7;
        int g = gid & 127;
        size_t src = (size_t)m * 1024 + g * 8;
        float4 v0 = *reinterpret_cast<const float4*>(x + src);
        float4 v1 = *reinterpret_cast<const float4*>(x + src + 4);
        uint4 w;
        w.x = (unsigned)f2bf(v0.x) | ((unsigned)f2bf(v0.y) << 16);
        w.y = (unsigned)f2bf(v0.z) | ((unsigned)f2bf(v0.w) << 16);
        w.z = (unsigned)f2bf(v1.x) | ((unsigned)f2bf(v1.y) << 16);
        w.w = (unsigned)f2bf(v1.z) | ((unsigned)f2bf(v1.w) << 16);
        size_t dst = (size_t)m * 1024 + ((g * 8) ^ ((m & 7) << 3));
        *reinterpret_cast<uint4*>(xbf + dst) = w;
        return;
    }

    const float* W; unsigned short* WT; int K, Nsrc, nb, kb;
    if (id < 1024)      { W = w_in;  WT = wT_in;  K = 1024; Nsrc = 4096; nb = id & 63; kb = id >> 6; }
    else if (id < 1536) { int q = id - 1024; W = w_out; WT = wT_out; K = 2048; Nsrc = 1024; nb = q & 15; kb = q >> 4; }
    else if (id < 1600) { int q = id - 1536; W = w_x;   WT = wXT;   K = 2048; Nsrc = 96;   nb = q & 1;  kb = q >> 1; }
    else                { int q = id - 1600; W = w_dt;  WT = wDT;   K = 64;   Nsrc = 2048; nb = q;      kb = 0; }

    const int n0 = nb * 64;
    const int k0 = kb * 64;

    #pragma unroll
    for (int i = 0; i < 16; ++i) {
        int flat = i * 256 + t;
        int r = flat >> 6, c = flat & 63;
        tile[r][c] = (n0 + c < Nsrc) ? W[(size_t)(k0 + r) * Nsrc + n0 + c] : 0.0f;
    }
    __syncthreads();
    #pragma unroll
    for (int i = 0; i < 16; ++i) {
        int flat = i * 256 + t;
        int n = flat >> 6, k = flat & 63;
        int ks = k ^ ((n & 7) << 3);
        WT[(size_t)(n0 + n) * K + k0 + ks] = f2bf(tile[k][n]);
    }
}

// ---------------------------------------------------------------------------
// Pure-bf16 MFMA GEMM, issue-ahead double-buffered K-loop with counted vmcnt.
// Both operands pre-swizzled bf16 [.][K]; width-16 global_load_lds (8/thread
// per K-tile). 128x128 tile, BK=64. OBF=1: bf16 C; OBF=0: fp32 C.
// Race-freedom: STAGE(t+1 -> buf^1) targets a buffer whose last reads were
// before the PREVIOUS end-barrier; vmcnt(8) leaves only those 8 new loads
// in flight when computing t.
// ---------------------------------------------------------------------------
template<int OBF>
__global__ __launch_bounds__(256) void gemm_bb_kernel(
    const unsigned short* __restrict__ Abf, const unsigned short* __restrict__ BT,
    void* __restrict__ Cv, int M, int N, int K, int ldc)
{
    __shared__ unsigned short lds_a[2][128 * 64];
    __shared__ unsigned short lds_b[2][128 * 64];

    const int tid  = threadIdx.x;
    const int lane = tid & 63;
    const int w    = tid >> 6;
    const int wr   = (w >> 1) * 64;
    const int wc   = (w & 1) * 64;
    const int row0 = blockIdx.y * 128;
    const int col0 = blockIdx.x * 128;
    const int NT   = K >> 6;

    f32x4 acc[4][4];
    #pragma unroll
    for (int m = 0; m < 4; ++m)
        #pragma unroll
        for (int n = 0; n < 4; ++n)
            acc[m][n] = (f32x4){0.f, 0.f, 0.f, 0.f};

    auto STAGE = [&](int bi, int kt) {
        int k0 = kt << 6;
        #pragma unroll
        for (int j = 0; j < 4; ++j) {
            int c  = (j * 4 + w) * 64 + lane;
            int r  = c >> 3;
            int cc = c & 7;
            __builtin_amdgcn_global_load_lds(
                (const __attribute__((address_space(1))) void*)
                    ((const char*)Abf + ((size_t)(row0 + r) * K + k0) * 2 + cc * 16),
                (__attribute__((address_space(3))) void*)
                    ((char*)lds_a[bi] + (j * 4 + w) * 1024), 16, 0, 0);
            __builtin_amdgcn_global_load_lds(
                (const __attribute__((address_space(1))) void*)
                    ((const char*)BT + ((size_t)(col0 + r) * K + k0) * 2 + cc * 16),
                (__attribute__((address_space(3))) void*)
                    ((char*)lds_b[bi] + (j * 4 + w) * 1024), 16, 0, 0);
        }
    };

    STAGE(0, 0);
    for (int t = 0; t < NT; ++t) {
        const int cur = t & 1;
        if (t + 1 < NT) {
            STAGE(cur ^ 1, t + 1);
            asm volatile("s_waitcnt vmcnt(8)" ::: "memory");
        } else {
            asm volatile("s_waitcnt vmcnt(0)" ::: "memory");
        }
        __builtin_amdgcn_s_barrier();

        #pragma unroll
        for (int kk = 0; kk < 2; ++kk) {
            bf16x8 af[4], bfr[4];
            #pragma unroll
            for (int m = 0; m < 4; ++m) {
                int r = wr + m * 16 + (lane & 15);
                int byteoff = r * 128 + ((kk * 64 + (lane >> 4) * 16) ^ ((r & 7) << 4));
                af[m] = *reinterpret_cast<const bf16x8*>((const char*)lds_a[cur] + byteoff);
            }
            #pragma unroll
            for (int n = 0; n < 4; ++n) {
                int r = wc + n * 16 + (lane & 15);
                int byteoff = r * 128 + ((kk * 64 + (lane >> 4) * 16) ^ ((r & 7) << 4));
                bfr[n] = *reinterpret_cast<const bf16x8*>((const char*)lds_b[cur] + byteoff);
            }
            #pragma unroll
            for (int m = 0; m < 4; ++m)
                #pragma unroll
                for (int n = 0; n < 4; ++n)
                    acc[m][n] = __builtin_amdgcn_mfma_f32_16x16x32_bf16(
                        af[m], bfr[n], acc[m][n], 0, 0, 0);
        }
        asm volatile("s_waitcnt lgkmcnt(0)" ::: "memory");
        __builtin_amdgcn_s_barrier();
    }

    #pragma unroll
    for (int m = 0; m < 4; ++m) {
        int rbase = row0 + wr + m * 16 + (lane >> 4) * 4;
        #pragma unroll
        for (int n = 0; n < 4; ++n) {
            int col = col0 + wc + n * 16 + (lane & 15);
            #pragma unroll
            for (int r = 0; r < 4; ++r) {
                if (OBF) {
                    ((unsigned short*)Cv)[(size_t)(rbase + r) * ldc + col] =
                        f2bf(acc[m][n][r]);
                } else {
                    ((float*)Cv)[(size_t)(rbase + r) * ldc + col] = acc[m][n][r];
                }
            }
        }
    }
}

// ---------------------------------------------------------------------------
// MFMA split-K x_proj with the same issue-ahead pipeline. NT = 4.
// part[z] = ucbf[:, kb:kb+256] @ wXT^T (N=96 of 128). Grid (1, M/128, XKS).
// ---------------------------------------------------------------------------
__global__ __launch_bounds__(256) void xproj_splitk_bb_kernel(
    const unsigned short* __restrict__ Abf, const unsigned short* __restrict__ BT,
    float* __restrict__ part)
{
    __shared__ unsigned short lds_a[2][128 * 64];
    __shared__ unsigned short lds_b[2][128 * 64];

    const int tid  = threadIdx.x;
    const int lane = tid & 63;
    const int w    = tid >> 6;
    const int wr   = (w >> 1) * 64;
    const int wc   = (w & 1) * 64;
    const int row0 = blockIdx.y * 128;
    const int kb   = blockIdx.z * XKCH;
    const int K    = DINNER;
    const int NT   = XKCH >> 6;   // 4

    f32x4 acc[4][4];
    #pragma unroll
    for (int m = 0; m < 4; ++m)
        #pragma unroll
        for (int n = 0; n < 4; ++n)
            acc[m][n] = (f32x4){0.f, 0.f, 0.f, 0.f};

    auto STAGE = [&](int bi, int kt) {
        int k0 = kb + (kt << 6);
        #pragma unroll
        for (int j = 0; j < 4; ++j) {
            int c  = (j * 4 + w) * 64 + lane;
            int r  = c >> 3;
            int cc = c & 7;
            __builtin_amdgcn_global_load_lds(
                (const __attribute__((address_space(1))) void*)
                    ((const char*)Abf + ((size_t)(row0 + r) * K + k0) * 2 + cc * 16),
                (__attribute__((address_space(3))) void*)
                    ((char*)lds_a[bi] + (j * 4 + w) * 1024), 16, 0, 0);
            __builtin_amdgcn_global_load_lds(
                (const __attribute__((address_space(1))) void*)
                    ((const char*)BT + ((size_t)r * K + k0) * 2 + cc * 16),
                (__attribute__((address_space(3))) void*)
                    ((char*)lds_b[bi] + (j * 4 + w) * 1024), 16, 0, 0);
        }
    };

    STAGE(0, 0);
    for (int t = 0; t < NT; ++t) {
        const int cur = t & 1;
        if (t + 1 < NT) {
            STAGE(cur ^ 1, t + 1);
            asm volatile("s_waitcnt vmcnt(8)" ::: "memory");
        } else {
            asm volatile("s_waitcnt vmcnt(0)" ::: "memory");
        }
        __builtin_amdgcn_s_barrier();

        #pragma unroll
        for (int kk = 0; kk < 2; ++kk) {
            bf16x8 af[4], bfr[4];
            #pragma unroll
            for (int m = 0; m < 4; ++m) {
                int r = wr + m * 16 + (lane & 15);
                int byteoff = r * 128 + ((kk * 64 + (lane >> 4) * 16) ^ ((r & 7) << 4));
                af[m] = *reinterpret_cast<const bf16x8*>((const char*)lds_a[cur] + byteoff);
            }
            #pragma unroll
            for (int n = 0; n < 4; ++n) {
                int r = wc + n * 16 + (lane & 15);
                int byteoff = r * 128 + ((kk * 64 + (lane >> 4) * 16) ^ ((r & 7) << 4));
                bfr[n] = *reinterpret_cast<const bf16x8*>((const char*)lds_b[cur] + byteoff);
            }
            #pragma unroll
            for (int m = 0; m < 4; ++m)
                #pragma unroll
                for (int n = 0; n < 4; ++n)
                    acc[m][n] = __builtin_amdgcn_mfma_f32_16x16x32_bf16(
                        af[m], bfr[n], acc[m][n], 0, 0, 0);
        }
        asm volatile("s_waitcnt lgkmcnt(0)" ::: "memory");
        __builtin_amdgcn_s_barrier();
    }

    float* pbase = part + (size_t)blockIdx.z * MROWS * 96;
    #pragma unroll
    for (int m = 0; m < 4; ++m) {
        int rbase = row0 + wr + m * 16 + (lane >> 4) * 4;
        #pragma unroll
        for (int n = 0; n < 4; ++n) {
            int col = wc + n * 16 + (lane & 15);
            if (col < 96) {
                #pragma unroll
                for (int r = 0; r < 4; ++r)
                    pbase[(size_t)(rbase + r) * 96 + col] = acc[m][n][r];
            }
        }
    }
}

// Reduce XKS partials -> dbc fp32; cols<64 also emitted as pre-swizzled bf16.
__global__ __launch_bounds__(256) void xproj_reduce_kernel(
    const float* __restrict__ part, float* __restrict__ dbc,
    unsigned short* __restrict__ dtlo)
{
    int gid = blockIdx.x * 256 + threadIdx.x;
    float s = 0.f;
    #pragma unroll
    for (int k = 0; k < XKS; ++k)
        s += part[(size_t)k * MROWS * 96 + gid];
    dbc[gid] = s;
    int row = gid / 96;
    int col = gid - row * 96;
    if (col < 64)
        dtlo[(size_t)row * 64 + (col ^ ((row & 7) << 3))] = f2bf(s);
}

// ---------------------------------------------------------------------------
// dt_proj MFMA (K=64, one K-step): dtb = bf16(softplus(dtlo @ wDT^T + bias)).
// ---------------------------------------------------------------------------
__global__ __launch_bounds__(256) void gemm_dtproj_bb_kernel(
    const unsigned short* __restrict__ Abf, const unsigned short* __restrict__ BT,
    const float* __restrict__ bias, unsigned short* __restrict__ C)
{
    __shared__ unsigned short lds_a[128 * 64];
    __shared__ unsigned short lds_b[128 * 64];

    const int tid  = threadIdx.x;
    const int lane = tid & 63;
    const int w    = tid >> 6;
    const int wr   = (w >> 1) * 64;
    const int wc   = (w & 1) * 64;
    const int row0 = blockIdx.y * 128;
    const int col0 = blockIdx.x * 128;

    f32x4 acc[4][4];
    #pragma unroll
    for (int m = 0; m < 4; ++m)
        #pragma unroll
        for (int n = 0; n < 4; ++n)
            acc[m][n] = (f32x4){0.f, 0.f, 0.f, 0.f};

    #pragma unroll
    for (int j = 0; j < 4; ++j) {
        int c  = (j * 4 + w) * 64 + lane;
        int r  = c >> 3;
        int cc = c & 7;
        const char* asrc = (const char*)Abf + ((size_t)(row0 + r) * 64) * 2 + cc * 16;
        __builtin_amdgcn_global_load_lds(
            (const __attribute__((address_space(1))) void*)asrc,
            (__attribute__((address_space(3))) void*)((char*)lds_a + (j * 4 + w) * 1024),
            16, 0, 0);
        const char* bsrc = (const char*)BT + ((size_t)(col0 + r) * 64) * 2 + cc * 16;
        __builtin_amdgcn_global_load_lds(
            (const __attribute__((address_space(1))) void*)bsrc,
            (__attribute__((address_space(3))) void*)((char*)lds_b + (j * 4 + w) * 1024),
            16, 0, 0);
    }
    __syncthreads();

    #pragma unroll
    for (int kk = 0; kk < 2; ++kk) {
        bf16x8 af[4], bfr[4];
        #pragma unroll
        for (int m = 0; m < 4; ++m) {
            int r = wr + m * 16 + (lane & 15);
            int byteoff = r * 128 + ((kk * 64 + (lane >> 4) * 16) ^ ((r & 7) << 4));
            af[m] = *reinterpret_cast<const bf16x8*>((const char*)lds_a + byteoff);
        }
        #pragma unroll
        for (int n = 0; n < 4; ++n) {
            int r = wc + n * 16 + (lane & 15);
            int byteoff = r * 128 + ((kk * 64 + (lane >> 4) * 16) ^ ((r & 7) << 4));
            bfr[n] = *reinterpret_cast<const bf16x8*>((const char*)lds_b + byteoff);
        }
        #pragma unroll
        for (int m = 0; m < 4; ++m)
            #pragma unroll
            for (int n = 0; n < 4; ++n)
                acc[m][n] = __builtin_amdgcn_mfma_f32_16x16x32_bf16(
                    af[m], bfr[n], acc[m][n], 0, 0, 0);
    }

    #pragma unroll
    for (int m = 0; m < 4; ++m) {
        int rbase = row0 + wr + m * 16 + (lane >> 4) * 4;
        #pragma unroll
        for (int n = 0; n < 4; ++n) {
            int col = col0 + wc + n * 16 + (lane & 15);
            float bv = bias[col];
            #pragma unroll
            for (int r = 0; r < 4; ++r) {
                float v = acc[m][n][r] + bv;
                v = (v > 20.0f) ? v : log1pf(__expf(v));
                C[(size_t)(rbase + r) * DINNER + col] = f2bf(v);
            }
        }
    }
}

// ---------------------------------------------------------------------------
// Causal depthwise conv1d (width 4) + bias + silu, bf16 in -> swizzled bf16 out.
// ---------------------------------------------------------------------------
__global__ __launch_bounds__(256) void conv_silu_kernel(
    const unsigned short* __restrict__ xzb, const float* __restrict__ cw,
    const float* __restrict__ cb, unsigned short* __restrict__ ucbf)
{
    int gid = blockIdx.x * 256 + threadIdx.x;     // over MROWS * (DINNER/8)
    int row = gid >> 8;
    int d0  = (gid & 255) * 8;
    int t = row & (LSEQ - 1);

    uint4 uv[4];
    #pragma unroll
    for (int k = 0; k < 4; ++k) {
        if (t - 3 + k >= 0)
            uv[k] = *reinterpret_cast<const uint4*>(
                xzb + (size_t)(row + k - 3) * 4096 + d0);
        else
            uv[k] = (uint4){0u, 0u, 0u, 0u};
    }

    float v[8];
    #pragma unroll
    for (int i = 0; i < 8; ++i) {
        float acc = cb[d0 + i];
        float4 wv = *reinterpret_cast<const float4*>(cw + (size_t)(d0 + i) * 4);
        float wk[4] = {wv.x, wv.y, wv.z, wv.w};
        #pragma unroll
        for (int k = 0; k < 4; ++k) {
            unsigned int word = (&uv[k].x)[i >> 1];
            float u = __uint_as_float((i & 1) ? (word & 0xffff0000u) : (word << 16));
            acc = fmaf(u, wk[k], acc);
        }
        v[i] = acc * sigmoidf_(acc);
    }

    uint4 o;
    o.x = (unsigned)f2bf(v[0]) | ((unsigned)f2bf(v[1]) << 16);
    o.y = (unsigned)f2bf(v[2]) | ((unsigned)f2bf(v[3]) << 16);
    o.z = (unsigned)f2bf(v[4]) | ((unsigned)f2bf(v[5]) << 16);
    o.w = (unsigned)f2bf(v[6]) | ((unsigned)f2bf(v[7]) << 16);
    *reinterpret_cast<uint4*>(
        ucbf + (size_t)row * DINNER + (d0 ^ ((row & 7) << 3))) = o;
}

// ---------------------------------------------------------------------------
// Chunked scan, pass A: local end-state E[16] and chunk decay P[n].
// ---------------------------------------------------------------------------
__global__ __launch_bounds__(256) void scan_partial_kernel(
    const unsigned short* __restrict__ dtb, const unsigned short* __restrict__ ucbf,
    const float* __restrict__ dbc, const float* __restrict__ A_log,
    float* __restrict__ Pbuf, float* __restrict__ Ebuf)
{
    __shared__ float sB[CHUNK][NSTATE];
    const int tid = threadIdx.x;
    const int c = blockIdx.x;
    const int b = blockIdx.z;
    const int d = blockIdx.y * 256 + tid;
    const size_t row0 = (size_t)b * LSEQ + c * CHUNK;

    {
        int s = tid >> 2, f = tid & 3;
        float4 v = *reinterpret_cast<const float4*>(dbc + (row0 + s) * 96 + 64 + f * 4);
        *reinterpret_cast<float4*>(&sB[s][f * 4]) = v;
    }

    float An2[NSTATE];
    #pragma unroll
    for (int k = 0; k < 4; ++k) {
        float4 a = *reinterpret_cast<const float4*>(A_log + (size_t)d * NSTATE + k * 4);
        An2[k*4+0] = -__expf(a.x) * LOG2E;
        An2[k*4+1] = -__expf(a.y) * LOG2E;
        An2[k*4+2] = -__expf(a.z) * LOG2E;
        An2[k*4+3] = -__expf(a.w) * LOG2E;
    }
    __syncthreads();

    float E[NSTATE];
    #pragma unroll
    for (int n = 0; n < NSTATE; ++n) E[n] = 0.f;
    float S = 0.f;

    float dtc = bf2f(dtb[row0 * DINNER + d]);
    float ucv = bf2f(ucbf[row0 * DINNER + d]);
    for (int s = 0; s < CHUNK; ++s) {
        float dtn = 0.f, un = 0.f;
        if (s + 1 < CHUNK) {
            dtn = bf2f(dtb[(row0 + s + 1) * DINNER + d]);
            un  = bf2f(ucbf[(row0 + s + 1) * DINNER + (d ^ (((s + 1) & 7) << 3))]);
        }
        S += dtc;
        float du = dtc * ucv;
        float Bv[NSTATE];
        #pragma unroll
        for (int k = 0; k < 4; ++k)
            *reinterpret_cast<float4*>(&Bv[k*4]) =
                *reinterpret_cast<const float4*>(&sB[s][k*4]);
        #pragma unroll
        for (int n = 0; n < NSTATE; ++n) {
            float q = EXP2F(dtc * An2[n]);
            E[n] = fmaf(E[n], q, du * Bv[n]);
        }
        dtc = dtn; ucv = un;
    }

    size_t base = (((size_t)c * BSZ + b) * DINNER + d) * NSTATE;
    #pragma unroll
    for (int n = 0; n < NSTATE; ++n) {
        Pbuf[base + n] = EXP2F(An2[n] * S);
        Ebuf[base + n] = E[n];
    }
}

// ---------------------------------------------------------------------------
// Pass B: exclusive scan over chunks per (b,d,n); h0 written IN PLACE over P.
// ---------------------------------------------------------------------------
__global__ __launch_bounds__(256) void scan_prefix_kernel(
    float* __restrict__ Pbuf, const float* __restrict__ Ebuf)
{
    const int gid = blockIdx.x * 256 + threadIdx.x;
    const size_t stride = (size_t)BSZ * DINNER * NSTATE;
    size_t idx = gid;
    float h = 0.f;
    for (int c = 0; c < NCHUNK; ++c) {
        float P = Pbuf[idx];
        float Ev = Ebuf[idx];
        Pbuf[idx] = h;
        h = fmaf(P, h, Ev);
        idx += stride;
    }
}

// ---------------------------------------------------------------------------
// Pass C: local scan seeded with h0; fuse y, skip, gate; emit swizzled bf16 ybf.
// ---------------------------------------------------------------------------
__global__ __launch_bounds__(256) void scan_final_kernel(
    const unsigned short* __restrict__ dtb, const unsigned short* __restrict__ ucbf,
    const unsigned short* __restrict__ xzb, const float* __restrict__ dbc,
    const float* __restrict__ A_log, const float* __restrict__ Dp,
    const float* __restrict__ H0, unsigned short* __restrict__ ybf)
{
    __shared__ float sBC[CHUNK][2 * NSTATE];
    const int tid = threadIdx.x;
    const int c = blockIdx.x;
    const int b = blockIdx.z;
    const int d = blockIdx.y * 256 + tid;
    const size_t row0 = (size_t)b * LSEQ + c * CHUNK;

    {
        #pragma unroll
        for (int i = 0; i < 2; ++i) {
            int j = tid * 2 + i;
            int s = j >> 3, f = j & 7;
            float4 v = *reinterpret_cast<const float4*>(dbc + (row0 + s) * 96 + 64 + f * 4);
            *reinterpret_cast<float4*>(&sBC[s][f * 4]) = v;
        }
    }

    float An2[NSTATE];
    #pragma unroll
    for (int k = 0; k < 4; ++k) {
        float4 a = *reinterpret_cast<const float4*>(A_log + (size_t)d * NSTATE + k * 4);
        An2[k*4+0] = -__expf(a.x) * LOG2E;
        An2[k*4+1] = -__expf(a.y) * LOG2E;
        An2[k*4+2] = -__expf(a.z) * LOG2E;
        An2[k*4+3] = -__expf(a.w) * LOG2E;
    }
    const float Dpd = Dp[d];

    float h[NSTATE];
    {
        size_t base = (((size_t)c * BSZ + b) * DINNER + d) * NSTATE;
        #pragma unroll
        for (int n = 0; n < NSTATE; ++n) h[n] = H0[base + n];
    }
    __syncthreads();

    float dtc = bf2f(dtb[row0 * DINNER + d]);
    float ucv = bf2f(ucbf[row0 * DINNER + d]);
    float zc  = bf2f(xzb[row0 * 4096 + 2048 + d]);
    for (int s = 0; s < CHUNK; ++s) {
        float dtn = 0.f, un = 0.f, zn = 0.f;
        if (s + 1 < CHUNK) {
            dtn = bf2f(dtb[(row0 + s + 1) * DINNER + d]);
            un  = bf2f(ucbf[(row0 + s + 1) * DINNER + (d ^ (((s + 1) & 7) << 3))]);
            zn  = bf2f(xzb[(row0 + s + 1) * 4096 + 2048 + d]);
        }
        float du = dtc * ucv;
        float Bv[NSTATE], Cv[NSTATE];
        #pragma unroll
        for (int k = 0; k < 4; ++k) {
            *reinterpret_cast<float4*>(&Bv[k*4]) =
                *reinterpret_cast<const float4*>(&sBC[s][k*4]);
            *reinterpret_cast<float4*>(&Cv[k*4]) =
                *reinterpret_cast<const float4*>(&sBC[s][16 + k*4]);
        }
        float y0 = 0.f, y1 = 0.f, y2 = 0.f, y3 = 0.f;
        #pragma unroll
        for (int n = 0; n < NSTATE; ++n) {
            float q = EXP2F(dtc * An2[n]);
            h[n] = fmaf(h[n], q, du * Bv[n]);
            float& yk = (n & 3) == 0 ? y0 : (n & 3) == 1 ? y1 : (n & 3) == 2 ? y2 : y3;
            yk = fmaf(h[n], Cv[n], yk);
        }
        float y = (y0 + y1) + (y2 + y3);
        float yg = (y + ucv * Dpd) * (zc * sigmoidf_(zc));
        ybf[(row0 + s) * DINNER + (d ^ ((s & 7) << 3))] = f2bf(yg);
        dtc = dtn; ucv = un; zc = zn;
    }
}

// ---------------------------------------------------------------------------
extern "C" void kernel_launch(void* const* d_in, const int* in_sizes, int n_in,
                              void* d_out, int out_size, void* d_ws, size_t ws_size,
                              hipStream_t stream)
{
    const float* x         = (const float*)d_in[0];
    const float* in_proj_w = (const float*)d_in[1];
    const float* conv_w    = (const float*)d_in[2];
    const float* conv_b    = (const float*)d_in[3];
    const float* x_proj_w  = (const float*)d_in[4];
    const float* dt_proj_w = (const float*)d_in[5];
    const float* dt_proj_b = (const float*)d_in[6];
    const float* A_log     = (const float*)d_in[7];
    const float* Dp        = (const float*)d_in[8];
    const float* out_proj_w= (const float*)d_in[9];
    float* out = (float*)d_out;

    // Workspace (208 MiB total) — same layout as round 9.
    char* base = (char*)d_ws;
    unsigned short* xzb  = (unsigned short*)base;
    unsigned short* dtb  = (unsigned short*)(base + (64ull << 20));
    unsigned short* ucbf = (unsigned short*)(base + (96ull << 20));
    float* dbc           = (float*)(base + (128ull << 20));
    unsigned short* wT_in  = (unsigned short*)(base + (131ull << 20));
    unsigned short* wT_out = (unsigned short*)(base + (139ull << 20));
    unsigned short* wXT    = (unsigned short*)(base + (143ull << 20));
    unsigned short* wDT    = (unsigned short*)(base + (143ull << 20) + (512ull << 10));
    char* U = base + (144ull << 20);
    unsigned short* xbf  = (unsigned short*)U;
    float* part          = (float*)U;
    unsigned short* dtlo = (unsigned short*)(U + (24ull << 20));
    float* Pbuf          = (float*)U;
    float* Ebuf          = (float*)(U + (16ull << 20));
    unsigned short* ybf  = (unsigned short*)(U + (32ull << 20));

    dim3 blk(256);

    // 0) fused operand prep (cvt x + all 4 weight transposes)
    prep_kernel<<<dim3(5728), blk, 0, stream>>>(
        x, xbf, in_proj_w, wT_in, out_proj_w, wT_out, x_proj_w, wXT, dt_proj_w, wDT);

    // 1) xzb = bf16(x @ in_proj_w)
    gemm_bb_kernel<1><<<dim3(32, 64), blk, 0, stream>>>(
        xbf, wT_in, (void*)xzb, MROWS, 4096, 1024, 4096);

    // 2) ucbf = swz_bf16(silu(causal_conv(u) + conv_b))
    conv_silu_kernel<<<dim3((MROWS * (DINNER / 8)) / 256), blk, 0, stream>>>(
        xzb, conv_w, conv_b, ucbf);

    // 3) dbc = uc @ x_proj_w  (bf16 MFMA split-K + reduce; emits dtlo bf16)
    xproj_splitk_bb_kernel<<<dim3(1, 64, XKS), blk, 0, stream>>>(ucbf, wXT, part);
    xproj_reduce_kernel<<<dim3((MROWS * 96) / 256), blk, 0, stream>>>(part, dbc, dtlo);

    // 4) dtb = bf16(softplus(dtlo @ dt_proj_w + dt_proj_b))
    gemm_dtproj_bb_kernel<<<dim3(16, 64), blk, 0, stream>>>(dtlo, wDT, dt_proj_b, dtb);

    // 5) chunked selective scan (3 passes) -> ybf (swizzled bf16)
    scan_partial_kernel<<<dim3(NCHUNK, DINNER / 256, BSZ), blk, 0, stream>>>(
        dtb, ucbf, dbc, A_log, Pbuf, Ebuf);
    scan_prefix_kernel<<<dim3((BSZ * DINNER * NSTATE) / 256), blk, 0, stream>>>(Pbuf, Ebuf);
    scan_final_kernel<<<dim3(NCHUNK, DINNER / 256, BSZ), blk, 0, stream>>>(
        dtb, ucbf, xzb, dbc, A_log, Dp, Pbuf, ybf);

    // 6) out = y_gated @ out_proj_w (fp32 out)
    gemm_bb_kernel<0><<<dim3(8, 64), blk, 0, stream>>>(
        ybf, wT_out, (void*)out, MROWS, 1024, 2048, 1024);
}

// Round 11
// 384.412 us; speedup vs baseline: 8.4853x; 1.0215x over previous
//
#include <hip/hip_runtime.h>
#include <hip/hip_bf16.h>
#include <math.h>

#define BSZ 2
#define LSEQ 4096
#define DMODEL 1024
#define DINNER 2048
#define NSTATE 16
#define DTRANK 64
#define MROWS (BSZ * LSEQ)   // 8192
#define NCHUNK 64
#define CHUNK (LSEQ / NCHUNK)  // 64
#define XKS 8
#define XKCH (DINNER / XKS)    // 256

#if __has_builtin(__builtin_amdgcn_exp2f)
#define EXP2F(x) __builtin_amdgcn_exp2f(x)
#else
#define EXP2F(x) exp2f(x)
#endif
#define LOG2E 1.44269504088896f

typedef __attribute__((ext_vector_type(8))) short bf16x8;
typedef __attribute__((ext_vector_type(4))) float f32x4;

__device__ __forceinline__ float sigmoidf_(float x) { return 1.0f / (1.0f + __expf(-x)); }

__device__ __forceinline__ unsigned short f2bf(float x) {
    unsigned int u = __float_as_uint(x);
    u += 0x7fff + ((u >> 16) & 1);          // round-to-nearest-even
    return (unsigned short)(u >> 16);
}
__device__ __forceinline__ float bf2f(unsigned short b) {
    return __uint_as_float(((unsigned int)b) << 16);
}

// ---------------------------------------------------------------------------
// Fused operand prep (cvt x + 4 weight transposes), demuxed on blockIdx.
// Swizzle: element k of a 64-window stored at k ^ ((row&7)<<3).
// ---------------------------------------------------------------------------
__global__ __launch_bounds__(256) void prep_kernel(
    const float* __restrict__ x, unsigned short* __restrict__ xbf,
    const float* __restrict__ w_in, unsigned short* __restrict__ wT_in,
    const float* __restrict__ w_out, unsigned short* __restrict__ wT_out,
    const float* __restrict__ w_x, unsigned short* __restrict__ wXT,
    const float* __restrict__ w_dt, unsigned short* __restrict__ wDT)
{
    __shared__ float tile[64][65];
    const int id = blockIdx.x;
    const int t = threadIdx.x;

    if (id >= 1632) {   // cvt x -> xbf (K=1024, 128 groups of 8 per row)
        int gid = (id - 1632) * 256 + t;
        int m = gid >> 7;
        int g = gid & 127;
        size_t src = (size_t)m * 1024 + g * 8;
        float4 v0 = *reinterpret_cast<const float4*>(x + src);
        float4 v1 = *reinterpret_cast<const float4*>(x + src + 4);
        uint4 w;
        w.x = (unsigned)f2bf(v0.x) | ((unsigned)f2bf(v0.y) << 16);
        w.y = (unsigned)f2bf(v0.z) | ((unsigned)f2bf(v0.w) << 16);
        w.z = (unsigned)f2bf(v1.x) | ((unsigned)f2bf(v1.y) << 16);
        w.w = (unsigned)f2bf(v1.z) | ((unsigned)f2bf(v1.w) << 16);
        size_t dst = (size_t)m * 1024 + ((g * 8) ^ ((m & 7) << 3));
        *reinterpret_cast<uint4*>(xbf + dst) = w;
        return;
    }

    const float* W; unsigned short* WT; int K, Nsrc, nb, kb;
    if (id < 1024)      { W = w_in;  WT = wT_in;  K = 1024; Nsrc = 4096; nb = id & 63; kb = id >> 6; }
    else if (id < 1536) { int q = id - 1024; W = w_out; WT = wT_out; K = 2048; Nsrc = 1024; nb = q & 15; kb = q >> 4; }
    else if (id < 1600) { int q = id - 1536; W = w_x;   WT = wXT;   K = 2048; Nsrc = 96;   nb = q & 1;  kb = q >> 1; }
    else                { int q = id - 1600; W = w_dt;  WT = wDT;   K = 64;   Nsrc = 2048; nb = q;      kb = 0; }

    const int n0 = nb * 64;
    const int k0 = kb * 64;

    #pragma unroll
    for (int i = 0; i < 16; ++i) {
        int flat = i * 256 + t;
        int r = flat >> 6, c = flat & 63;
        tile[r][c] = (n0 + c < Nsrc) ? W[(size_t)(k0 + r) * Nsrc + n0 + c] : 0.0f;
    }
    __syncthreads();
    #pragma unroll
    for (int i = 0; i < 16; ++i) {
        int flat = i * 256 + t;
        int n = flat >> 6, k = flat & 63;
        int ks = k ^ ((n & 7) << 3);
        WT[(size_t)(n0 + n) * K + k0 + ks] = f2bf(tile[k][n]);
    }
}

// ---------------------------------------------------------------------------
// Pure-bf16 MFMA GEMM (single-buffer; round-8 proven form — dbuf was neutral
// and cost occupancy). Both operands pre-swizzled bf16 [.][K], width-16
// global_load_lds. 128x128 tile, BK=64. OBF=1: bf16 C; OBF=0: fp32 C.
// ---------------------------------------------------------------------------
template<int OBF>
__global__ __launch_bounds__(256) void gemm_bb_kernel(
    const unsigned short* __restrict__ Abf, const unsigned short* __restrict__ BT,
    void* __restrict__ Cv, int M, int N, int K, int ldc)
{
    __shared__ unsigned short lds_a[128 * 64];
    __shared__ unsigned short lds_b[128 * 64];

    const int tid  = threadIdx.x;
    const int lane = tid & 63;
    const int w    = tid >> 6;
    const int wr   = (w >> 1) * 64;
    const int wc   = (w & 1) * 64;
    const int row0 = blockIdx.y * 128;
    const int col0 = blockIdx.x * 128;

    f32x4 acc[4][4];
    #pragma unroll
    for (int m = 0; m < 4; ++m)
        #pragma unroll
        for (int n = 0; n < 4; ++n)
            acc[m][n] = (f32x4){0.f, 0.f, 0.f, 0.f};

    for (int k0 = 0; k0 < K; k0 += 64) {
        #pragma unroll
        for (int j = 0; j < 4; ++j) {
            int c  = (j * 4 + w) * 64 + lane;
            int r  = c >> 3;
            int cc = c & 7;
            const char* asrc = (const char*)Abf +
                ((size_t)(row0 + r) * K + k0) * 2 + cc * 16;
            __builtin_amdgcn_global_load_lds(
                (const __attribute__((address_space(1))) void*)asrc,
                (__attribute__((address_space(3))) void*)((char*)lds_a + (j * 4 + w) * 1024),
                16, 0, 0);
            const char* bsrc = (const char*)BT +
                ((size_t)(col0 + r) * K + k0) * 2 + cc * 16;
            __builtin_amdgcn_global_load_lds(
                (const __attribute__((address_space(1))) void*)bsrc,
                (__attribute__((address_space(3))) void*)((char*)lds_b + (j * 4 + w) * 1024),
                16, 0, 0);
        }
        __syncthreads();

        #pragma unroll
        for (int kk = 0; kk < 2; ++kk) {
            bf16x8 af[4], bfr[4];
            #pragma unroll
            for (int m = 0; m < 4; ++m) {
                int r = wr + m * 16 + (lane & 15);
                int byteoff = r * 128 + ((kk * 64 + (lane >> 4) * 16) ^ ((r & 7) << 4));
                af[m] = *reinterpret_cast<const bf16x8*>((const char*)lds_a + byteoff);
            }
            #pragma unroll
            for (int n = 0; n < 4; ++n) {
                int r = wc + n * 16 + (lane & 15);
                int byteoff = r * 128 + ((kk * 64 + (lane >> 4) * 16) ^ ((r & 7) << 4));
                bfr[n] = *reinterpret_cast<const bf16x8*>((const char*)lds_b + byteoff);
            }
            #pragma unroll
            for (int m = 0; m < 4; ++m)
                #pragma unroll
                for (int n = 0; n < 4; ++n)
                    acc[m][n] = __builtin_amdgcn_mfma_f32_16x16x32_bf16(
                        af[m], bfr[n], acc[m][n], 0, 0, 0);
        }
        __syncthreads();
    }

    #pragma unroll
    for (int m = 0; m < 4; ++m) {
        int rbase = row0 + wr + m * 16 + (lane >> 4) * 4;
        #pragma unroll
        for (int n = 0; n < 4; ++n) {
            int col = col0 + wc + n * 16 + (lane & 15);
            #pragma unroll
            for (int r = 0; r < 4; ++r) {
                if (OBF) {
                    ((unsigned short*)Cv)[(size_t)(rbase + r) * ldc + col] =
                        f2bf(acc[m][n][r]);
                } else {
                    ((float*)Cv)[(size_t)(rbase + r) * ldc + col] = acc[m][n][r];
                }
            }
        }
    }
}

// ---------------------------------------------------------------------------
// MFMA split-K x_proj (single-buffer): part[z] = ucbf[:, kb:kb+256] @ wXT^T.
// Grid (1, M/128, XKS). fp32 partials [XKS][MROWS][96].
// ---------------------------------------------------------------------------
__global__ __launch_bounds__(256) void xproj_splitk_bb_kernel(
    const unsigned short* __restrict__ Abf, const unsigned short* __restrict__ BT,
    float* __restrict__ part)
{
    __shared__ unsigned short lds_a[128 * 64];
    __shared__ unsigned short lds_b[128 * 64];

    const int tid  = threadIdx.x;
    const int lane = tid & 63;
    const int w    = tid >> 6;
    const int wr   = (w >> 1) * 64;
    const int wc   = (w & 1) * 64;
    const int row0 = blockIdx.y * 128;
    const int kb   = blockIdx.z * XKCH;
    const int K    = DINNER;

    f32x4 acc[4][4];
    #pragma unroll
    for (int m = 0; m < 4; ++m)
        #pragma unroll
        for (int n = 0; n < 4; ++n)
            acc[m][n] = (f32x4){0.f, 0.f, 0.f, 0.f};

    for (int k0 = kb; k0 < kb + XKCH; k0 += 64) {
        #pragma unroll
        for (int j = 0; j < 4; ++j) {
            int c  = (j * 4 + w) * 64 + lane;
            int r  = c >> 3;
            int cc = c & 7;
            const char* asrc = (const char*)Abf +
                ((size_t)(row0 + r) * K + k0) * 2 + cc * 16;
            __builtin_amdgcn_global_load_lds(
                (const __attribute__((address_space(1))) void*)asrc,
                (__attribute__((address_space(3))) void*)((char*)lds_a + (j * 4 + w) * 1024),
                16, 0, 0);
            const char* bsrc = (const char*)BT +
                ((size_t)r * K + k0) * 2 + cc * 16;
            __builtin_amdgcn_global_load_lds(
                (const __attribute__((address_space(1))) void*)bsrc,
                (__attribute__((address_space(3))) void*)((char*)lds_b + (j * 4 + w) * 1024),
                16, 0, 0);
        }
        __syncthreads();

        #pragma unroll
        for (int kk = 0; kk < 2; ++kk) {
            bf16x8 af[4], bfr[4];
            #pragma unroll
            for (int m = 0; m < 4; ++m) {
                int r = wr + m * 16 + (lane & 15);
                int byteoff = r * 128 + ((kk * 64 + (lane >> 4) * 16) ^ ((r & 7) << 4));
                af[m] = *reinterpret_cast<const bf16x8*>((const char*)lds_a + byteoff);
            }
            #pragma unroll
            for (int n = 0; n < 4; ++n) {
                int r = wc + n * 16 + (lane & 15);
                int byteoff = r * 128 + ((kk * 64 + (lane >> 4) * 16) ^ ((r & 7) << 4));
                bfr[n] = *reinterpret_cast<const bf16x8*>((const char*)lds_b + byteoff);
            }
            #pragma unroll
            for (int m = 0; m < 4; ++m)
                #pragma unroll
                for (int n = 0; n < 4; ++n)
                    acc[m][n] = __builtin_amdgcn_mfma_f32_16x16x32_bf16(
                        af[m], bfr[n], acc[m][n], 0, 0, 0);
        }
        __syncthreads();
    }

    float* pbase = part + (size_t)blockIdx.z * MROWS * 96;
    #pragma unroll
    for (int m = 0; m < 4; ++m) {
        int rbase = row0 + wr + m * 16 + (lane >> 4) * 4;
        #pragma unroll
        for (int n = 0; n < 4; ++n) {
            int col = wc + n * 16 + (lane & 15);
            if (col < 96) {
                #pragma unroll
                for (int r = 0; r < 4; ++r)
                    pbase[(size_t)(rbase + r) * 96 + col] = acc[m][n][r];
            }
        }
    }
}

// Reduce XKS partials -> dbc fp32; cols<64 also emitted as pre-swizzled bf16.
__global__ __launch_bounds__(256) void xproj_reduce_kernel(
    const float* __restrict__ part, float* __restrict__ dbc,
    unsigned short* __restrict__ dtlo)
{
    int gid = blockIdx.x * 256 + threadIdx.x;
    float s = 0.f;
    #pragma unroll
    for (int k = 0; k < XKS; ++k)
        s += part[(size_t)k * MROWS * 96 + gid];
    dbc[gid] = s;
    int row = gid / 96;
    int col = gid - row * 96;
    if (col < 64)
        dtlo[(size_t)row * 64 + (col ^ ((row & 7) << 3))] = f2bf(s);
}

// ---------------------------------------------------------------------------
// dt_proj MFMA (K=64, one K-step): dtb = bf16(softplus(dtlo @ wDT^T + bias)).
// ---------------------------------------------------------------------------
__global__ __launch_bounds__(256) void gemm_dtproj_bb_kernel(
    const unsigned short* __restrict__ Abf, const unsigned short* __restrict__ BT,
    const float* __restrict__ bias, unsigned short* __restrict__ C)
{
    __shared__ unsigned short lds_a[128 * 64];
    __shared__ unsigned short lds_b[128 * 64];

    const int tid  = threadIdx.x;
    const int lane = tid & 63;
    const int w    = tid >> 6;
    const int wr   = (w >> 1) * 64;
    const int wc   = (w & 1) * 64;
    const int row0 = blockIdx.y * 128;
    const int col0 = blockIdx.x * 128;

    f32x4 acc[4][4];
    #pragma unroll
    for (int m = 0; m < 4; ++m)
        #pragma unroll
        for (int n = 0; n < 4; ++n)
            acc[m][n] = (f32x4){0.f, 0.f, 0.f, 0.f};

    #pragma unroll
    for (int j = 0; j < 4; ++j) {
        int c  = (j * 4 + w) * 64 + lane;
        int r  = c >> 3;
        int cc = c & 7;
        const char* asrc = (const char*)Abf + ((size_t)(row0 + r) * 64) * 2 + cc * 16;
        __builtin_amdgcn_global_load_lds(
            (const __attribute__((address_space(1))) void*)asrc,
            (__attribute__((address_space(3))) void*)((char*)lds_a + (j * 4 + w) * 1024),
            16, 0, 0);
        const char* bsrc = (const char*)BT + ((size_t)(col0 + r) * 64) * 2 + cc * 16;
        __builtin_amdgcn_global_load_lds(
            (const __attribute__((address_space(1))) void*)bsrc,
            (__attribute__((address_space(3))) void*)((char*)lds_b + (j * 4 + w) * 1024),
            16, 0, 0);
    }
    __syncthreads();

    #pragma unroll
    for (int kk = 0; kk < 2; ++kk) {
        bf16x8 af[4], bfr[4];
        #pragma unroll
        for (int m = 0; m < 4; ++m) {
            int r = wr + m * 16 + (lane & 15);
            int byteoff = r * 128 + ((kk * 64 + (lane >> 4) * 16) ^ ((r & 7) << 4));
            af[m] = *reinterpret_cast<const bf16x8*>((const char*)lds_a + byteoff);
        }
        #pragma unroll
        for (int n = 0; n < 4; ++n) {
            int r = wc + n * 16 + (lane & 15);
            int byteoff = r * 128 + ((kk * 64 + (lane >> 4) * 16) ^ ((r & 7) << 4));
            bfr[n] = *reinterpret_cast<const bf16x8*>((const char*)lds_b + byteoff);
        }
        #pragma unroll
        for (int m = 0; m < 4; ++m)
            #pragma unroll
            for (int n = 0; n < 4; ++n)
                acc[m][n] = __builtin_amdgcn_mfma_f32_16x16x32_bf16(
                    af[m], bfr[n], acc[m][n], 0, 0, 0);
    }

    #pragma unroll
    for (int m = 0; m < 4; ++m) {
        int rbase = row0 + wr + m * 16 + (lane >> 4) * 4;
        #pragma unroll
        for (int n = 0; n < 4; ++n) {
            int col = col0 + wc + n * 16 + (lane & 15);
            float bv = bias[col];
            #pragma unroll
            for (int r = 0; r < 4; ++r) {
                float v = acc[m][n][r] + bv;
                v = (v > 20.0f) ? v : log1pf(__expf(v));
                C[(size_t)(rbase + r) * DINNER + col] = f2bf(v);
            }
        }
    }
}

// ---------------------------------------------------------------------------
// Causal depthwise conv1d (width 4) + bias + silu, bf16 in -> swizzled bf16 out.
// ---------------------------------------------------------------------------
__global__ __launch_bounds__(256) void conv_silu_kernel(
    const unsigned short* __restrict__ xzb, const float* __restrict__ cw,
    const float* __restrict__ cb, unsigned short* __restrict__ ucbf)
{
    int gid = blockIdx.x * 256 + threadIdx.x;     // over MROWS * (DINNER/8)
    int row = gid >> 8;
    int d0  = (gid & 255) * 8;
    int t = row & (LSEQ - 1);

    uint4 uv[4];
    #pragma unroll
    for (int k = 0; k < 4; ++k) {
        if (t - 3 + k >= 0)
            uv[k] = *reinterpret_cast<const uint4*>(
                xzb + (size_t)(row + k - 3) * 4096 + d0);
        else
            uv[k] = (uint4){0u, 0u, 0u, 0u};
    }

    float v[8];
    #pragma unroll
    for (int i = 0; i < 8; ++i) {
        float acc = cb[d0 + i];
        float4 wv = *reinterpret_cast<const float4*>(cw + (size_t)(d0 + i) * 4);
        float wk[4] = {wv.x, wv.y, wv.z, wv.w};
        #pragma unroll
        for (int k = 0; k < 4; ++k) {
            unsigned int word = (&uv[k].x)[i >> 1];
            float u = __uint_as_float((i & 1) ? (word & 0xffff0000u) : (word << 16));
            acc = fmaf(u, wk[k], acc);
        }
        v[i] = acc * sigmoidf_(acc);
    }

    uint4 o;
    o.x = (unsigned)f2bf(v[0]) | ((unsigned)f2bf(v[1]) << 16);
    o.y = (unsigned)f2bf(v[2]) | ((unsigned)f2bf(v[3]) << 16);
    o.z = (unsigned)f2bf(v[4]) | ((unsigned)f2bf(v[5]) << 16);
    o.w = (unsigned)f2bf(v[6]) | ((unsigned)f2bf(v[7]) << 16);
    *reinterpret_cast<uint4*>(
        ucbf + (size_t)row * DINNER + (d0 ^ ((row & 7) << 3))) = o;
}

// ---------------------------------------------------------------------------
// Chunked scan, pass A. Fast path: if An2[n] == (n+1)*An2[0] (geometric
// structure, checked at runtime per channel), dA[n] = q^(n+1) via one exp2 +
// 15 mults instead of 16 exp2 (transcendentals are quarter-rate).
// Generic fallback keeps full per-n exp2.
// ---------------------------------------------------------------------------
__global__ __launch_bounds__(256) void scan_partial_kernel(
    const unsigned short* __restrict__ dtb, const unsigned short* __restrict__ ucbf,
    const float* __restrict__ dbc, const float* __restrict__ A_log,
    float* __restrict__ Pbuf, float* __restrict__ Ebuf)
{
    __shared__ float sB[CHUNK][NSTATE];
    const int tid = threadIdx.x;
    const int c = blockIdx.x;
    const int b = blockIdx.z;
    const int d = blockIdx.y * 256 + tid;
    const size_t row0 = (size_t)b * LSEQ + c * CHUNK;

    {
        int s = tid >> 2, f = tid & 3;
        float4 v = *reinterpret_cast<const float4*>(dbc + (row0 + s) * 96 + 64 + f * 4);
        *reinterpret_cast<float4*>(&sB[s][f * 4]) = v;
    }

    float An2[NSTATE];
    #pragma unroll
    for (int k = 0; k < 4; ++k) {
        float4 a = *reinterpret_cast<const float4*>(A_log + (size_t)d * NSTATE + k * 4);
        An2[k*4+0] = -__expf(a.x) * LOG2E;
        An2[k*4+1] = -__expf(a.y) * LOG2E;
        An2[k*4+2] = -__expf(a.z) * LOG2E;
        An2[k*4+3] = -__expf(a.w) * LOG2E;
    }
    const float c0 = An2[0];
    bool powok = true;
    #pragma unroll
    for (int n = 1; n < NSTATE; ++n)
        powok = powok && (fabsf(An2[n] - (n + 1) * c0) <= 1e-4f * (n + 1) * fabsf(c0));
    __syncthreads();

    float E[NSTATE];
    #pragma unroll
    for (int n = 0; n < NSTATE; ++n) E[n] = 0.f;
    float S = 0.f;

    float dtc = bf2f(dtb[row0 * DINNER + d]);
    float ucv = bf2f(ucbf[row0 * DINNER + d]);
    for (int s = 0; s < CHUNK; ++s) {
        float dtn = 0.f, un = 0.f;
        if (s + 1 < CHUNK) {
            dtn = bf2f(dtb[(row0 + s + 1) * DINNER + d]);
            un  = bf2f(ucbf[(row0 + s + 1) * DINNER + (d ^ (((s + 1) & 7) << 3))]);
        }
        S += dtc;
        float du = dtc * ucv;
        float Bv[NSTATE];
        #pragma unroll
        for (int k = 0; k < 4; ++k)
            *reinterpret_cast<float4*>(&Bv[k*4]) =
                *reinterpret_cast<const float4*>(&sB[s][k*4]);
        if (powok) {
            float q = EXP2F(dtc * c0);
            float dA = q;
            #pragma unroll
            for (int n = 0; n < NSTATE; ++n) {
                E[n] = fmaf(E[n], dA, du * Bv[n]);
                dA *= q;
            }
        } else {
            #pragma unroll
            for (int n = 0; n < NSTATE; ++n) {
                float qq = EXP2F(dtc * An2[n]);
                E[n] = fmaf(E[n], qq, du * Bv[n]);
            }
        }
        dtc = dtn; ucv = un;
    }

    size_t base = (((size_t)c * BSZ + b) * DINNER + d) * NSTATE;
    if (powok) {
        float R = EXP2F(c0 * S);
        float P = R;
        #pragma unroll
        for (int n = 0; n < NSTATE; ++n) {
            Pbuf[base + n] = P;
            Ebuf[base + n] = E[n];
            P *= R;
        }
    } else {
        #pragma unroll
        for (int n = 0; n < NSTATE; ++n) {
            Pbuf[base + n] = EXP2F(An2[n] * S);
            Ebuf[base + n] = E[n];
        }
    }
}

// ---------------------------------------------------------------------------
// Pass B: exclusive scan over chunks per (b,d,n); h0 written IN PLACE over P.
// ---------------------------------------------------------------------------
__global__ __launch_bounds__(256) void scan_prefix_kernel(
    float* __restrict__ Pbuf, const float* __restrict__ Ebuf)
{
    const int gid = blockIdx.x * 256 + threadIdx.x;
    const size_t stride = (size_t)BSZ * DINNER * NSTATE;
    size_t idx = gid;
    float h = 0.f;
    for (int c = 0; c < NCHUNK; ++c) {
        float P = Pbuf[idx];
        float Ev = Ebuf[idx];
        Pbuf[idx] = h;
        h = fmaf(P, h, Ev);
        idx += stride;
    }
}

// ---------------------------------------------------------------------------
// Pass C: local scan seeded with h0; fuse y, skip, gate; emit swizzled bf16
// ybf. Same geometric fast path as pass A.
// ---------------------------------------------------------------------------
__global__ __launch_bounds__(256) void scan_final_kernel(
    const unsigned short* __restrict__ dtb, const unsigned short* __restrict__ ucbf,
    const unsigned short* __restrict__ xzb, const float* __restrict__ dbc,
    const float* __restrict__ A_log, const float* __restrict__ Dp,
    const float* __restrict__ H0, unsigned short* __restrict__ ybf)
{
    __shared__ float sBC[CHUNK][2 * NSTATE];
    const int tid = threadIdx.x;
    const int c = blockIdx.x;
    const int b = blockIdx.z;
    const int d = blockIdx.y * 256 + tid;
    const size_t row0 = (size_t)b * LSEQ + c * CHUNK;

    {
        #pragma unroll
        for (int i = 0; i < 2; ++i) {
            int j = tid * 2 + i;
            int s = j >> 3, f = j & 7;
            float4 v = *reinterpret_cast<const float4*>(dbc + (row0 + s) * 96 + 64 + f * 4);
            *reinterpret_cast<float4*>(&sBC[s][f * 4]) = v;
        }
    }

    float An2[NSTATE];
    #pragma unroll
    for (int k = 0; k < 4; ++k) {
        float4 a = *reinterpret_cast<const float4*>(A_log + (size_t)d * NSTATE + k * 4);
        An2[k*4+0] = -__expf(a.x) * LOG2E;
        An2[k*4+1] = -__expf(a.y) * LOG2E;
        An2[k*4+2] = -__expf(a.z) * LOG2E;
        An2[k*4+3] = -__expf(a.w) * LOG2E;
    }
    const float c0 = An2[0];
    bool powok = true;
    #pragma unroll
    for (int n = 1; n < NSTATE; ++n)
        powok = powok && (fabsf(An2[n] - (n + 1) * c0) <= 1e-4f * (n + 1) * fabsf(c0));
    const float Dpd = Dp[d];

    float h[NSTATE];
    {
        size_t base = (((size_t)c * BSZ + b) * DINNER + d) * NSTATE;
        #pragma unroll
        for (int n = 0; n < NSTATE; ++n) h[n] = H0[base + n];
    }
    __syncthreads();

    float dtc = bf2f(dtb[row0 * DINNER + d]);
    float ucv = bf2f(ucbf[row0 * DINNER + d]);
    float zc  = bf2f(xzb[row0 * 4096 + 2048 + d]);
    for (int s = 0; s < CHUNK; ++s) {
        float dtn = 0.f, un = 0.f, zn = 0.f;
        if (s + 1 < CHUNK) {
            dtn = bf2f(dtb[(row0 + s + 1) * DINNER + d]);
            un  = bf2f(ucbf[(row0 + s + 1) * DINNER + (d ^ (((s + 1) & 7) << 3))]);
            zn  = bf2f(xzb[(row0 + s + 1) * 4096 + 2048 + d]);
        }
        float du = dtc * ucv;
        float Bv[NSTATE], Cv[NSTATE];
        #pragma unroll
        for (int k = 0; k < 4; ++k) {
            *reinterpret_cast<float4*>(&Bv[k*4]) =
                *reinterpret_cast<const float4*>(&sBC[s][k*4]);
            *reinterpret_cast<float4*>(&Cv[k*4]) =
                *reinterpret_cast<const float4*>(&sBC[s][16 + k*4]);
        }
        float y0 = 0.f, y1 = 0.f, y2 = 0.f, y3 = 0.f;
        if (powok) {
            float q = EXP2F(dtc * c0);
            float dA = q;
            #pragma unroll
            for (int n = 0; n < NSTATE; ++n) {
                h[n] = fmaf(h[n], dA, du * Bv[n]);
                float& yk = (n & 3) == 0 ? y0 : (n & 3) == 1 ? y1 : (n & 3) == 2 ? y2 : y3;
                yk = fmaf(h[n], Cv[n], yk);
                dA *= q;
            }
        } else {
            #pragma unroll
            for (int n = 0; n < NSTATE; ++n) {
                float qq = EXP2F(dtc * An2[n]);
                h[n] = fmaf(h[n], qq, du * Bv[n]);
                float& yk = (n & 3) == 0 ? y0 : (n & 3) == 1 ? y1 : (n & 3) == 2 ? y2 : y3;
                yk = fmaf(h[n], Cv[n], yk);
            }
        }
        float y = (y0 + y1) + (y2 + y3);
        float yg = (y + ucv * Dpd) * (zc * sigmoidf_(zc));
        ybf[(row0 + s) * DINNER + (d ^ ((s & 7) << 3))] = f2bf(yg);
        dtc = dtn; ucv = un; zc = zn;
    }
}

// ---------------------------------------------------------------------------
extern "C" void kernel_launch(void* const* d_in, const int* in_sizes, int n_in,
                              void* d_out, int out_size, void* d_ws, size_t ws_size,
                              hipStream_t stream)
{
    const float* x         = (const float*)d_in[0];
    const float* in_proj_w = (const float*)d_in[1];
    const float* conv_w    = (const float*)d_in[2];
    const float* conv_b    = (const float*)d_in[3];
    const float* x_proj_w  = (const float*)d_in[4];
    const float* dt_proj_w = (const float*)d_in[5];
    const float* dt_proj_b = (const float*)d_in[6];
    const float* A_log     = (const float*)d_in[7];
    const float* Dp        = (const float*)d_in[8];
    const float* out_proj_w= (const float*)d_in[9];
    float* out = (float*)d_out;

    // Workspace (208 MiB total) — same layout as round 9/10.
    char* base = (char*)d_ws;
    unsigned short* xzb  = (unsigned short*)base;
    unsigned short* dtb  = (unsigned short*)(base + (64ull << 20));
    unsigned short* ucbf = (unsigned short*)(base + (96ull << 20));
    float* dbc           = (float*)(base + (128ull << 20));
    unsigned short* wT_in  = (unsigned short*)(base + (131ull << 20));
    unsigned short* wT_out = (unsigned short*)(base + (139ull << 20));
    unsigned short* wXT    = (unsigned short*)(base + (143ull << 20));
    unsigned short* wDT    = (unsigned short*)(base + (143ull << 20) + (512ull << 10));
    char* U = base + (144ull << 20);
    unsigned short* xbf  = (unsigned short*)U;
    float* part          = (float*)U;
    unsigned short* dtlo = (unsigned short*)(U + (24ull << 20));
    float* Pbuf          = (float*)U;
    float* Ebuf          = (float*)(U + (16ull << 20));
    unsigned short* ybf  = (unsigned short*)(U + (32ull << 20));

    dim3 blk(256);

    // 0) fused operand prep (cvt x + all 4 weight transposes)
    prep_kernel<<<dim3(5728), blk, 0, stream>>>(
        x, xbf, in_proj_w, wT_in, out_proj_w, wT_out, x_proj_w, wXT, dt_proj_w, wDT);

    // 1) xzb = bf16(x @ in_proj_w)
    gemm_bb_kernel<1><<<dim3(32, 64), blk, 0, stream>>>(
        xbf, wT_in, (void*)xzb, MROWS, 4096, 1024, 4096);

    // 2) ucbf = swz_bf16(silu(causal_conv(u) + conv_b))
    conv_silu_kernel<<<dim3((MROWS * (DINNER / 8)) / 256), blk, 0, stream>>>(
        xzb, conv_w, conv_b, ucbf);

    // 3) dbc = uc @ x_proj_w  (bf16 MFMA split-K + reduce; emits dtlo bf16)
    xproj_splitk_bb_kernel<<<dim3(1, 64, XKS), blk, 0, stream>>>(ucbf, wXT, part);
    xproj_reduce_kernel<<<dim3((MROWS * 96) / 256), blk, 0, stream>>>(part, dbc, dtlo);

    // 4) dtb = bf16(softplus(dtlo @ dt_proj_w + dt_proj_b))
    gemm_dtproj_bb_kernel<<<dim3(16, 64), blk, 0, stream>>>(dtlo, wDT, dt_proj_b, dtb);

    // 5) chunked selective scan (3 passes) -> ybf (swizzled bf16)
    scan_partial_kernel<<<dim3(NCHUNK, DINNER / 256, BSZ), blk, 0, stream>>>(
        dtb, ucbf, dbc, A_log, Pbuf, Ebuf);
    scan_prefix_kernel<<<dim3((BSZ * DINNER * NSTATE) / 256), blk, 0, stream>>>(Pbuf, Ebuf);
    scan_final_kernel<<<dim3(NCHUNK, DINNER / 256, BSZ), blk, 0, stream>>>(
        dtb, ucbf, xzb, dbc, A_log, Dp, Pbuf, ybf);

    // 6) out = y_gated @ out_proj_w (fp32 out)
    gemm_bb_kernel<0><<<dim3(8, 64), blk, 0, stream>>>(
        ybf, wT_out, (void*)out, MROWS, 1024, 2048, 1024);
}

// Round 12
// 379.444 us; speedup vs baseline: 8.5964x; 1.0131x over previous
//
#include <hip/hip_runtime.h>
#include <hip/hip_bf16.h>
#include <math.h>

#define BSZ 2
#define LSEQ 4096
#define DMODEL 1024
#define DINNER 2048
#define NSTATE 16
#define DTRANK 64
#define MROWS (BSZ * LSEQ)   // 8192
#define NCHUNK 64
#define CHUNK (LSEQ / NCHUNK)  // 64
#define XKS 8
#define XKCH (DINNER / XKS)    // 256

#if __has_builtin(__builtin_amdgcn_exp2f)
#define EXP2F(x) __builtin_amdgcn_exp2f(x)
#else
#define EXP2F(x) exp2f(x)
#endif
#define LOG2E 1.44269504088896f

typedef __attribute__((ext_vector_type(8))) short bf16x8;
typedef __attribute__((ext_vector_type(4))) float f32x4;
typedef __attribute__((ext_vector_type(16))) float f32x16;

__device__ __forceinline__ float sigmoidf_(float x) { return 1.0f / (1.0f + __expf(-x)); }

__device__ __forceinline__ unsigned short f2bf(float x) {
    unsigned int u = __float_as_uint(x);
    u += 0x7fff + ((u >> 16) & 1);          // round-to-nearest-even
    return (unsigned short)(u >> 16);
}
__device__ __forceinline__ float bf2f(unsigned short b) {
    return __uint_as_float(((unsigned int)b) << 16);
}

// ---------------------------------------------------------------------------
// Fused operand prep (cvt x + 4 weight transposes), demuxed on blockIdx.
// Swizzle: element k of a 64-window stored at k ^ ((row&7)<<3).
// ---------------------------------------------------------------------------
__global__ __launch_bounds__(256) void prep_kernel(
    const float* __restrict__ x, unsigned short* __restrict__ xbf,
    const float* __restrict__ w_in, unsigned short* __restrict__ wT_in,
    const float* __restrict__ w_out, unsigned short* __restrict__ wT_out,
    const float* __restrict__ w_x, unsigned short* __restrict__ wXT,
    const float* __restrict__ w_dt, unsigned short* __restrict__ wDT)
{
    __shared__ float tile[64][65];
    const int id = blockIdx.x;
    const int t = threadIdx.x;

    if (id >= 1632) {   // cvt x -> xbf (K=1024, 128 groups of 8 per row)
        int gid = (id - 1632) * 256 + t;
        int m = gid >> 7;
        int g = gid & 127;
        size_t src = (size_t)m * 1024 + g * 8;
        float4 v0 = *reinterpret_cast<const float4*>(x + src);
        float4 v1 = *reinterpret_cast<const float4*>(x + src + 4);
        uint4 w;
        w.x = (unsigned)f2bf(v0.x) | ((unsigned)f2bf(v0.y) << 16);
        w.y = (unsigned)f2bf(v0.z) | ((unsigned)f2bf(v0.w) << 16);
        w.z = (unsigned)f2bf(v1.x) | ((unsigned)f2bf(v1.y) << 16);
        w.w = (unsigned)f2bf(v1.z) | ((unsigned)f2bf(v1.w) << 16);
        size_t dst = (size_t)m * 1024 + ((g * 8) ^ ((m & 7) << 3));
        *reinterpret_cast<uint4*>(xbf + dst) = w;
        return;
    }

    const float* W; unsigned short* WT; int K, Nsrc, nb, kb;
    if (id < 1024)      { W = w_in;  WT = wT_in;  K = 1024; Nsrc = 4096; nb = id & 63; kb = id >> 6; }
    else if (id < 1536) { int q = id - 1024; W = w_out; WT = wT_out; K = 2048; Nsrc = 1024; nb = q & 15; kb = q >> 4; }
    else if (id < 1600) { int q = id - 1536; W = w_x;   WT = wXT;   K = 2048; Nsrc = 96;   nb = q & 1;  kb = q >> 1; }
    else                { int q = id - 1600; W = w_dt;  WT = wDT;   K = 64;   Nsrc = 2048; nb = q;      kb = 0; }

    const int n0 = nb * 64;
    const int k0 = kb * 64;

    #pragma unroll
    for (int i = 0; i < 16; ++i) {
        int flat = i * 256 + t;
        int r = flat >> 6, c = flat & 63;
        tile[r][c] = (n0 + c < Nsrc) ? W[(size_t)(k0 + r) * Nsrc + n0 + c] : 0.0f;
    }
    __syncthreads();
    #pragma unroll
    for (int i = 0; i < 16; ++i) {
        int flat = i * 256 + t;
        int n = flat >> 6, k = flat & 63;
        int ks = k ^ ((n & 7) << 3);
        WT[(size_t)(n0 + n) * K + k0 + ks] = f2bf(tile[k][n]);
    }
}

// ---------------------------------------------------------------------------
// Pure-bf16 MFMA GEMM, 32x32x16 fragments (higher per-cycle rate, half the
// MFMA instruction count vs 16x16x32). Both operands pre-swizzled bf16 [.][K],
// width-16 global_load_lds. 128x128 tile, BK=64, 4 waves x 64x64 quadrant
// = 2x2 of 32x32 fragments. A/B frag: lane&31 = row/col, k = (lane>>5)*8+j
// (within-instruction k-permutation cancels between A and B).
// C/D: col=lane&31, row=(reg&3)+8*(reg>>2)+4*(lane>>5) [HW-verified].
// OBF=1: bf16 C; OBF=0: fp32 C.
// ---------------------------------------------------------------------------
template<int OBF>
__global__ __launch_bounds__(256) void gemm_bb_kernel(
    const unsigned short* __restrict__ Abf, const unsigned short* __restrict__ BT,
    void* __restrict__ Cv, int M, int N, int K, int ldc)
{
    __shared__ unsigned short lds_a[128 * 64];
    __shared__ unsigned short lds_b[128 * 64];

    const int tid  = threadIdx.x;
    const int lane = tid & 63;
    const int w    = tid >> 6;
    const int wr   = (w >> 1) * 64;
    const int wc   = (w & 1) * 64;
    const int row0 = blockIdx.y * 128;
    const int col0 = blockIdx.x * 128;

    f32x16 acc[2][2];
    #pragma unroll
    for (int m = 0; m < 2; ++m)
        #pragma unroll
        for (int n = 0; n < 2; ++n)
            acc[m][n] = (f32x16){0.f,0.f,0.f,0.f,0.f,0.f,0.f,0.f,
                                 0.f,0.f,0.f,0.f,0.f,0.f,0.f,0.f};

    for (int k0 = 0; k0 < K; k0 += 64) {
        #pragma unroll
        for (int j = 0; j < 4; ++j) {
            int c  = (j * 4 + w) * 64 + lane;
            int r  = c >> 3;
            int cc = c & 7;
            const char* asrc = (const char*)Abf +
                ((size_t)(row0 + r) * K + k0) * 2 + cc * 16;
            __builtin_amdgcn_global_load_lds(
                (const __attribute__((address_space(1))) void*)asrc,
                (__attribute__((address_space(3))) void*)((char*)lds_a + (j * 4 + w) * 1024),
                16, 0, 0);
            const char* bsrc = (const char*)BT +
                ((size_t)(col0 + r) * K + k0) * 2 + cc * 16;
            __builtin_amdgcn_global_load_lds(
                (const __attribute__((address_space(1))) void*)bsrc,
                (__attribute__((address_space(3))) void*)((char*)lds_b + (j * 4 + w) * 1024),
                16, 0, 0);
        }
        __syncthreads();

        #pragma unroll
        for (int kk = 0; kk < 4; ++kk) {
            const int koff = kk * 32 + ((lane >> 5) << 4);   // byte offset of 8-k group
            bf16x8 af[2], bfr[2];
            #pragma unroll
            for (int m = 0; m < 2; ++m) {
                int r = wr + m * 32 + (lane & 31);
                int byteoff = r * 128 + (koff ^ ((r & 7) << 4));
                af[m] = *reinterpret_cast<const bf16x8*>((const char*)lds_a + byteoff);
            }
            #pragma unroll
            for (int n = 0; n < 2; ++n) {
                int r = wc + n * 32 + (lane & 31);
                int byteoff = r * 128 + (koff ^ ((r & 7) << 4));
                bfr[n] = *reinterpret_cast<const bf16x8*>((const char*)lds_b + byteoff);
            }
            #pragma unroll
            for (int m = 0; m < 2; ++m)
                #pragma unroll
                for (int n = 0; n < 2; ++n)
                    acc[m][n] = __builtin_amdgcn_mfma_f32_32x32x16_bf16(
                        af[m], bfr[n], acc[m][n], 0, 0, 0);
        }
        __syncthreads();
    }

    #pragma unroll
    for (int m = 0; m < 2; ++m) {
        #pragma unroll
        for (int n = 0; n < 2; ++n) {
            int col = col0 + wc + n * 32 + (lane & 31);
            #pragma unroll
            for (int g = 0; g < 4; ++g) {
                #pragma unroll
                for (int rr = 0; rr < 4; ++rr) {
                    int row = row0 + wr + m * 32 + g * 8 + rr + ((lane >> 5) << 2);
                    float v = acc[m][n][g * 4 + rr];
                    if (OBF) {
                        ((unsigned short*)Cv)[(size_t)row * ldc + col] = f2bf(v);
                    } else {
                        ((float*)Cv)[(size_t)row * ldc + col] = v;
                    }
                }
            }
        }
    }
}

// ---------------------------------------------------------------------------
// MFMA split-K x_proj (16x16 fragments, unchanged): part[z] = ucbf @ wXT^T.
// Grid (1, M/128, XKS). fp32 partials [XKS][MROWS][96].
// ---------------------------------------------------------------------------
__global__ __launch_bounds__(256) void xproj_splitk_bb_kernel(
    const unsigned short* __restrict__ Abf, const unsigned short* __restrict__ BT,
    float* __restrict__ part)
{
    __shared__ unsigned short lds_a[128 * 64];
    __shared__ unsigned short lds_b[128 * 64];

    const int tid  = threadIdx.x;
    const int lane = tid & 63;
    const int w    = tid >> 6;
    const int wr   = (w >> 1) * 64;
    const int wc   = (w & 1) * 64;
    const int row0 = blockIdx.y * 128;
    const int kb   = blockIdx.z * XKCH;
    const int K    = DINNER;

    f32x4 acc[4][4];
    #pragma unroll
    for (int m = 0; m < 4; ++m)
        #pragma unroll
        for (int n = 0; n < 4; ++n)
            acc[m][n] = (f32x4){0.f, 0.f, 0.f, 0.f};

    for (int k0 = kb; k0 < kb + XKCH; k0 += 64) {
        #pragma unroll
        for (int j = 0; j < 4; ++j) {
            int c  = (j * 4 + w) * 64 + lane;
            int r  = c >> 3;
            int cc = c & 7;
            const char* asrc = (const char*)Abf +
                ((size_t)(row0 + r) * K + k0) * 2 + cc * 16;
            __builtin_amdgcn_global_load_lds(
                (const __attribute__((address_space(1))) void*)asrc,
                (__attribute__((address_space(3))) void*)((char*)lds_a + (j * 4 + w) * 1024),
                16, 0, 0);
            const char* bsrc = (const char*)BT +
                ((size_t)r * K + k0) * 2 + cc * 16;
            __builtin_amdgcn_global_load_lds(
                (const __attribute__((address_space(1))) void*)bsrc,
                (__attribute__((address_space(3))) void*)((char*)lds_b + (j * 4 + w) * 1024),
                16, 0, 0);
        }
        __syncthreads();

        #pragma unroll
        for (int kk = 0; kk < 2; ++kk) {
            bf16x8 af[4], bfr[4];
            #pragma unroll
            for (int m = 0; m < 4; ++m) {
                int r = wr + m * 16 + (lane & 15);
                int byteoff = r * 128 + ((kk * 64 + (lane >> 4) * 16) ^ ((r & 7) << 4));
                af[m] = *reinterpret_cast<const bf16x8*>((const char*)lds_a + byteoff);
            }
            #pragma unroll
            for (int n = 0; n < 4; ++n) {
                int r = wc + n * 16 + (lane & 15);
                int byteoff = r * 128 + ((kk * 64 + (lane >> 4) * 16) ^ ((r & 7) << 4));
                bfr[n] = *reinterpret_cast<const bf16x8*>((const char*)lds_b + byteoff);
            }
            #pragma unroll
            for (int m = 0; m < 4; ++m)
                #pragma unroll
                for (int n = 0; n < 4; ++n)
                    acc[m][n] = __builtin_amdgcn_mfma_f32_16x16x32_bf16(
                        af[m], bfr[n], acc[m][n], 0, 0, 0);
        }
        __syncthreads();
    }

    float* pbase = part + (size_t)blockIdx.z * MROWS * 96;
    #pragma unroll
    for (int m = 0; m < 4; ++m) {
        int rbase = row0 + wr + m * 16 + (lane >> 4) * 4;
        #pragma unroll
        for (int n = 0; n < 4; ++n) {
            int col = wc + n * 16 + (lane & 15);
            if (col < 96) {
                #pragma unroll
                for (int r = 0; r < 4; ++r)
                    pbase[(size_t)(rbase + r) * 96 + col] = acc[m][n][r];
            }
        }
    }
}

// Reduce XKS partials -> dbc fp32; cols<64 also emitted as pre-swizzled bf16.
__global__ __launch_bounds__(256) void xproj_reduce_kernel(
    const float* __restrict__ part, float* __restrict__ dbc,
    unsigned short* __restrict__ dtlo)
{
    int gid = blockIdx.x * 256 + threadIdx.x;
    float s = 0.f;
    #pragma unroll
    for (int k = 0; k < XKS; ++k)
        s += part[(size_t)k * MROWS * 96 + gid];
    dbc[gid] = s;
    int row = gid / 96;
    int col = gid - row * 96;
    if (col < 64)
        dtlo[(size_t)row * 64 + (col ^ ((row & 7) << 3))] = f2bf(s);
}

// ---------------------------------------------------------------------------
// dt_proj MFMA (K=64, one K-step): dtb = bf16(softplus(dtlo @ wDT^T + bias)).
// ---------------------------------------------------------------------------
__global__ __launch_bounds__(256) void gemm_dtproj_bb_kernel(
    const unsigned short* __restrict__ Abf, const unsigned short* __restrict__ BT,
    const float* __restrict__ bias, unsigned short* __restrict__ C)
{
    __shared__ unsigned short lds_a[128 * 64];
    __shared__ unsigned short lds_b[128 * 64];

    const int tid  = threadIdx.x;
    const int lane = tid & 63;
    const int w    = tid >> 6;
    const int wr   = (w >> 1) * 64;
    const int wc   = (w & 1) * 64;
    const int row0 = blockIdx.y * 128;
    const int col0 = blockIdx.x * 128;

    f32x4 acc[4][4];
    #pragma unroll
    for (int m = 0; m < 4; ++m)
        #pragma unroll
        for (int n = 0; n < 4; ++n)
            acc[m][n] = (f32x4){0.f, 0.f, 0.f, 0.f};

    #pragma unroll
    for (int j = 0; j < 4; ++j) {
        int c  = (j * 4 + w) * 64 + lane;
        int r  = c >> 3;
        int cc = c & 7;
        const char* asrc = (const char*)Abf + ((size_t)(row0 + r) * 64) * 2 + cc * 16;
        __builtin_amdgcn_global_load_lds(
            (const __attribute__((address_space(1))) void*)asrc,
            (__attribute__((address_space(3))) void*)((char*)lds_a + (j * 4 + w) * 1024),
            16, 0, 0);
        const char* bsrc = (const char*)BT + ((size_t)(col0 + r) * 64) * 2 + cc * 16;
        __builtin_amdgcn_global_load_lds(
            (const __attribute__((address_space(1))) void*)bsrc,
            (__attribute__((address_space(3))) void*)((char*)lds_b + (j * 4 + w) * 1024),
            16, 0, 0);
    }
    __syncthreads();

    #pragma unroll
    for (int kk = 0; kk < 2; ++kk) {
        bf16x8 af[4], bfr[4];
        #pragma unroll
        for (int m = 0; m < 4; ++m) {
            int r = wr + m * 16 + (lane & 15);
            int byteoff = r * 128 + ((kk * 64 + (lane >> 4) * 16) ^ ((r & 7) << 4));
            af[m] = *reinterpret_cast<const bf16x8*>((const char*)lds_a + byteoff);
        }
        #pragma unroll
        for (int n = 0; n < 4; ++n) {
            int r = wc + n * 16 + (lane & 15);
            int byteoff = r * 128 + ((kk * 64 + (lane >> 4) * 16) ^ ((r & 7) << 4));
            bfr[n] = *reinterpret_cast<const bf16x8*>((const char*)lds_b + byteoff);
        }
        #pragma unroll
        for (int m = 0; m < 4; ++m)
            #pragma unroll
            for (int n = 0; n < 4; ++n)
                acc[m][n] = __builtin_amdgcn_mfma_f32_16x16x32_bf16(
                    af[m], bfr[n], acc[m][n], 0, 0, 0);
    }

    #pragma unroll
    for (int m = 0; m < 4; ++m) {
        int rbase = row0 + wr + m * 16 + (lane >> 4) * 4;
        #pragma unroll
        for (int n = 0; n < 4; ++n) {
            int col = col0 + wc + n * 16 + (lane & 15);
            float bv = bias[col];
            #pragma unroll
            for (int r = 0; r < 4; ++r) {
                float v = acc[m][n][r] + bv;
                v = (v > 20.0f) ? v : log1pf(__expf(v));
                C[(size_t)(rbase + r) * DINNER + col] = f2bf(v);
            }
        }
    }
}

// ---------------------------------------------------------------------------
// Causal depthwise conv1d (width 4) + bias + silu, bf16 in -> swizzled bf16 out.
// ---------------------------------------------------------------------------
__global__ __launch_bounds__(256) void conv_silu_kernel(
    const unsigned short* __restrict__ xzb, const float* __restrict__ cw,
    const float* __restrict__ cb, unsigned short* __restrict__ ucbf)
{
    int gid = blockIdx.x * 256 + threadIdx.x;     // over MROWS * (DINNER/8)
    int row = gid >> 8;
    int d0  = (gid & 255) * 8;
    int t = row & (LSEQ - 1);

    uint4 uv[4];
    #pragma unroll
    for (int k = 0; k < 4; ++k) {
        if (t - 3 + k >= 0)
            uv[k] = *reinterpret_cast<const uint4*>(
                xzb + (size_t)(row + k - 3) * 4096 + d0);
        else
            uv[k] = (uint4){0u, 0u, 0u, 0u};
    }

    float v[8];
    #pragma unroll
    for (int i = 0; i < 8; ++i) {
        float acc = cb[d0 + i];
        float4 wv = *reinterpret_cast<const float4*>(cw + (size_t)(d0 + i) * 4);
        float wk[4] = {wv.x, wv.y, wv.z, wv.w};
        #pragma unroll
        for (int k = 0; k < 4; ++k) {
            unsigned int word = (&uv[k].x)[i >> 1];
            float u = __uint_as_float((i & 1) ? (word & 0xffff0000u) : (word << 16));
            acc = fmaf(u, wk[k], acc);
        }
        v[i] = acc * sigmoidf_(acc);
    }

    uint4 o;
    o.x = (unsigned)f2bf(v[0]) | ((unsigned)f2bf(v[1]) << 16);
    o.y = (unsigned)f2bf(v[2]) | ((unsigned)f2bf(v[3]) << 16);
    o.z = (unsigned)f2bf(v[4]) | ((unsigned)f2bf(v[5]) << 16);
    o.w = (unsigned)f2bf(v[6]) | ((unsigned)f2bf(v[7]) << 16);
    *reinterpret_cast<uint4*>(
        ucbf + (size_t)row * DINNER + (d0 ^ ((row & 7) << 3))) = o;
}

// ---------------------------------------------------------------------------
// Chunked scan, pass A, with geometric-A fast path (checked at runtime).
// ---------------------------------------------------------------------------
__global__ __launch_bounds__(256) void scan_partial_kernel(
    const unsigned short* __restrict__ dtb, const unsigned short* __restrict__ ucbf,
    const float* __restrict__ dbc, const float* __restrict__ A_log,
    float* __restrict__ Pbuf, float* __restrict__ Ebuf)
{
    __shared__ float sB[CHUNK][NSTATE];
    const int tid = threadIdx.x;
    const int c = blockIdx.x;
    const int b = blockIdx.z;
    const int d = blockIdx.y * 256 + tid;
    const size_t row0 = (size_t)b * LSEQ + c * CHUNK;

    {
        int s = tid >> 2, f = tid & 3;
        float4 v = *reinterpret_cast<const float4*>(dbc + (row0 + s) * 96 + 64 + f * 4);
        *reinterpret_cast<float4*>(&sB[s][f * 4]) = v;
    }

    float An2[NSTATE];
    #pragma unroll
    for (int k = 0; k < 4; ++k) {
        float4 a = *reinterpret_cast<const float4*>(A_log + (size_t)d * NSTATE + k * 4);
        An2[k*4+0] = -__expf(a.x) * LOG2E;
        An2[k*4+1] = -__expf(a.y) * LOG2E;
        An2[k*4+2] = -__expf(a.z) * LOG2E;
        An2[k*4+3] = -__expf(a.w) * LOG2E;
    }
    const float c0 = An2[0];
    bool powok = true;
    #pragma unroll
    for (int n = 1; n < NSTATE; ++n)
        powok = powok && (fabsf(An2[n] - (n + 1) * c0) <= 1e-4f * (n + 1) * fabsf(c0));
    __syncthreads();

    float E[NSTATE];
    #pragma unroll
    for (int n = 0; n < NSTATE; ++n) E[n] = 0.f;
    float S = 0.f;

    float dtc = bf2f(dtb[row0 * DINNER + d]);
    float ucv = bf2f(ucbf[row0 * DINNER + d]);
    for (int s = 0; s < CHUNK; ++s) {
        float dtn = 0.f, un = 0.f;
        if (s + 1 < CHUNK) {
            dtn = bf2f(dtb[(row0 + s + 1) * DINNER + d]);
            un  = bf2f(ucbf[(row0 + s + 1) * DINNER + (d ^ (((s + 1) & 7) << 3))]);
        }
        S += dtc;
        float du = dtc * ucv;
        float Bv[NSTATE];
        #pragma unroll
        for (int k = 0; k < 4; ++k)
            *reinterpret_cast<float4*>(&Bv[k*4]) =
                *reinterpret_cast<const float4*>(&sB[s][k*4]);
        if (powok) {
            float q = EXP2F(dtc * c0);
            float dA = q;
            #pragma unroll
            for (int n = 0; n < NSTATE; ++n) {
                E[n] = fmaf(E[n], dA, du * Bv[n]);
                dA *= q;
            }
        } else {
            #pragma unroll
            for (int n = 0; n < NSTATE; ++n) {
                float qq = EXP2F(dtc * An2[n]);
                E[n] = fmaf(E[n], qq, du * Bv[n]);
            }
        }
        dtc = dtn; ucv = un;
    }

    size_t base = (((size_t)c * BSZ + b) * DINNER + d) * NSTATE;
    if (powok) {
        float R = EXP2F(c0 * S);
        float P = R;
        #pragma unroll
        for (int n = 0; n < NSTATE; ++n) {
            Pbuf[base + n] = P;
            Ebuf[base + n] = E[n];
            P *= R;
        }
    } else {
        #pragma unroll
        for (int n = 0; n < NSTATE; ++n) {
            Pbuf[base + n] = EXP2F(An2[n] * S);
            Ebuf[base + n] = E[n];
        }
    }
}

// ---------------------------------------------------------------------------
// Pass B: exclusive scan over chunks per (b,d,n); h0 written IN PLACE over P.
// ---------------------------------------------------------------------------
__global__ __launch_bounds__(256) void scan_prefix_kernel(
    float* __restrict__ Pbuf, const float* __restrict__ Ebuf)
{
    const int gid = blockIdx.x * 256 + threadIdx.x;
    const size_t stride = (size_t)BSZ * DINNER * NSTATE;
    size_t idx = gid;
    float h = 0.f;
    for (int c = 0; c < NCHUNK; ++c) {
        float P = Pbuf[idx];
        float Ev = Ebuf[idx];
        Pbuf[idx] = h;
        h = fmaf(P, h, Ev);
        idx += stride;
    }
}

// ---------------------------------------------------------------------------
// Pass C: local scan seeded with h0; fuse y, skip, gate; emit swizzled bf16
// ybf. Same geometric fast path as pass A.
// ---------------------------------------------------------------------------
__global__ __launch_bounds__(256) void scan_final_kernel(
    const unsigned short* __restrict__ dtb, const unsigned short* __restrict__ ucbf,
    const unsigned short* __restrict__ xzb, const float* __restrict__ dbc,
    const float* __restrict__ A_log, const float* __restrict__ Dp,
    const float* __restrict__ H0, unsigned short* __restrict__ ybf)
{
    __shared__ float sBC[CHUNK][2 * NSTATE];
    const int tid = threadIdx.x;
    const int c = blockIdx.x;
    const int b = blockIdx.z;
    const int d = blockIdx.y * 256 + tid;
    const size_t row0 = (size_t)b * LSEQ + c * CHUNK;

    {
        #pragma unroll
        for (int i = 0; i < 2; ++i) {
            int j = tid * 2 + i;
            int s = j >> 3, f = j & 7;
            float4 v = *reinterpret_cast<const float4*>(dbc + (row0 + s) * 96 + 64 + f * 4);
            *reinterpret_cast<float4*>(&sBC[s][f * 4]) = v;
        }
    }

    float An2[NSTATE];
    #pragma unroll
    for (int k = 0; k < 4; ++k) {
        float4 a = *reinterpret_cast<const float4*>(A_log + (size_t)d * NSTATE + k * 4);
        An2[k*4+0] = -__expf(a.x) * LOG2E;
        An2[k*4+1] = -__expf(a.y) * LOG2E;
        An2[k*4+2] = -__expf(a.z) * LOG2E;
        An2[k*4+3] = -__expf(a.w) * LOG2E;
    }
    const float c0 = An2[0];
    bool powok = true;
    #pragma unroll
    for (int n = 1; n < NSTATE; ++n)
        powok = powok && (fabsf(An2[n] - (n + 1) * c0) <= 1e-4f * (n + 1) * fabsf(c0));
    const float Dpd = Dp[d];

    float h[NSTATE];
    {
        size_t base = (((size_t)c * BSZ + b) * DINNER + d) * NSTATE;
        #pragma unroll
        for (int n = 0; n < NSTATE; ++n) h[n] = H0[base + n];
    }
    __syncthreads();

    float dtc = bf2f(dtb[row0 * DINNER + d]);
    float ucv = bf2f(ucbf[row0 * DINNER + d]);
    float zc  = bf2f(xzb[row0 * 4096 + 2048 + d]);
    for (int s = 0; s < CHUNK; ++s) {
        float dtn = 0.f, un = 0.f, zn = 0.f;
        if (s + 1 < CHUNK) {
            dtn = bf2f(dtb[(row0 + s + 1) * DINNER + d]);
            un  = bf2f(ucbf[(row0 + s + 1) * DINNER + (d ^ (((s + 1) & 7) << 3))]);
            zn  = bf2f(xzb[(row0 + s + 1) * 4096 + 2048 + d]);
        }
        float du = dtc * ucv;
        float Bv[NSTATE], Cv[NSTATE];
        #pragma unroll
        for (int k = 0; k < 4; ++k) {
            *reinterpret_cast<float4*>(&Bv[k*4]) =
                *reinterpret_cast<const float4*>(&sBC[s][k*4]);
            *reinterpret_cast<float4*>(&Cv[k*4]) =
                *reinterpret_cast<const float4*>(&sBC[s][16 + k*4]);
        }
        float y0 = 0.f, y1 = 0.f, y2 = 0.f, y3 = 0.f;
        if (powok) {
            float q = EXP2F(dtc * c0);
            float dA = q;
            #pragma unroll
            for (int n = 0; n < NSTATE; ++n) {
                h[n] = fmaf(h[n], dA, du * Bv[n]);
                float& yk = (n & 3) == 0 ? y0 : (n & 3) == 1 ? y1 : (n & 3) == 2 ? y2 : y3;
                yk = fmaf(h[n], Cv[n], yk);
                dA *= q;
            }
        } else {
            #pragma unroll
            for (int n = 0; n < NSTATE; ++n) {
                float qq = EXP2F(dtc * An2[n]);
                h[n] = fmaf(h[n], qq, du * Bv[n]);
                float& yk = (n & 3) == 0 ? y0 : (n & 3) == 1 ? y1 : (n & 3) == 2 ? y2 : y3;
                yk = fmaf(h[n], Cv[n], yk);
            }
        }
        float y = (y0 + y1) + (y2 + y3);
        float yg = (y + ucv * Dpd) * (zc * sigmoidf_(zc));
        ybf[(row0 + s) * DINNER + (d ^ ((s & 7) << 3))] = f2bf(yg);
        dtc = dtn; ucv = un; zc = zn;
    }
}

// ---------------------------------------------------------------------------
extern "C" void kernel_launch(void* const* d_in, const int* in_sizes, int n_in,
                              void* d_out, int out_size, void* d_ws, size_t ws_size,
                              hipStream_t stream)
{
    const float* x         = (const float*)d_in[0];
    const float* in_proj_w = (const float*)d_in[1];
    const float* conv_w    = (const float*)d_in[2];
    const float* conv_b    = (const float*)d_in[3];
    const float* x_proj_w  = (const float*)d_in[4];
    const float* dt_proj_w = (const float*)d_in[5];
    const float* dt_proj_b = (const float*)d_in[6];
    const float* A_log     = (const float*)d_in[7];
    const float* Dp        = (const float*)d_in[8];
    const float* out_proj_w= (const float*)d_in[9];
    float* out = (float*)d_out;

    // Workspace (208 MiB total) — same layout as rounds 9-11.
    char* base = (char*)d_ws;
    unsigned short* xzb  = (unsigned short*)base;
    unsigned short* dtb  = (unsigned short*)(base + (64ull << 20));
    unsigned short* ucbf = (unsigned short*)(base + (96ull << 20));
    float* dbc           = (float*)(base + (128ull << 20));
    unsigned short* wT_in  = (unsigned short*)(base + (131ull << 20));
    unsigned short* wT_out = (unsigned short*)(base + (139ull << 20));
    unsigned short* wXT    = (unsigned short*)(base + (143ull << 20));
    unsigned short* wDT    = (unsigned short*)(base + (143ull << 20) + (512ull << 10));
    char* U = base + (144ull << 20);
    unsigned short* xbf  = (unsigned short*)U;
    float* part          = (float*)U;
    unsigned short* dtlo = (unsigned short*)(U + (24ull << 20));
    float* Pbuf          = (float*)U;
    float* Ebuf          = (float*)(U + (16ull << 20));
    unsigned short* ybf  = (unsigned short*)(U + (32ull << 20));

    dim3 blk(256);

    // 0) fused operand prep (cvt x + all 4 weight transposes)
    prep_kernel<<<dim3(5728), blk, 0, stream>>>(
        x, xbf, in_proj_w, wT_in, out_proj_w, wT_out, x_proj_w, wXT, dt_proj_w, wDT);

    // 1) xzb = bf16(x @ in_proj_w)
    gemm_bb_kernel<1><<<dim3(32, 64), blk, 0, stream>>>(
        xbf, wT_in, (void*)xzb, MROWS, 4096, 1024, 4096);

    // 2) ucbf = swz_bf16(silu(causal_conv(u) + conv_b))
    conv_silu_kernel<<<dim3((MROWS * (DINNER / 8)) / 256), blk, 0, stream>>>(
        xzb, conv_w, conv_b, ucbf);

    // 3) dbc = uc @ x_proj_w  (bf16 MFMA split-K + reduce; emits dtlo bf16)
    xproj_splitk_bb_kernel<<<dim3(1, 64, XKS), blk, 0, stream>>>(ucbf, wXT, part);
    xproj_reduce_kernel<<<dim3((MROWS * 96) / 256), blk, 0, stream>>>(part, dbc, dtlo);

    // 4) dtb = bf16(softplus(dtlo @ dt_proj_w + dt_proj_b))
    gemm_dtproj_bb_kernel<<<dim3(16, 64), blk, 0, stream>>>(dtlo, wDT, dt_proj_b, dtb);

    // 5) chunked selective scan (3 passes) -> ybf (swizzled bf16)
    scan_partial_kernel<<<dim3(NCHUNK, DINNER / 256, BSZ), blk, 0, stream>>>(
        dtb, ucbf, dbc, A_log, Pbuf, Ebuf);
    scan_prefix_kernel<<<dim3((BSZ * DINNER * NSTATE) / 256), blk, 0, stream>>>(Pbuf, Ebuf);
    scan_final_kernel<<<dim3(NCHUNK, DINNER / 256, BSZ), blk, 0, stream>>>(
        dtb, ucbf, xzb, dbc, A_log, Dp, Pbuf, ybf);

    // 6) out = y_gated @ out_proj_w (fp32 out)
    gemm_bb_kernel<0><<<dim3(8, 64), blk, 0, stream>>>(
        ybf, wT_out, (void*)out, MROWS, 1024, 2048, 1024);
}